// Round 2
// baseline (2722.217 us; speedup 1.0000x reference)
//
#include <hip/hip_runtime.h>
#include <hip/hip_bf16.h>

typedef __hip_bfloat16 bf16;

__device__ __forceinline__ float u2f(unsigned short u){
  union { unsigned int i; float f; } v; v.i = ((unsigned int)u) << 16; return v.f;
}
__device__ __forceinline__ float bfu(bf16 x){ return __bfloat162float(x); }
__device__ __forceinline__ bf16  f2b(float x){ return __float2bfloat16(x); }

__device__ __forceinline__ float4 load4(const bf16* p){
  ushort4 v = *reinterpret_cast<const ushort4*>(p);
  return make_float4(u2f(v.x), u2f(v.y), u2f(v.z), u2f(v.w));
}
__device__ __forceinline__ float4 load4(const float* p){
  return *reinterpret_cast<const float4*>(p);
}

// ---------------- block reduction (256 threads) ----------------
__device__ __forceinline__ float block_sum256(float v, float* red){
  #pragma unroll
  for (int o = 32; o > 0; o >>= 1) v += __shfl_down(v, o, 64);
  int lane = threadIdx.x & 63, wid = threadIdx.x >> 6;
  if (lane == 0) red[wid] = v;
  __syncthreads();
  float r = red[0] + red[1] + red[2] + red[3];
  __syncthreads();
  return r;
}

// ---------------- stem: conv_a + pool/conv_p + SE -> h (f32, [N][4][512]) ----
__global__ __launch_bounds__(256) void stem_kernel(
    const float* __restrict__ x_flat, const float* __restrict__ caw,
    const float* __restrict__ cpw,
    const float* __restrict__ sw1, const float* __restrict__ sb1,
    const float* __restrict__ sw2, const float* __restrict__ sb2,
    float* __restrict__ hout)
{
  __shared__ float xs[512][8];
  __shared__ float ps[512][4];
  __shared__ float ys[512][4];
  __shared__ float yms[512];
  __shared__ float s1s[32];
  const int n = blockIdx.x, tid = threadIdx.x;
  const float* xr = x_flat + (size_t)n * 3584;
  for (int i = tid; i < 3584; i += 256) xs[i / 7][i % 7] = xr[i];
  __syncthreads();
  // maxpool k=3 s=2 pad=1
  for (int i = tid; i < 2048; i += 256){
    int c = i >> 2, t = i & 3, st = 2 * t - 1;
    float m = -1e30f;
    #pragma unroll
    for (int k = 0; k < 3; ++k){ int p = st + k; if (p >= 0 && p < 7) m = fmaxf(m, xs[c][p]); }
    ps[c][t] = m;
  }
  __syncthreads();
  // conv_a: o = tid, k=3 s=2 pad=1, relu
  {
    const int o = tid;
    float a0=0.f, a1=0.f, a2=0.f, a3=0.f;
    const float* wr = caw + (size_t)o * 1536;
    for (int i = 0; i < 512; ++i){
      float w0 = wr[i*3], w1 = wr[i*3+1], w2 = wr[i*3+2];
      const float* xi = xs[i];
      a0 += xi[0]*w1 + xi[1]*w2;
      a1 += xi[1]*w0 + xi[2]*w1 + xi[3]*w2;
      a2 += xi[3]*w0 + xi[4]*w1 + xi[5]*w2;
      a3 += xi[5]*w0 + xi[6]*w1;
    }
    ys[o][0]=fmaxf(a0,0.f); ys[o][1]=fmaxf(a1,0.f); ys[o][2]=fmaxf(a2,0.f); ys[o][3]=fmaxf(a3,0.f);
  }
  // conv_p: 1x1 on pooled, relu
  {
    const int o = tid;
    float a[4] = {0.f,0.f,0.f,0.f};
    const float* wr = cpw + (size_t)o * 512;
    for (int i = 0; i < 512; ++i){
      float w = wr[i];
      a[0]+=w*ps[i][0]; a[1]+=w*ps[i][1]; a[2]+=w*ps[i][2]; a[3]+=w*ps[i][3];
    }
    #pragma unroll
    for (int t = 0; t < 4; ++t) ys[256+o][t] = fmaxf(a[t],0.f);
  }
  __syncthreads();
  for (int c = tid; c < 512; c += 256)
    yms[c] = 0.25f * (ys[c][0]+ys[c][1]+ys[c][2]+ys[c][3]);
  __syncthreads();
  if (tid < 32){
    float a = sb1[tid];
    const float* wr = sw1 + (size_t)tid * 512;
    for (int i = 0; i < 512; ++i) a += wr[i] * yms[i];
    s1s[tid] = fmaxf(a, 0.f);
  }
  __syncthreads();
  for (int c = tid; c < 512; c += 256){
    float a = sb2[c];
    const float* wr = sw2 + (size_t)c * 32;
    #pragma unroll
    for (int j = 0; j < 32; ++j) a += wr[j] * s1s[j];
    float s = 1.f / (1.f + __expf(-a));
    #pragma unroll
    for (int t = 0; t < 4; ++t)
      hout[((size_t)n*4 + t)*512 + c] = ys[c][t] * s;
  }
}

// ---------------- layernorm rows of 512: f32 in -> bf16 out ----------------
__global__ __launch_bounds__(256) void ln_kernel(
    const float* __restrict__ x, const float* __restrict__ g,
    const float* __restrict__ b, bf16* __restrict__ out)
{
  __shared__ float red[4];
  const int row = blockIdx.x, t = threadIdx.x;
  const float* xr = x + (size_t)row * 512;
  float v0 = xr[t], v1 = xr[t + 256];
  float s = block_sum256(v0 + v1, red);
  float mu = s * (1.f/512.f);
  float d0 = v0 - mu, d1 = v1 - mu;
  float sq = block_sum256(d0*d0 + d1*d1, red);
  float rstd = rsqrtf(sq * (1.f/512.f) + 1e-5f);
  out[(size_t)row*512 + t]       = f2b(d0*rstd*g[t]     + b[t]);
  out[(size_t)row*512 + t + 256] = f2b(d1*rstd*g[t+256] + b[t+256]);
}

// ---------------- final LN + mean over t -> feat bf16 [N][512] -------------
__global__ __launch_bounds__(256) void finalln_kernel(
    const float* __restrict__ h, const float* __restrict__ g,
    const float* __restrict__ b, bf16* __restrict__ feat)
{
  __shared__ float red[4];
  const int n = blockIdx.x, t = threadIdx.x;
  float a0 = 0.f, a1 = 0.f;
  for (int tt = 0; tt < 4; ++tt){
    const float* xr = h + ((size_t)n*4 + tt)*512;
    float v0 = xr[t], v1 = xr[t+256];
    float s = block_sum256(v0 + v1, red);
    float mu = s * (1.f/512.f);
    float d0 = v0 - mu, d1 = v1 - mu;
    float sq = block_sum256(d0*d0 + d1*d1, red);
    float rstd = rsqrtf(sq * (1.f/512.f) + 1e-5f);
    a0 += d0*rstd*g[t]     + b[t];
    a1 += d1*rstd*g[t+256] + b[t+256];
  }
  feat[(size_t)n*512 + t]       = f2b(a0 * 0.25f);
  feat[(size_t)n*512 + t + 256] = f2b(a1 * 0.25f);
}

// ---------------- causal depthwise conv (L=4,K=4) + silu ------------------
// xz: [N*4][2048], xi = cols 0..1023; d=1 reads time-flipped.
__global__ __launch_bounds__(256) void dwconv_kernel(
    const bf16* __restrict__ xz, const float* __restrict__ cw,
    const float* __restrict__ cb, int d, bf16* __restrict__ u)
{
  const int n = blockIdx.x;
  for (int c = threadIdx.x; c < 1024; c += 256){
    float in[4];
    #pragma unroll
    for (int t = 0; t < 4; ++t){
      int ts = d ? (3 - t) : t;
      in[t] = bfu(xz[((size_t)n*4 + ts)*2048 + c]);
    }
    float w0 = cw[c*4+0], w1 = cw[c*4+1], w2 = cw[c*4+2], w3 = cw[c*4+3];
    float bb = cb[c];
    float o[4];
    o[0] = in[0]*w3 + bb;
    o[1] = in[0]*w2 + in[1]*w3 + bb;
    o[2] = in[0]*w1 + in[1]*w2 + in[2]*w3 + bb;
    o[3] = in[0]*w0 + in[1]*w1 + in[2]*w2 + in[3]*w3 + bb;
    #pragma unroll
    for (int t = 0; t < 4; ++t){
      float v = o[t];
      float sv = v / (1.f + __expf(-v));   // silu
      u[((size_t)n*4 + t)*1024 + c] = f2b(sv);
    }
  }
}

// ---------------- selective scan (L=4, S=16) + D term ---------------------
__global__ __launch_bounds__(256) void scan_kernel(
    const float* __restrict__ dt, const bf16* __restrict__ u,
    const float* __restrict__ dbl, const float* __restrict__ Alog,
    const float* __restrict__ Dp, int d, float* __restrict__ ybuf)
{
  __shared__ float Bs[4][16], Cs[4][16];
  const int n = blockIdx.x, g = blockIdx.y, tid = threadIdx.x;
  if (tid < 128){
    int t = tid >> 5, j = tid & 31;
    float v = dbl[((size_t)n*4 + t)*64 + 32 + j];
    if (j < 16) Bs[t][j] = v; else Cs[t][j-16] = v;
  }
  __syncthreads();
  const int c = g*256 + tid;
  float A[16];
  #pragma unroll
  for (int s = 0; s < 16; ++s) A[s] = -__expf(Alog[(size_t)c*16 + s]);
  const float Dpc = Dp[c];
  float hs[16];
  #pragma unroll
  for (int s = 0; s < 16; ++s) hs[s] = 0.f;
  #pragma unroll
  for (int t = 0; t < 4; ++t){
    float dtv = dt[((size_t)n*4 + t)*1024 + c];
    float uv  = bfu(u[((size_t)n*4 + t)*1024 + c]);
    float du = dtv * uv;
    float y = 0.f;
    #pragma unroll
    for (int s = 0; s < 16; ++s){
      float dA = __expf(dtv * A[s]);
      hs[s] = dA * hs[s] + du * Bs[t][s];
      y += hs[s] * Cs[t][s];
    }
    float yd = y + uv * Dpc;
    int to = d ? (3 - t) : t;
    float* dst = &ybuf[((size_t)n*4 + to)*1024 + c];
    if (d == 0) *dst = yd; else *dst += yd;
  }
}

// ---------------- gate: gated = ybuf * silu(z) ----------------------------
__global__ __launch_bounds__(256) void gate_kernel(
    const float* __restrict__ ybuf, const bf16* __restrict__ xz,
    bf16* __restrict__ gated)
{
  const size_t total = (size_t)8192 * 1024;
  for (size_t i = (size_t)blockIdx.x*256 + threadIdx.x; i < total; i += (size_t)8192*256){
    size_t row = i >> 10; int c = (int)(i & 1023);
    float z = bfu(xz[row*2048 + 1024 + c]);
    float sv = z / (1.f + __expf(-z));
    gated[i] = f2b(ybuf[i] * sv);
  }
}

// ---------------- generic GEMM: out[m,n] = act(sum_k A[m,k]*W[n,k] + bias[n])
// A: bf16 or f32 (intermediates / dbl). W,bias: f32 (harness inputs).
// ACT: 0 none, 1 relu, 2 softplus.  OMODE: 0 bf16 store, 1 f32 store, 2 f32 +=
template<typename TA, int ACT, int OMODE>
__global__ __launch_bounds__(256) void gemm_kernel(
    const TA* __restrict__ A, int lda,
    const float* __restrict__ W, int ldw,
    const float* __restrict__ bias,
    void* __restrict__ outp, int ldo, int K)
{
  __shared__ float As[16][64];
  __shared__ float Ws[16][68];
  const int tid = threadIdx.x;
  const int m0 = blockIdx.x * 64, n0 = blockIdx.y * 64;
  const int lr = tid >> 2, lk = (tid & 3) << 2;
  const int tx = tid & 15, ty = tid >> 4;
  float acc[4][4] = {{0.f}};
  const TA*    Aptr = A + (size_t)(m0 + lr) * lda + lk;
  const float* Wptr = W + (size_t)(n0 + lr) * ldw + lk;
  for (int kt = 0; kt < K; kt += 16){
    float4 av = load4(Aptr + kt);
    float4 wv = load4(Wptr + kt);
    __syncthreads();
    As[lk+0][lr] = av.x; As[lk+1][lr] = av.y;
    As[lk+2][lr] = av.z; As[lk+3][lr] = av.w;
    Ws[lk+0][lr] = wv.x; Ws[lk+1][lr] = wv.y;
    Ws[lk+2][lr] = wv.z; Ws[lk+3][lr] = wv.w;
    __syncthreads();
    #pragma unroll
    for (int kk = 0; kk < 16; ++kk){
      float4 a4 = *reinterpret_cast<const float4*>(&As[kk][ty << 2]);
      float4 w4 = *reinterpret_cast<const float4*>(&Ws[kk][tx << 2]);
      acc[0][0] += a4.x*w4.x; acc[0][1] += a4.x*w4.y; acc[0][2] += a4.x*w4.z; acc[0][3] += a4.x*w4.w;
      acc[1][0] += a4.y*w4.x; acc[1][1] += a4.y*w4.y; acc[1][2] += a4.y*w4.z; acc[1][3] += a4.y*w4.w;
      acc[2][0] += a4.z*w4.x; acc[2][1] += a4.z*w4.y; acc[2][2] += a4.z*w4.z; acc[2][3] += a4.z*w4.w;
      acc[3][0] += a4.w*w4.x; acc[3][1] += a4.w*w4.y; acc[3][2] += a4.w*w4.z; acc[3][3] += a4.w*w4.w;
    }
  }
  const int mbase = m0 + (ty << 2), nbase = n0 + (tx << 2);
  float bv[4] = {0.f,0.f,0.f,0.f};
  if (bias){
    #pragma unroll
    for (int j = 0; j < 4; ++j) bv[j] = bias[nbase + j];
  }
  #pragma unroll
  for (int i = 0; i < 4; ++i){
    #pragma unroll
    for (int j = 0; j < 4; ++j){
      float v = acc[i][j] + bv[j];
      if (ACT == 1) v = fmaxf(v, 0.f);
      if (ACT == 2) v = (v > 20.f) ? v : log1pf(__expf(v));
      size_t oi = (size_t)(mbase + i) * ldo + (nbase + j);
      if (OMODE == 0)      ((bf16*)outp)[oi] = f2b(v);
      else if (OMODE == 1) ((float*)outp)[oi] = v;
      else                 ((float*)outp)[oi] += v;
    }
  }
}

// ---------------- launch ---------------------------------------------------
extern "C" void kernel_launch(void* const* d_in, const int* in_sizes, int n_in,
                              void* d_out, int out_size, void* d_ws, size_t ws_size,
                              hipStream_t stream)
{
  const float* x_flat    = (const float*)d_in[0];
  const float* conv_a_w  = (const float*)d_in[1];
  const float* conv_p_w  = (const float*)d_in[2];
  const float* se_w1     = (const float*)d_in[3];
  const float* se_b1     = (const float*)d_in[4];
  const float* se_w2     = (const float*)d_in[5];
  const float* se_b2     = (const float*)d_in[6];
  const float* ln_g      = (const float*)d_in[7];
  const float* ln_b      = (const float*)d_in[8];
  const float* in_proj_w = (const float*)d_in[9];
  const float* conv_w    = (const float*)d_in[10];
  const float* conv_b    = (const float*)d_in[11];
  const float* x_proj_w  = (const float*)d_in[12];
  const float* dt_proj_w = (const float*)d_in[13];
  const float* dt_proj_b = (const float*)d_in[14];
  const float* A_log     = (const float*)d_in[15];
  const float* D_param   = (const float*)d_in[16];
  const float* out_proj_w= (const float*)d_in[17];
  const float* out_ln_g  = (const float*)d_in[18];
  const float* out_ln_b  = (const float*)d_in[19];
  const float* mlp_w1    = (const float*)d_in[20];
  const float* mlp_b1    = (const float*)d_in[21];
  const float* mlp_w2    = (const float*)d_in[22];
  const float* mlp_b2    = (const float*)d_in[23];

  char* ws = (char*)d_ws;
  // offsets (bytes), aligned
  const size_t OFF_H    = 0;                       // f32  8192*512   = 16.78MB
  const size_t OFF_HN   = OFF_H    + 16777216;     // bf16 8192*512   =  8.39MB
  const size_t OFF_XZ   = OFF_HN   + 8388608;      // bf16 8192*2048  = 33.55MB
  const size_t OFF_U    = OFF_XZ   + 33554432;     // bf16 8192*1024  = 16.78MB (also gated)
  const size_t OFF_DBL  = OFF_U    + 16777216;     // f32  8192*64    =  2.10MB
  const size_t OFF_DT   = OFF_DBL  + 2097152;      // f32  8192*1024  = 33.55MB
  const size_t OFF_YB   = OFF_DT   + 33554432;     // f32  8192*1024  = 33.55MB
  // total ~145MB; feat overlays HN, z1 overlays XZ (dead by then)

  float* h    = (float*)(ws + OFF_H);
  bf16*  hn   = (bf16*) (ws + OFF_HN);
  bf16*  xz   = (bf16*) (ws + OFF_XZ);
  bf16*  u    = (bf16*) (ws + OFF_U);
  float* dbl  = (float*)(ws + OFF_DBL);
  float* dt   = (float*)(ws + OFF_DT);
  float* ybuf = (float*)(ws + OFF_YB);
  bf16*  feat = (bf16*) (ws + OFF_HN);   // overlay
  bf16*  z1   = (bf16*) (ws + OFF_XZ);   // overlay
  float* outf = (float*)d_out;

  stem_kernel<<<2048, 256, 0, stream>>>(x_flat, conv_a_w, conv_p_w,
                                        se_w1, se_b1, se_w2, se_b2, h);

  for (int l = 0; l < 2; ++l){
    ln_kernel<<<8192, 256, 0, stream>>>(h, ln_g + l*512, ln_b + l*512, hn);
    gemm_kernel<bf16,0,0><<<dim3(128,32), 256, 0, stream>>>(
        hn, 512, in_proj_w + (size_t)l*2048*512, 512, nullptr, xz, 2048, 512);
    for (int d = 0; d < 2; ++d){
      int ld = l*2 + d;
      dwconv_kernel<<<2048, 256, 0, stream>>>(
          xz, conv_w + (size_t)ld*4096, conv_b + (size_t)ld*1024, d, u);
      gemm_kernel<bf16,0,1><<<dim3(128,1), 256, 0, stream>>>(
          u, 1024, x_proj_w + (size_t)ld*64*1024, 1024, nullptr, dbl, 64, 1024);
      gemm_kernel<float,2,1><<<dim3(128,16), 256, 0, stream>>>(
          dbl, 64, dt_proj_w + (size_t)ld*1024*32, 32, dt_proj_b + (size_t)ld*1024,
          dt, 1024, 32);
      scan_kernel<<<dim3(2048,4), 256, 0, stream>>>(
          dt, u, dbl, A_log + (size_t)ld*16384, D_param + (size_t)ld*1024, d, ybuf);
    }
    gate_kernel<<<8192, 256, 0, stream>>>(ybuf, xz, u /* gated overlays u */);
    gemm_kernel<bf16,0,2><<<dim3(128,8), 256, 0, stream>>>(
        u, 1024, out_proj_w + (size_t)l*512*1024, 1024, nullptr, h, 512, 1024);
  }

  finalln_kernel<<<2048, 256, 0, stream>>>(h, out_ln_g, out_ln_b, feat);
  gemm_kernel<bf16,1,0><<<dim3(32,64), 256, 0, stream>>>(
      feat, 512, mlp_w1, 512, mlp_b1, z1, 4096, 512);
  gemm_kernel<bf16,1,1><<<dim3(32,64), 256, 0, stream>>>(
      z1, 4096, mlp_w2, 4096, mlp_b2, outf, 4096, 4096);
}

// Round 3
// 1314.566 us; speedup vs baseline: 2.0708x; 2.0708x over previous
//
#include <hip/hip_runtime.h>
#include <hip/hip_bf16.h>

typedef __hip_bfloat16 bf16;
typedef __attribute__((ext_vector_type(8))) short s16x8;
typedef __attribute__((ext_vector_type(4))) float f32x4;

__device__ __forceinline__ float u2f(unsigned short u){
  union { unsigned int i; float f; } v; v.i = ((unsigned int)u) << 16; return v.f;
}
__device__ __forceinline__ float bfu(bf16 x){ return __bfloat162float(x); }
__device__ __forceinline__ bf16  f2b(float x){ return __float2bfloat16(x); }

__device__ __forceinline__ float4 load4(const bf16* p){
  ushort4 v = *reinterpret_cast<const ushort4*>(p);
  return make_float4(u2f(v.x), u2f(v.y), u2f(v.z), u2f(v.w));
}
__device__ __forceinline__ float4 load4(const float* p){
  return *reinterpret_cast<const float4*>(p);
}

__device__ __forceinline__ void gload16(const void* g, void* l){
  __builtin_amdgcn_global_load_lds(
      (const __attribute__((address_space(1))) void*)g,
      (__attribute__((address_space(3))) void*)l, 16, 0, 0);
}

// ---------------- block reduction (256 threads) ----------------
__device__ __forceinline__ float block_sum256(float v, float* red){
  #pragma unroll
  for (int o = 32; o > 0; o >>= 1) v += __shfl_down(v, o, 64);
  int lane = threadIdx.x & 63, wid = threadIdx.x >> 6;
  if (lane == 0) red[wid] = v;
  __syncthreads();
  float r = red[0] + red[1] + red[2] + red[3];
  __syncthreads();
  return r;
}

// ---------------- fp32 -> bf16 weight conversion (vectorized) --------------
__global__ __launch_bounds__(256) void f2b4_kernel(
    const float4* __restrict__ in, ushort4* __restrict__ out, int n4)
{
  int stride = gridDim.x * 256;
  for (int i = blockIdx.x*256 + threadIdx.x; i < n4; i += stride){
    float4 v = in[i];
    ushort4 o;
    o.x = __bfloat16_as_ushort(f2b(v.x));
    o.y = __bfloat16_as_ushort(f2b(v.y));
    o.z = __bfloat16_as_ushort(f2b(v.z));
    o.w = __bfloat16_as_ushort(f2b(v.w));
    out[i] = o;
  }
}

// ---------------- MFMA GEMM: out[m,n] = act(sum_k A[m,k]*W[n,k] + bias[n])
// A,W bf16 row-major (leading dim = K). 128x128 tile, BK=64, 4 waves.
// ACT: 0 none, 1 relu. OMODE: 0 bf16 store, 1 f32 store, 2 f32 +=.
template<int ACT, int OMODE, bool HASBIAS>
__global__ __launch_bounds__(256) void mgemm_kernel(
    const bf16* __restrict__ A, const bf16* __restrict__ W,
    const float* __restrict__ bias, void* __restrict__ outp,
    int K, int ldo)
{
  __shared__ char lsA[16384];
  __shared__ char lsB[16384];
  const int tid = threadIdx.x;
  const int w = tid >> 6, l = tid & 63;
  const int m0 = blockIdx.x * 128, n0 = blockIdx.y * 128;
  const int wr = w >> 1, wc = w & 1;          // wave sub-tile origin (wr*64, wc*64)
  const size_t ldb = (size_t)K * 2;           // row stride in bytes
  const char* Ab = (const char*)A + (size_t)m0 * ldb;
  const char* Wb = (const char*)W + (size_t)n0 * ldb;

  // staging geometry: chunk i covers LDS rows (i*4+w)*8 + (l>>3)
  const int srow = l >> 3;                     // row-within-8 = row&7
  const int scb  = ((l & 7) ^ srow) << 4;      // swizzled global col-byte

  // fragment geometry
  const int fr = l & 15;                       // fragment row (A/W row within 16)
  const int fg = l >> 4;                       // k-group
  const int fsw = (fr & 7) << 4;               // read-side swizzle

  f32x4 acc[4][4];
  #pragma unroll
  for (int m = 0; m < 4; ++m)
    #pragma unroll
    for (int n = 0; n < 4; ++n) acc[m][n] = (f32x4){0.f,0.f,0.f,0.f};

  const int nk = K >> 6;
  for (int kt = 0; kt < nk; ++kt){
    const char* As = Ab + (size_t)kt * 128;
    const char* Ws = Wb + (size_t)kt * 128;
    #pragma unroll
    for (int i = 0; i < 4; ++i){
      int row = (i*4 + w)*8 + srow;
      gload16(As + (size_t)row*ldb + scb, &lsA[(i*4 + w)*1024]);
    }
    #pragma unroll
    for (int i = 0; i < 4; ++i){
      int row = (i*4 + w)*8 + srow;
      gload16(Ws + (size_t)row*ldb + scb, &lsB[(i*4 + w)*1024]);
    }
    __syncthreads();   // drains vmcnt -> tile ready

    s16x8 af[4][2], bfr[4][2];
    #pragma unroll
    for (int m = 0; m < 4; ++m){
      int row = wr*64 + m*16 + fr;
      af[m][0] = *(const s16x8*)&lsA[row*128 + (( 0 + fg*16) ^ fsw)];
      af[m][1] = *(const s16x8*)&lsA[row*128 + ((64 + fg*16) ^ fsw)];
    }
    #pragma unroll
    for (int n = 0; n < 4; ++n){
      int row = wc*64 + n*16 + fr;
      bfr[n][0] = *(const s16x8*)&lsB[row*128 + (( 0 + fg*16) ^ fsw)];
      bfr[n][1] = *(const s16x8*)&lsB[row*128 + ((64 + fg*16) ^ fsw)];
    }
    #pragma unroll
    for (int m = 0; m < 4; ++m)
      #pragma unroll
      for (int n = 0; n < 4; ++n){
        acc[m][n] = __builtin_amdgcn_mfma_f32_16x16x32_bf16(af[m][0], bfr[n][0], acc[m][n], 0, 0, 0);
        acc[m][n] = __builtin_amdgcn_mfma_f32_16x16x32_bf16(af[m][1], bfr[n][1], acc[m][n], 0, 0, 0);
      }
    __syncthreads();   // all reads done before next stage overwrites
  }

  // epilogue: C/D layout col = lane&15, row = (lane>>4)*4 + reg
  const int orow0 = m0 + wr*64, ocol0 = n0 + wc*64;
  #pragma unroll
  for (int n = 0; n < 4; ++n){
    int col = ocol0 + n*16 + fr;
    float bv = HASBIAS ? bias[col] : 0.f;
    #pragma unroll
    for (int m = 0; m < 4; ++m){
      int rbase = orow0 + m*16 + fg*4;
      #pragma unroll
      for (int r = 0; r < 4; ++r){
        float v = acc[m][n][r] + bv;
        if (ACT == 1) v = fmaxf(v, 0.f);
        size_t oi = (size_t)(rbase + r) * ldo + col;
        if (OMODE == 0)      ((bf16*)outp)[oi] = f2b(v);
        else if (OMODE == 1) ((float*)outp)[oi] = v;
        else                 ((float*)outp)[oi] += v;
      }
    }
  }
}

// ---------------- stem: conv_a + pool/conv_p + SE -> h (f32, [N][4][512]) ----
__global__ __launch_bounds__(256) void stem_kernel(
    const float* __restrict__ x_flat, const float* __restrict__ caw,
    const float* __restrict__ cpw,
    const float* __restrict__ sw1, const float* __restrict__ sb1,
    const float* __restrict__ sw2, const float* __restrict__ sb2,
    float* __restrict__ hout)
{
  __shared__ float xs[512][8];
  __shared__ float ps[512][4];
  __shared__ float ys[512][4];
  __shared__ float yms[512];
  __shared__ float s1s[32];
  const int n = blockIdx.x, tid = threadIdx.x;
  const float* xr = x_flat + (size_t)n * 3584;
  for (int i = tid; i < 3584; i += 256) xs[i / 7][i % 7] = xr[i];
  __syncthreads();
  for (int i = tid; i < 2048; i += 256){
    int c = i >> 2, t = i & 3, st = 2 * t - 1;
    float m = -1e30f;
    #pragma unroll
    for (int k = 0; k < 3; ++k){ int p = st + k; if (p >= 0 && p < 7) m = fmaxf(m, xs[c][p]); }
    ps[c][t] = m;
  }
  __syncthreads();
  {
    const int o = tid;
    float a0=0.f, a1=0.f, a2=0.f, a3=0.f;
    const float* wr = caw + (size_t)o * 1536;
    for (int i = 0; i < 512; ++i){
      float w0 = wr[i*3], w1 = wr[i*3+1], w2 = wr[i*3+2];
      const float* xi = xs[i];
      a0 += xi[0]*w1 + xi[1]*w2;
      a1 += xi[1]*w0 + xi[2]*w1 + xi[3]*w2;
      a2 += xi[3]*w0 + xi[4]*w1 + xi[5]*w2;
      a3 += xi[5]*w0 + xi[6]*w1;
    }
    ys[o][0]=fmaxf(a0,0.f); ys[o][1]=fmaxf(a1,0.f); ys[o][2]=fmaxf(a2,0.f); ys[o][3]=fmaxf(a3,0.f);
  }
  {
    const int o = tid;
    float a[4] = {0.f,0.f,0.f,0.f};
    const float* wr = cpw + (size_t)o * 512;
    for (int i = 0; i < 512; ++i){
      float w = wr[i];
      a[0]+=w*ps[i][0]; a[1]+=w*ps[i][1]; a[2]+=w*ps[i][2]; a[3]+=w*ps[i][3];
    }
    #pragma unroll
    for (int t = 0; t < 4; ++t) ys[256+o][t] = fmaxf(a[t],0.f);
  }
  __syncthreads();
  for (int c = tid; c < 512; c += 256)
    yms[c] = 0.25f * (ys[c][0]+ys[c][1]+ys[c][2]+ys[c][3]);
  __syncthreads();
  if (tid < 32){
    float a = sb1[tid];
    const float* wr = sw1 + (size_t)tid * 512;
    for (int i = 0; i < 512; ++i) a += wr[i] * yms[i];
    s1s[tid] = fmaxf(a, 0.f);
  }
  __syncthreads();
  for (int c = tid; c < 512; c += 256){
    float a = sb2[c];
    const float* wr = sw2 + (size_t)c * 32;
    #pragma unroll
    for (int j = 0; j < 32; ++j) a += wr[j] * s1s[j];
    float s = 1.f / (1.f + __expf(-a));
    #pragma unroll
    for (int t = 0; t < 4; ++t)
      hout[((size_t)n*4 + t)*512 + c] = ys[c][t] * s;
  }
}

// ---------------- layernorm rows of 512: f32 in -> bf16 out ----------------
__global__ __launch_bounds__(256) void ln_kernel(
    const float* __restrict__ x, const float* __restrict__ g,
    const float* __restrict__ b, bf16* __restrict__ out)
{
  __shared__ float red[4];
  const int row = blockIdx.x, t = threadIdx.x;
  const float* xr = x + (size_t)row * 512;
  float v0 = xr[t], v1 = xr[t + 256];
  float s = block_sum256(v0 + v1, red);
  float mu = s * (1.f/512.f);
  float d0 = v0 - mu, d1 = v1 - mu;
  float sq = block_sum256(d0*d0 + d1*d1, red);
  float rstd = rsqrtf(sq * (1.f/512.f) + 1e-5f);
  out[(size_t)row*512 + t]       = f2b(d0*rstd*g[t]     + b[t]);
  out[(size_t)row*512 + t + 256] = f2b(d1*rstd*g[t+256] + b[t+256]);
}

// ---------------- final LN + mean over t -> feat bf16 [N][512] -------------
__global__ __launch_bounds__(256) void finalln_kernel(
    const float* __restrict__ h, const float* __restrict__ g,
    const float* __restrict__ b, bf16* __restrict__ feat)
{
  __shared__ float red[4];
  const int n = blockIdx.x, t = threadIdx.x;
  float a0 = 0.f, a1 = 0.f;
  for (int tt = 0; tt < 4; ++tt){
    const float* xr = h + ((size_t)n*4 + tt)*512;
    float v0 = xr[t], v1 = xr[t+256];
    float s = block_sum256(v0 + v1, red);
    float mu = s * (1.f/512.f);
    float d0 = v0 - mu, d1 = v1 - mu;
    float sq = block_sum256(d0*d0 + d1*d1, red);
    float rstd = rsqrtf(sq * (1.f/512.f) + 1e-5f);
    a0 += d0*rstd*g[t]     + b[t];
    a1 += d1*rstd*g[t+256] + b[t+256];
  }
  feat[(size_t)n*512 + t]       = f2b(a0 * 0.25f);
  feat[(size_t)n*512 + t + 256] = f2b(a1 * 0.25f);
}

// ---------------- causal depthwise conv (L=4,K=4) + silu ------------------
__global__ __launch_bounds__(256) void dwconv_kernel(
    const bf16* __restrict__ xz, const float* __restrict__ cw,
    const float* __restrict__ cb, int d, bf16* __restrict__ u)
{
  const int n = blockIdx.x;
  for (int c = threadIdx.x; c < 1024; c += 256){
    float in[4];
    #pragma unroll
    for (int t = 0; t < 4; ++t){
      int ts = d ? (3 - t) : t;
      in[t] = bfu(xz[((size_t)n*4 + ts)*2048 + c]);
    }
    float w0 = cw[c*4+0], w1 = cw[c*4+1], w2 = cw[c*4+2], w3 = cw[c*4+3];
    float bb = cb[c];
    float o[4];
    o[0] = in[0]*w3 + bb;
    o[1] = in[0]*w2 + in[1]*w3 + bb;
    o[2] = in[0]*w1 + in[1]*w2 + in[2]*w3 + bb;
    o[3] = in[0]*w0 + in[1]*w1 + in[2]*w2 + in[3]*w3 + bb;
    #pragma unroll
    for (int t = 0; t < 4; ++t){
      float v = o[t];
      float sv = v / (1.f + __expf(-v));
      u[((size_t)n*4 + t)*1024 + c] = f2b(sv);
    }
  }
}

// ---------------- selective scan (L=4, S=16) + D term ---------------------
__global__ __launch_bounds__(256) void scan_kernel(
    const float* __restrict__ dt, const bf16* __restrict__ u,
    const float* __restrict__ dbl, const float* __restrict__ Alog,
    const float* __restrict__ Dp, int d, float* __restrict__ ybuf)
{
  __shared__ float Bs[4][16], Cs[4][16];
  const int n = blockIdx.x, g = blockIdx.y, tid = threadIdx.x;
  if (tid < 128){
    int t = tid >> 5, j = tid & 31;
    float v = dbl[((size_t)n*4 + t)*64 + 32 + j];
    if (j < 16) Bs[t][j] = v; else Cs[t][j-16] = v;
  }
  __syncthreads();
  const int c = g*256 + tid;
  float A[16];
  #pragma unroll
  for (int s = 0; s < 16; ++s) A[s] = -__expf(Alog[(size_t)c*16 + s]);
  const float Dpc = Dp[c];
  float hs[16];
  #pragma unroll
  for (int s = 0; s < 16; ++s) hs[s] = 0.f;
  #pragma unroll
  for (int t = 0; t < 4; ++t){
    float dtv = dt[((size_t)n*4 + t)*1024 + c];
    float uv  = bfu(u[((size_t)n*4 + t)*1024 + c]);
    float du = dtv * uv;
    float y = 0.f;
    #pragma unroll
    for (int s = 0; s < 16; ++s){
      float dA = __expf(dtv * A[s]);
      hs[s] = dA * hs[s] + du * Bs[t][s];
      y += hs[s] * Cs[t][s];
    }
    float yd = y + uv * Dpc;
    int to = d ? (3 - t) : t;
    float* dst = &ybuf[((size_t)n*4 + to)*1024 + c];
    if (d == 0) *dst = yd; else *dst += yd;
  }
}

// ---------------- gate: gated = ybuf * silu(z) ----------------------------
__global__ __launch_bounds__(256) void gate_kernel(
    const float* __restrict__ ybuf, const bf16* __restrict__ xz,
    bf16* __restrict__ gated)
{
  const size_t total = (size_t)8192 * 1024;
  for (size_t i = (size_t)blockIdx.x*256 + threadIdx.x; i < total; i += (size_t)8192*256){
    size_t row = i >> 10; int c = (int)(i & 1023);
    float z = bfu(xz[row*2048 + 1024 + c]);
    float sv = z / (1.f + __expf(-z));
    gated[i] = f2b(ybuf[i] * sv);
  }
}

// ---------------- naive fp32 GEMM (small shapes: x_proj, dt_proj) ----------
// ACT: 0 none, 2 softplus. OMODE: 1 f32 store.
template<typename TA, int ACT, int OMODE>
__global__ __launch_bounds__(256) void gemm_kernel(
    const TA* __restrict__ A, int lda,
    const float* __restrict__ W, int ldw,
    const float* __restrict__ bias,
    void* __restrict__ outp, int ldo, int K)
{
  __shared__ float As[16][64];
  __shared__ float Ws[16][68];
  const int tid = threadIdx.x;
  const int m0 = blockIdx.x * 64, n0 = blockIdx.y * 64;
  const int lr = tid >> 2, lk = (tid & 3) << 2;
  const int tx = tid & 15, ty = tid >> 4;
  float acc[4][4] = {{0.f}};
  const TA*    Aptr = A + (size_t)(m0 + lr) * lda + lk;
  const float* Wptr = W + (size_t)(n0 + lr) * ldw + lk;
  for (int kt = 0; kt < K; kt += 16){
    float4 av = load4(Aptr + kt);
    float4 wv = load4(Wptr + kt);
    __syncthreads();
    As[lk+0][lr] = av.x; As[lk+1][lr] = av.y;
    As[lk+2][lr] = av.z; As[lk+3][lr] = av.w;
    Ws[lk+0][lr] = wv.x; Ws[lk+1][lr] = wv.y;
    Ws[lk+2][lr] = wv.z; Ws[lk+3][lr] = wv.w;
    __syncthreads();
    #pragma unroll
    for (int kk = 0; kk < 16; ++kk){
      float4 a4 = *reinterpret_cast<const float4*>(&As[kk][ty << 2]);
      float4 w4 = *reinterpret_cast<const float4*>(&Ws[kk][tx << 2]);
      acc[0][0] += a4.x*w4.x; acc[0][1] += a4.x*w4.y; acc[0][2] += a4.x*w4.z; acc[0][3] += a4.x*w4.w;
      acc[1][0] += a4.y*w4.x; acc[1][1] += a4.y*w4.y; acc[1][2] += a4.y*w4.z; acc[1][3] += a4.y*w4.w;
      acc[2][0] += a4.z*w4.x; acc[2][1] += a4.z*w4.y; acc[2][2] += a4.z*w4.z; acc[2][3] += a4.z*w4.w;
      acc[3][0] += a4.w*w4.x; acc[3][1] += a4.w*w4.y; acc[3][2] += a4.w*w4.z; acc[3][3] += a4.w*w4.w;
    }
  }
  const int mbase = m0 + (ty << 2), nbase = n0 + (tx << 2);
  float bv[4] = {0.f,0.f,0.f,0.f};
  if (bias){
    #pragma unroll
    for (int j = 0; j < 4; ++j) bv[j] = bias[nbase + j];
  }
  #pragma unroll
  for (int i = 0; i < 4; ++i){
    #pragma unroll
    for (int j = 0; j < 4; ++j){
      float v = acc[i][j] + bv[j];
      if (ACT == 1) v = fmaxf(v, 0.f);
      if (ACT == 2) v = (v > 20.f) ? v : log1pf(__expf(v));
      size_t oi = (size_t)(mbase + i) * ldo + (nbase + j);
      if (OMODE == 0)      ((bf16*)outp)[oi] = f2b(v);
      else if (OMODE == 1) ((float*)outp)[oi] = v;
      else                 ((float*)outp)[oi] += v;
    }
  }
}

// ---------------- launch ---------------------------------------------------
extern "C" void kernel_launch(void* const* d_in, const int* in_sizes, int n_in,
                              void* d_out, int out_size, void* d_ws, size_t ws_size,
                              hipStream_t stream)
{
  const float* x_flat    = (const float*)d_in[0];
  const float* conv_a_w  = (const float*)d_in[1];
  const float* conv_p_w  = (const float*)d_in[2];
  const float* se_w1     = (const float*)d_in[3];
  const float* se_b1     = (const float*)d_in[4];
  const float* se_w2     = (const float*)d_in[5];
  const float* se_b2     = (const float*)d_in[6];
  const float* ln_g      = (const float*)d_in[7];
  const float* ln_b      = (const float*)d_in[8];
  const float* in_proj_w = (const float*)d_in[9];
  const float* conv_w    = (const float*)d_in[10];
  const float* conv_b    = (const float*)d_in[11];
  const float* x_proj_w  = (const float*)d_in[12];
  const float* dt_proj_w = (const float*)d_in[13];
  const float* dt_proj_b = (const float*)d_in[14];
  const float* A_log     = (const float*)d_in[15];
  const float* D_param   = (const float*)d_in[16];
  const float* out_proj_w= (const float*)d_in[17];
  const float* out_ln_g  = (const float*)d_in[18];
  const float* out_ln_b  = (const float*)d_in[19];
  const float* mlp_w1    = (const float*)d_in[20];
  const float* mlp_b1    = (const float*)d_in[21];
  const float* mlp_w2    = (const float*)d_in[22];
  const float* mlp_b2    = (const float*)d_in[23];

  char* ws = (char*)d_ws;
  const size_t OFF_H    = 0;                       // f32  8192*512   = 16.78MB
  const size_t OFF_HN   = OFF_H    + 16777216;     // bf16 8192*512
  const size_t OFF_XZ   = OFF_HN   + 8388608;      // bf16 8192*2048
  const size_t OFF_U    = OFF_XZ   + 33554432;     // bf16 8192*1024 (also gated)
  const size_t OFF_DBL  = OFF_U    + 16777216;     // f32  8192*64
  const size_t OFF_DT   = OFF_DBL  + 2097152;      // f32  8192*1024 (wb1 overlays later)
  const size_t OFF_YB   = OFF_DT   + 33554432;     // f32  8192*1024 (wb2 overlays later)
  const size_t OFF_WB   = OFF_YB   + 33554432;     // bf16 in_proj(2.1M el)+out_proj(1.05M el)
  // total = OFF_WB + 6291456 = ~151MB

  float* h    = (float*)(ws + OFF_H);
  bf16*  hn   = (bf16*) (ws + OFF_HN);
  bf16*  xz   = (bf16*) (ws + OFF_XZ);
  bf16*  u    = (bf16*) (ws + OFF_U);
  float* dbl  = (float*)(ws + OFF_DBL);
  float* dt   = (float*)(ws + OFF_DT);
  float* ybuf = (float*)(ws + OFF_YB);
  bf16*  feat = (bf16*) (ws + OFF_HN);   // overlay (h's LN output no longer needed)
  bf16*  z1   = (bf16*) (ws + OFF_XZ);   // overlay
  bf16*  wbi  = (bf16*) (ws + OFF_WB);               // 2*2048*512
  bf16*  wbo  = (bf16*) (ws + OFF_WB + 4194304);     // 2*512*1024
  bf16*  wb1  = (bf16*) (ws + OFF_DT);   // overlay, dt dead by MLP time
  bf16*  wb2  = (bf16*) (ws + OFF_YB);   // overlay, ybuf dead by MLP time
  float* outf = (float*)d_out;

  // convert layer weights (needed during layers) to bf16
  f2b4_kernel<<<2048, 256, 0, stream>>>((const float4*)in_proj_w,  (ushort4*)wbi, 524288);
  f2b4_kernel<<<1024, 256, 0, stream>>>((const float4*)out_proj_w, (ushort4*)wbo, 262144);

  stem_kernel<<<2048, 256, 0, stream>>>(x_flat, conv_a_w, conv_p_w,
                                        se_w1, se_b1, se_w2, se_b2, h);

  for (int l = 0; l < 2; ++l){
    ln_kernel<<<8192, 256, 0, stream>>>(h, ln_g + l*512, ln_b + l*512, hn);
    mgemm_kernel<0,0,false><<<dim3(64,16), 256, 0, stream>>>(
        hn, wbi + (size_t)l*2048*512, nullptr, xz, 512, 2048);
    for (int d = 0; d < 2; ++d){
      int ld = l*2 + d;
      dwconv_kernel<<<2048, 256, 0, stream>>>(
          xz, conv_w + (size_t)ld*4096, conv_b + (size_t)ld*1024, d, u);
      gemm_kernel<bf16,0,1><<<dim3(128,1), 256, 0, stream>>>(
          u, 1024, x_proj_w + (size_t)ld*64*1024, 1024, nullptr, dbl, 64, 1024);
      gemm_kernel<float,2,1><<<dim3(128,16), 256, 0, stream>>>(
          dbl, 64, dt_proj_w + (size_t)ld*1024*32, 32, dt_proj_b + (size_t)ld*1024,
          dt, 1024, 32);
      scan_kernel<<<dim3(2048,4), 256, 0, stream>>>(
          dt, u, dbl, A_log + (size_t)ld*16384, D_param + (size_t)ld*1024, d, ybuf);
    }
    gate_kernel<<<8192, 256, 0, stream>>>(ybuf, xz, u /* gated overlays u */);
    mgemm_kernel<0,2,false><<<dim3(64,4), 256, 0, stream>>>(
        u, wbo + (size_t)l*512*1024, nullptr, h, 1024, 512);
  }

  finalln_kernel<<<2048, 256, 0, stream>>>(h, out_ln_g, out_ln_b, feat);

  // convert MLP weights into dead dt/ybuf regions
  f2b4_kernel<<<1024, 256, 0, stream>>>((const float4*)mlp_w1, (ushort4*)wb1, 524288);
  f2b4_kernel<<<2048, 256, 0, stream>>>((const float4*)mlp_w2, (ushort4*)wb2, 4194304);

  mgemm_kernel<1,0,true><<<dim3(16,32), 256, 0, stream>>>(
      feat, wb1, mlp_b1, z1, 512, 4096);
  mgemm_kernel<1,1,true><<<dim3(16,32), 256, 0, stream>>>(
      z1, wb2, mlp_b2, outf, 4096, 4096);
}

// Round 4
// 937.102 us; speedup vs baseline: 2.9049x; 1.4028x over previous
//
#include <hip/hip_runtime.h>
#include <hip/hip_bf16.h>

typedef __hip_bfloat16 bf16;
typedef __attribute__((ext_vector_type(8))) short s16x8;
typedef __attribute__((ext_vector_type(4))) float f32x4;

__device__ __forceinline__ float u2f(unsigned short u){
  union { unsigned int i; float f; } v; v.i = ((unsigned int)u) << 16; return v.f;
}
__device__ __forceinline__ float bfu(bf16 x){ return __bfloat162float(x); }
__device__ __forceinline__ bf16  f2b(float x){ return __float2bfloat16(x); }

__device__ __forceinline__ float4 load4(const bf16* p){
  ushort4 v = *reinterpret_cast<const ushort4*>(p);
  return make_float4(u2f(v.x), u2f(v.y), u2f(v.z), u2f(v.w));
}
__device__ __forceinline__ float4 load4(const float* p){
  return *reinterpret_cast<const float4*>(p);
}

__device__ __forceinline__ void gload16(const void* g, void* l){
  __builtin_amdgcn_global_load_lds(
      (const __attribute__((address_space(1))) void*)g,
      (__attribute__((address_space(3))) void*)l, 16, 0, 0);
}

// ---------------- block reduction (256 threads) ----------------
__device__ __forceinline__ float block_sum256(float v, float* red){
  #pragma unroll
  for (int o = 32; o > 0; o >>= 1) v += __shfl_down(v, o, 64);
  int lane = threadIdx.x & 63, wid = threadIdx.x >> 6;
  if (lane == 0) red[wid] = v;
  __syncthreads();
  float r = red[0] + red[1] + red[2] + red[3];
  __syncthreads();
  return r;
}

// ---------------- fp32 -> bf16 weight conversion (vectorized) --------------
__global__ __launch_bounds__(256) void f2b4_kernel(
    const float4* __restrict__ in, ushort4* __restrict__ out, int n4)
{
  int stride = gridDim.x * 256;
  for (int i = blockIdx.x*256 + threadIdx.x; i < n4; i += stride){
    float4 v = in[i];
    ushort4 o;
    o.x = __bfloat16_as_ushort(f2b(v.x));
    o.y = __bfloat16_as_ushort(f2b(v.y));
    o.z = __bfloat16_as_ushort(f2b(v.z));
    o.w = __bfloat16_as_ushort(f2b(v.w));
    out[i] = o;
  }
}

// ---------------- MFMA GEMM: out[m,n] = act(sum_k A[m,k]*W[n,k] + bias[n])
// A,W bf16 row-major (leading dim = K). 128x128 tile, BK=64, 4 waves.
// ACT: 0 none, 1 relu. OMODE: 0 bf16 store, 1 f32 store, 2 f32 +=.
template<int ACT, int OMODE, bool HASBIAS>
__global__ __launch_bounds__(256) void mgemm_kernel(
    const bf16* __restrict__ A, const bf16* __restrict__ W,
    const float* __restrict__ bias, void* __restrict__ outp,
    int K, int ldo)
{
  __shared__ char lsA[16384];
  __shared__ char lsB[16384];
  const int tid = threadIdx.x;
  const int w = tid >> 6, l = tid & 63;
  const int m0 = blockIdx.x * 128, n0 = blockIdx.y * 128;
  const int wr = w >> 1, wc = w & 1;          // wave sub-tile origin (wr*64, wc*64)
  const size_t ldb = (size_t)K * 2;           // row stride in bytes
  const char* Ab = (const char*)A + (size_t)m0 * ldb;
  const char* Wb = (const char*)W + (size_t)n0 * ldb;

  // staging geometry: chunk i covers LDS rows (i*4+w)*8 + (l>>3)
  const int srow = l >> 3;                     // row-within-8 = row&7
  const int scb  = ((l & 7) ^ srow) << 4;      // swizzled global col-byte

  // fragment geometry
  const int fr = l & 15;                       // fragment row (A/W row within 16)
  const int fg = l >> 4;                       // k-group
  const int fsw = (fr & 7) << 4;               // read-side swizzle

  f32x4 acc[4][4];
  #pragma unroll
  for (int m = 0; m < 4; ++m)
    #pragma unroll
    for (int n = 0; n < 4; ++n) acc[m][n] = (f32x4){0.f,0.f,0.f,0.f};

  const int nk = K >> 6;
  for (int kt = 0; kt < nk; ++kt){
    const char* As = Ab + (size_t)kt * 128;
    const char* Ws = Wb + (size_t)kt * 128;
    #pragma unroll
    for (int i = 0; i < 4; ++i){
      int row = (i*4 + w)*8 + srow;
      gload16(As + (size_t)row*ldb + scb, &lsA[(i*4 + w)*1024]);
    }
    #pragma unroll
    for (int i = 0; i < 4; ++i){
      int row = (i*4 + w)*8 + srow;
      gload16(Ws + (size_t)row*ldb + scb, &lsB[(i*4 + w)*1024]);
    }
    __syncthreads();   // drains vmcnt -> tile ready

    s16x8 af[4][2], bfr[4][2];
    #pragma unroll
    for (int m = 0; m < 4; ++m){
      int row = wr*64 + m*16 + fr;
      af[m][0] = *(const s16x8*)&lsA[row*128 + (( 0 + fg*16) ^ fsw)];
      af[m][1] = *(const s16x8*)&lsA[row*128 + ((64 + fg*16) ^ fsw)];
    }
    #pragma unroll
    for (int n = 0; n < 4; ++n){
      int row = wc*64 + n*16 + fr;
      bfr[n][0] = *(const s16x8*)&lsB[row*128 + (( 0 + fg*16) ^ fsw)];
      bfr[n][1] = *(const s16x8*)&lsB[row*128 + ((64 + fg*16) ^ fsw)];
    }
    #pragma unroll
    for (int m = 0; m < 4; ++m)
      #pragma unroll
      for (int n = 0; n < 4; ++n){
        acc[m][n] = __builtin_amdgcn_mfma_f32_16x16x32_bf16(af[m][0], bfr[n][0], acc[m][n], 0, 0, 0);
        acc[m][n] = __builtin_amdgcn_mfma_f32_16x16x32_bf16(af[m][1], bfr[n][1], acc[m][n], 0, 0, 0);
      }
    __syncthreads();   // all reads done before next stage overwrites
  }

  // epilogue: C/D layout col = lane&15, row = (lane>>4)*4 + reg
  const int orow0 = m0 + wr*64, ocol0 = n0 + wc*64;
  #pragma unroll
  for (int n = 0; n < 4; ++n){
    int col = ocol0 + n*16 + fr;
    float bv = HASBIAS ? bias[col] : 0.f;
    #pragma unroll
    for (int m = 0; m < 4; ++m){
      int rbase = orow0 + m*16 + fg*4;
      #pragma unroll
      for (int r = 0; r < 4; ++r){
        float v = acc[m][n][r] + bv;
        if (ACT == 1) v = fmaxf(v, 0.f);
        size_t oi = (size_t)(rbase + r) * ldo + col;
        if (OMODE == 0)      ((bf16*)outp)[oi] = f2b(v);
        else if (OMODE == 1) ((float*)outp)[oi] = v;
        else                 ((float*)outp)[oi] += v;
      }
    }
  }
}

// ---------------- stem im2col: x -> conv_a patches (bf16) + maxpool (bf16) --
// Aa[(n*4+t)][c*3+kk] = x[n][c][2t-1+kk] (0-pad). P[(n*4+t)][c] = maxpool3s2p1.
__global__ __launch_bounds__(256) void im2col_kernel(
    const float* __restrict__ x_flat, bf16* __restrict__ Aa, bf16* __restrict__ P)
{
  __shared__ float xs[512][8];
  const int n = blockIdx.x, tid = threadIdx.x;
  const float* xr = x_flat + (size_t)n * 3584;
  for (int i = tid; i < 3584; i += 256) xs[i / 7][i % 7] = xr[i];
  __syncthreads();
  bf16* Ar = Aa + (size_t)n * 4 * 1536;
  for (int i = tid; i < 6144; i += 256){
    int t = i / 1536, col = i - t*1536;
    int c = col / 3, kk = col - c*3;
    int p = 2*t - 1 + kk;
    float v = (p >= 0 && p < 7) ? xs[c][p] : 0.f;
    Ar[i] = f2b(v);
  }
  bf16* Pr = P + (size_t)n * 4 * 512;
  for (int i = tid; i < 2048; i += 256){
    int t = i >> 9, c = i & 511;
    int st = 2*t - 1;
    float m = -1e30f;
    #pragma unroll
    for (int k = 0; k < 3; ++k){ int p = st + k; if (p >= 0 && p < 7) m = fmaxf(m, xs[c][p]); }
    Pr[i] = f2b(m);
  }
}

// ---------------- SE: mean over t -> 2 matvecs -> sigmoid -> scale h in place
__global__ __launch_bounds__(256) void se_kernel(
    const float* __restrict__ sw1, const float* __restrict__ sb1,
    const float* __restrict__ sw2, const float* __restrict__ sb2,
    float* __restrict__ h)
{
  __shared__ float yms[512];
  __shared__ float s1s[32];
  const int n = blockIdx.x, tid = threadIdx.x;
  float* hb = h + (size_t)n * 2048;
  for (int c = tid; c < 512; c += 256)
    yms[c] = 0.25f * (hb[c] + hb[512+c] + hb[1024+c] + hb[1536+c]);
  __syncthreads();
  if (tid < 32){
    float a = sb1[tid];
    const float* wr = sw1 + (size_t)tid * 512;
    for (int i = 0; i < 512; ++i) a += wr[i] * yms[i];
    s1s[tid] = fmaxf(a, 0.f);
  }
  __syncthreads();
  for (int c = tid; c < 512; c += 256){
    float a = sb2[c];
    const float* wr = sw2 + (size_t)c * 32;
    #pragma unroll
    for (int j = 0; j < 32; ++j) a += wr[j] * s1s[j];
    float s = 1.f / (1.f + __expf(-a));
    #pragma unroll
    for (int t = 0; t < 4; ++t) hb[t*512 + c] *= s;
  }
}

// ---------------- layernorm rows of 512: f32 in -> bf16 out ----------------
__global__ __launch_bounds__(256) void ln_kernel(
    const float* __restrict__ x, const float* __restrict__ g,
    const float* __restrict__ b, bf16* __restrict__ out)
{
  __shared__ float red[4];
  const int row = blockIdx.x, t = threadIdx.x;
  const float* xr = x + (size_t)row * 512;
  float v0 = xr[t], v1 = xr[t + 256];
  float s = block_sum256(v0 + v1, red);
  float mu = s * (1.f/512.f);
  float d0 = v0 - mu, d1 = v1 - mu;
  float sq = block_sum256(d0*d0 + d1*d1, red);
  float rstd = rsqrtf(sq * (1.f/512.f) + 1e-5f);
  out[(size_t)row*512 + t]       = f2b(d0*rstd*g[t]     + b[t]);
  out[(size_t)row*512 + t + 256] = f2b(d1*rstd*g[t+256] + b[t+256]);
}

// ---------------- final LN + mean over t -> feat bf16 [N][512] -------------
__global__ __launch_bounds__(256) void finalln_kernel(
    const float* __restrict__ h, const float* __restrict__ g,
    const float* __restrict__ b, bf16* __restrict__ feat)
{
  __shared__ float red[4];
  const int n = blockIdx.x, t = threadIdx.x;
  float a0 = 0.f, a1 = 0.f;
  for (int tt = 0; tt < 4; ++tt){
    const float* xr = h + ((size_t)n*4 + tt)*512;
    float v0 = xr[t], v1 = xr[t+256];
    float s = block_sum256(v0 + v1, red);
    float mu = s * (1.f/512.f);
    float d0 = v0 - mu, d1 = v1 - mu;
    float sq = block_sum256(d0*d0 + d1*d1, red);
    float rstd = rsqrtf(sq * (1.f/512.f) + 1e-5f);
    a0 += d0*rstd*g[t]     + b[t];
    a1 += d1*rstd*g[t+256] + b[t+256];
  }
  feat[(size_t)n*512 + t]       = f2b(a0 * 0.25f);
  feat[(size_t)n*512 + t + 256] = f2b(a1 * 0.25f);
}

// ---------------- causal depthwise conv (L=4,K=4) + silu ------------------
__global__ __launch_bounds__(256) void dwconv_kernel(
    const bf16* __restrict__ xz, const float* __restrict__ cw,
    const float* __restrict__ cb, int d, bf16* __restrict__ u)
{
  const int n = blockIdx.x;
  for (int c = threadIdx.x; c < 1024; c += 256){
    float in[4];
    #pragma unroll
    for (int t = 0; t < 4; ++t){
      int ts = d ? (3 - t) : t;
      in[t] = bfu(xz[((size_t)n*4 + ts)*2048 + c]);
    }
    float w0 = cw[c*4+0], w1 = cw[c*4+1], w2 = cw[c*4+2], w3 = cw[c*4+3];
    float bb = cb[c];
    float o[4];
    o[0] = in[0]*w3 + bb;
    o[1] = in[0]*w2 + in[1]*w3 + bb;
    o[2] = in[0]*w1 + in[1]*w2 + in[2]*w3 + bb;
    o[3] = in[0]*w0 + in[1]*w1 + in[2]*w2 + in[3]*w3 + bb;
    #pragma unroll
    for (int t = 0; t < 4; ++t){
      float v = o[t];
      float sv = v / (1.f + __expf(-v));
      u[((size_t)n*4 + t)*1024 + c] = f2b(sv);
    }
  }
}

// ---------------- selective scan (L=4, S=16) + D term ---------------------
__global__ __launch_bounds__(256) void scan_kernel(
    const float* __restrict__ dt, const bf16* __restrict__ u,
    const float* __restrict__ dbl, const float* __restrict__ Alog,
    const float* __restrict__ Dp, int d, float* __restrict__ ybuf)
{
  __shared__ float Bs[4][16], Cs[4][16];
  const int n = blockIdx.x, g = blockIdx.y, tid = threadIdx.x;
  if (tid < 128){
    int t = tid >> 5, j = tid & 31;
    float v = dbl[((size_t)n*4 + t)*64 + 32 + j];
    if (j < 16) Bs[t][j] = v; else Cs[t][j-16] = v;
  }
  __syncthreads();
  const int c = g*256 + tid;
  float A[16];
  #pragma unroll
  for (int s = 0; s < 16; ++s) A[s] = -__expf(Alog[(size_t)c*16 + s]);
  const float Dpc = Dp[c];
  float hs[16];
  #pragma unroll
  for (int s = 0; s < 16; ++s) hs[s] = 0.f;
  #pragma unroll
  for (int t = 0; t < 4; ++t){
    float dtv = dt[((size_t)n*4 + t)*1024 + c];
    float uv  = bfu(u[((size_t)n*4 + t)*1024 + c]);
    float du = dtv * uv;
    float y = 0.f;
    #pragma unroll
    for (int s = 0; s < 16; ++s){
      float dA = __expf(dtv * A[s]);
      hs[s] = dA * hs[s] + du * Bs[t][s];
      y += hs[s] * Cs[t][s];
    }
    float yd = y + uv * Dpc;
    int to = d ? (3 - t) : t;
    float* dst = &ybuf[((size_t)n*4 + to)*1024 + c];
    if (d == 0) *dst = yd; else *dst += yd;
  }
}

// ---------------- gate: gated = ybuf * silu(z) ----------------------------
__global__ __launch_bounds__(256) void gate_kernel(
    const float* __restrict__ ybuf, const bf16* __restrict__ xz,
    bf16* __restrict__ gated)
{
  const size_t total = (size_t)8192 * 1024;
  for (size_t i = (size_t)blockIdx.x*256 + threadIdx.x; i < total; i += (size_t)8192*256){
    size_t row = i >> 10; int c = (int)(i & 1023);
    float z = bfu(xz[row*2048 + 1024 + c]);
    float sv = z / (1.f + __expf(-z));
    gated[i] = f2b(ybuf[i] * sv);
  }
}

// ---------------- naive fp32 GEMM (small shapes: x_proj, dt_proj) ----------
template<typename TA, int ACT, int OMODE>
__global__ __launch_bounds__(256) void gemm_kernel(
    const TA* __restrict__ A, int lda,
    const float* __restrict__ W, int ldw,
    const float* __restrict__ bias,
    void* __restrict__ outp, int ldo, int K)
{
  __shared__ float As[16][64];
  __shared__ float Ws[16][68];
  const int tid = threadIdx.x;
  const int m0 = blockIdx.x * 64, n0 = blockIdx.y * 64;
  const int lr = tid >> 2, lk = (tid & 3) << 2;
  const int tx = tid & 15, ty = tid >> 4;
  float acc[4][4] = {{0.f}};
  const TA*    Aptr = A + (size_t)(m0 + lr) * lda + lk;
  const float* Wptr = W + (size_t)(n0 + lr) * ldw + lk;
  for (int kt = 0; kt < K; kt += 16){
    float4 av = load4(Aptr + kt);
    float4 wv = load4(Wptr + kt);
    __syncthreads();
    As[lk+0][lr] = av.x; As[lk+1][lr] = av.y;
    As[lk+2][lr] = av.z; As[lk+3][lr] = av.w;
    Ws[lk+0][lr] = wv.x; Ws[lk+1][lr] = wv.y;
    Ws[lk+2][lr] = wv.z; Ws[lk+3][lr] = wv.w;
    __syncthreads();
    #pragma unroll
    for (int kk = 0; kk < 16; ++kk){
      float4 a4 = *reinterpret_cast<const float4*>(&As[kk][ty << 2]);
      float4 w4 = *reinterpret_cast<const float4*>(&Ws[kk][tx << 2]);
      acc[0][0] += a4.x*w4.x; acc[0][1] += a4.x*w4.y; acc[0][2] += a4.x*w4.z; acc[0][3] += a4.x*w4.w;
      acc[1][0] += a4.y*w4.x; acc[1][1] += a4.y*w4.y; acc[1][2] += a4.y*w4.z; acc[1][3] += a4.y*w4.w;
      acc[2][0] += a4.z*w4.x; acc[2][1] += a4.z*w4.y; acc[2][2] += a4.z*w4.z; acc[2][3] += a4.z*w4.w;
      acc[3][0] += a4.w*w4.x; acc[3][1] += a4.w*w4.y; acc[3][2] += a4.w*w4.z; acc[3][3] += a4.w*w4.w;
    }
  }
  const int mbase = m0 + (ty << 2), nbase = n0 + (tx << 2);
  float bv[4] = {0.f,0.f,0.f,0.f};
  if (bias){
    #pragma unroll
    for (int j = 0; j < 4; ++j) bv[j] = bias[nbase + j];
  }
  #pragma unroll
  for (int i = 0; i < 4; ++i){
    #pragma unroll
    for (int j = 0; j < 4; ++j){
      float v = acc[i][j] + bv[j];
      if (ACT == 1) v = fmaxf(v, 0.f);
      if (ACT == 2) v = (v > 20.f) ? v : log1pf(__expf(v));
      size_t oi = (size_t)(mbase + i) * ldo + (nbase + j);
      if (OMODE == 0)      ((bf16*)outp)[oi] = f2b(v);
      else if (OMODE == 1) ((float*)outp)[oi] = v;
      else                 ((float*)outp)[oi] += v;
    }
  }
}

// ---------------- launch ---------------------------------------------------
extern "C" void kernel_launch(void* const* d_in, const int* in_sizes, int n_in,
                              void* d_out, int out_size, void* d_ws, size_t ws_size,
                              hipStream_t stream)
{
  const float* x_flat    = (const float*)d_in[0];
  const float* conv_a_w  = (const float*)d_in[1];
  const float* conv_p_w  = (const float*)d_in[2];
  const float* se_w1     = (const float*)d_in[3];
  const float* se_b1     = (const float*)d_in[4];
  const float* se_w2     = (const float*)d_in[5];
  const float* se_b2     = (const float*)d_in[6];
  const float* ln_g      = (const float*)d_in[7];
  const float* ln_b      = (const float*)d_in[8];
  const float* in_proj_w = (const float*)d_in[9];
  const float* conv_w    = (const float*)d_in[10];
  const float* conv_b    = (const float*)d_in[11];
  const float* x_proj_w  = (const float*)d_in[12];
  const float* dt_proj_w = (const float*)d_in[13];
  const float* dt_proj_b = (const float*)d_in[14];
  const float* A_log     = (const float*)d_in[15];
  const float* D_param   = (const float*)d_in[16];
  const float* out_proj_w= (const float*)d_in[17];
  const float* out_ln_g  = (const float*)d_in[18];
  const float* out_ln_b  = (const float*)d_in[19];
  const float* mlp_w1    = (const float*)d_in[20];
  const float* mlp_b1    = (const float*)d_in[21];
  const float* mlp_w2    = (const float*)d_in[22];
  const float* mlp_b2    = (const float*)d_in[23];

  char* ws = (char*)d_ws;
  const size_t OFF_H    = 0;                       // f32  8192*512   = 16.78MB
  const size_t OFF_HN   = OFF_H    + 16777216;     // bf16 8192*512
  const size_t OFF_XZ   = OFF_HN   + 8388608;      // bf16 8192*2048
  const size_t OFF_U    = OFF_XZ   + 33554432;     // bf16 8192*1024 (also gated)
  const size_t OFF_DBL  = OFF_U    + 16777216;     // f32  8192*64
  const size_t OFF_DT   = OFF_DBL  + 2097152;      // f32  8192*1024 (Aa/wb1 overlay)
  const size_t OFF_YB   = OFF_DT   + 33554432;     // f32  8192*1024 (P+wa+wp/wb2 overlay)
  const size_t OFF_WB   = OFF_YB   + 33554432;     // bf16 in_proj+out_proj
  // total = OFF_WB + 6291456 = ~151MB

  float* h    = (float*)(ws + OFF_H);
  bf16*  hn   = (bf16*) (ws + OFF_HN);
  bf16*  xz   = (bf16*) (ws + OFF_XZ);
  bf16*  u    = (bf16*) (ws + OFF_U);
  float* dbl  = (float*)(ws + OFF_DBL);
  float* dt   = (float*)(ws + OFF_DT);
  float* ybuf = (float*)(ws + OFF_YB);
  bf16*  feat = (bf16*) (ws + OFF_HN);   // overlay
  bf16*  z1   = (bf16*) (ws + OFF_XZ);   // overlay
  bf16*  wbi  = (bf16*) (ws + OFF_WB);               // 2*2048*512
  bf16*  wbo  = (bf16*) (ws + OFF_WB + 4194304);     // 2*512*1024
  bf16*  wb1  = (bf16*) (ws + OFF_DT);   // overlay (MLP phase)
  bf16*  wb2  = (bf16*) (ws + OFF_YB);   // overlay (MLP phase)
  // stem-phase overlays (dt/ybuf dead during stem)
  bf16*  Aa   = (bf16*) (ws + OFF_DT);                        // 8192*1536*2 = 25.2MB
  bf16*  Pm   = (bf16*) (ws + OFF_YB);                        // 8192*512*2  =  8.4MB
  bf16*  wa   = (bf16*) (ws + OFF_YB + 8388608);              // 256*1536*2
  bf16*  wp   = (bf16*) (ws + OFF_YB + 8388608 + 786432);     // 256*512*2
  float* outf = (float*)d_out;

  // weight conversions
  f2b4_kernel<<<512,  256, 0, stream>>>((const float4*)conv_a_w,   (ushort4*)wa,  98304);
  f2b4_kernel<<<256,  256, 0, stream>>>((const float4*)conv_p_w,   (ushort4*)wp,  32768);
  f2b4_kernel<<<2048, 256, 0, stream>>>((const float4*)in_proj_w,  (ushort4*)wbi, 524288);
  f2b4_kernel<<<1024, 256, 0, stream>>>((const float4*)out_proj_w, (ushort4*)wbo, 262144);

  // stem: im2col + MFMA GEMMs + SE
  im2col_kernel<<<2048, 256, 0, stream>>>(x_flat, Aa, Pm);
  mgemm_kernel<1,1,false><<<dim3(64,2), 256, 0, stream>>>(
      Aa, wa, nullptr, h, 1536, 512);             // conv_a -> h cols 0..255
  mgemm_kernel<1,1,false><<<dim3(64,2), 256, 0, stream>>>(
      Pm, wp, nullptr, (float*)h + 256, 512, 512); // conv_p -> h cols 256..511
  se_kernel<<<2048, 256, 0, stream>>>(se_w1, se_b1, se_w2, se_b2, h);

  for (int l = 0; l < 2; ++l){
    ln_kernel<<<8192, 256, 0, stream>>>(h, ln_g + l*512, ln_b + l*512, hn);
    mgemm_kernel<0,0,false><<<dim3(64,16), 256, 0, stream>>>(
        hn, wbi + (size_t)l*2048*512, nullptr, xz, 512, 2048);
    for (int d = 0; d < 2; ++d){
      int ld = l*2 + d;
      dwconv_kernel<<<2048, 256, 0, stream>>>(
          xz, conv_w + (size_t)ld*4096, conv_b + (size_t)ld*1024, d, u);
      gemm_kernel<bf16,0,1><<<dim3(128,1), 256, 0, stream>>>(
          u, 1024, x_proj_w + (size_t)ld*64*1024, 1024, nullptr, dbl, 64, 1024);
      gemm_kernel<float,2,1><<<dim3(128,16), 256, 0, stream>>>(
          dbl, 64, dt_proj_w + (size_t)ld*1024*32, 32, dt_proj_b + (size_t)ld*1024,
          dt, 1024, 32);
      scan_kernel<<<dim3(2048,4), 256, 0, stream>>>(
          dt, u, dbl, A_log + (size_t)ld*16384, D_param + (size_t)ld*1024, d, ybuf);
    }
    gate_kernel<<<8192, 256, 0, stream>>>(ybuf, xz, u /* gated overlays u */);
    mgemm_kernel<0,2,false><<<dim3(64,4), 256, 0, stream>>>(
        u, wbo + (size_t)l*512*1024, nullptr, h, 1024, 512);
  }

  finalln_kernel<<<2048, 256, 0, stream>>>(h, out_ln_g, out_ln_b, feat);

  // convert MLP weights into dead dt/ybuf regions
  f2b4_kernel<<<1024, 256, 0, stream>>>((const float4*)mlp_w1, (ushort4*)wb1, 524288);
  f2b4_kernel<<<2048, 256, 0, stream>>>((const float4*)mlp_w2, (ushort4*)wb2, 4194304);

  mgemm_kernel<1,0,true><<<dim3(16,32), 256, 0, stream>>>(
      feat, wb1, mlp_b1, z1, 512, 4096);
  mgemm_kernel<1,1,true><<<dim3(16,32), 256, 0, stream>>>(
      z1, wb2, mlp_b2, outf, 4096, 4096);
}

// Round 5
// 806.161 us; speedup vs baseline: 3.3768x; 1.1624x over previous
//
#include <hip/hip_runtime.h>
#include <hip/hip_bf16.h>

typedef __hip_bfloat16 bf16;
typedef __attribute__((ext_vector_type(8))) short s16x8;
typedef __attribute__((ext_vector_type(4))) float f32x4;

__device__ __forceinline__ float u2f(unsigned short u){
  union { unsigned int i; float f; } v; v.i = ((unsigned int)u) << 16; return v.f;
}
__device__ __forceinline__ float bfu(bf16 x){ return __bfloat162float(x); }
__device__ __forceinline__ bf16  f2b(float x){ return __float2bfloat16(x); }

__device__ __forceinline__ void gload16(const void* g, void* l){
  __builtin_amdgcn_global_load_lds(
      (const __attribute__((address_space(1))) void*)g,
      (__attribute__((address_space(3))) void*)l, 16, 0, 0);
}

// ---------------- block reduction (256 threads) ----------------
__device__ __forceinline__ float block_sum256(float v, float* red){
  #pragma unroll
  for (int o = 32; o > 0; o >>= 1) v += __shfl_down(v, o, 64);
  int lane = threadIdx.x & 63, wid = threadIdx.x >> 6;
  if (lane == 0) red[wid] = v;
  __syncthreads();
  float r = red[0] + red[1] + red[2] + red[3];
  __syncthreads();
  return r;
}

// ---------------- fp32 -> bf16 weight conversion (vectorized) --------------
__global__ __launch_bounds__(256) void f2b4_kernel(
    const float4* __restrict__ in, ushort4* __restrict__ out, int n4)
{
  int stride = gridDim.x * 256;
  for (int i = blockIdx.x*256 + threadIdx.x; i < n4; i += stride){
    float4 v = in[i];
    ushort4 o;
    o.x = __bfloat16_as_ushort(f2b(v.x));
    o.y = __bfloat16_as_ushort(f2b(v.y));
    o.z = __bfloat16_as_ushort(f2b(v.z));
    o.w = __bfloat16_as_ushort(f2b(v.w));
    out[i] = o;
  }
}

// ---------------- x_proj weights: [4][64][1024] f32 -> [4][128][1024] bf16, 0-pad
__global__ __launch_bounds__(256) void xpw_pad_kernel(
    const float* __restrict__ xpw, bf16* __restrict__ out)
{
  int idx = blockIdx.x*256 + threadIdx.x;       // 4*128*1024 = 524288
  if (idx >= 524288) return;
  int g = idx >> 17, rc = idx & 131071, r = rc >> 10, c = rc & 1023;
  float v = (r < 64) ? xpw[((size_t)g*64 + r)*1024 + c] : 0.f;
  out[idx] = f2b(v);
}

// ---------------- MFMA GEMM: out[m,n] = act(sum_k A[m,k]*W[n,k] + bias[n])
// A,W bf16 row-major (leading dim = K). 128x128 tile, BK=64, 4 waves.
// Grid (m-tiles, n-tiles); TOTAL BLOCKS MUST BE %8==0 (XCD swizzle).
// ACT: 0 none, 1 relu. OMODE: 0 bf16 store, 1 f32 store, 2 f32 +=.
template<int ACT, int OMODE, bool HASBIAS>
__global__ __launch_bounds__(256) void mgemm_kernel(
    const bf16* __restrict__ A, const bf16* __restrict__ W,
    const float* __restrict__ bias, void* __restrict__ outp,
    int K, int ldo)
{
  __shared__ char lsA[16384];
  __shared__ char lsB[16384];
  const int tid = threadIdx.x;
  const int w = tid >> 6, l = tid & 63;
  // XCD-aware bijective swizzle (nwg % 8 == 0 for all call sites)
  const int nwg = gridDim.x * gridDim.y;
  const int lin = blockIdx.y * gridDim.x + blockIdx.x;
  const int cpx = nwg >> 3;
  const int swz = (lin & 7) * cpx + (lin >> 3);
  const int m0 = (swz % gridDim.x) * 128, n0 = (swz / gridDim.x) * 128;
  const int wr = w >> 1, wc = w & 1;          // wave sub-tile origin (wr*64, wc*64)
  const size_t ldb = (size_t)K * 2;           // row stride in bytes
  const char* Ab = (const char*)A + (size_t)m0 * ldb;
  const char* Wb = (const char*)W + (size_t)n0 * ldb;

  // staging geometry: chunk i covers LDS rows (i*4+w)*8 + (l>>3)
  const int srow = l >> 3;                     // row-within-8 = row&7
  const int scb  = ((l & 7) ^ srow) << 4;      // swizzled global col-byte

  // fragment geometry
  const int fr = l & 15;                       // fragment row (A/W row within 16)
  const int fg = l >> 4;                       // k-group
  const int fsw = (fr & 7) << 4;               // read-side swizzle

  f32x4 acc[4][4];
  #pragma unroll
  for (int m = 0; m < 4; ++m)
    #pragma unroll
    for (int n = 0; n < 4; ++n) acc[m][n] = (f32x4){0.f,0.f,0.f,0.f};

  const int nk = K >> 6;
  for (int kt = 0; kt < nk; ++kt){
    const char* As = Ab + (size_t)kt * 128;
    const char* Ws = Wb + (size_t)kt * 128;
    #pragma unroll
    for (int i = 0; i < 4; ++i){
      int row = (i*4 + w)*8 + srow;
      gload16(As + (size_t)row*ldb + scb, &lsA[(i*4 + w)*1024]);
    }
    #pragma unroll
    for (int i = 0; i < 4; ++i){
      int row = (i*4 + w)*8 + srow;
      gload16(Ws + (size_t)row*ldb + scb, &lsB[(i*4 + w)*1024]);
    }
    __syncthreads();   // drains vmcnt -> tile ready

    s16x8 af[4][2], bfr[4][2];
    #pragma unroll
    for (int m = 0; m < 4; ++m){
      int row = wr*64 + m*16 + fr;
      af[m][0] = *(const s16x8*)&lsA[row*128 + (( 0 + fg*16) ^ fsw)];
      af[m][1] = *(const s16x8*)&lsA[row*128 + ((64 + fg*16) ^ fsw)];
    }
    #pragma unroll
    for (int n = 0; n < 4; ++n){
      int row = wc*64 + n*16 + fr;
      bfr[n][0] = *(const s16x8*)&lsB[row*128 + (( 0 + fg*16) ^ fsw)];
      bfr[n][1] = *(const s16x8*)&lsB[row*128 + ((64 + fg*16) ^ fsw)];
    }
    #pragma unroll
    for (int m = 0; m < 4; ++m)
      #pragma unroll
      for (int n = 0; n < 4; ++n){
        acc[m][n] = __builtin_amdgcn_mfma_f32_16x16x32_bf16(af[m][0], bfr[n][0], acc[m][n], 0, 0, 0);
        acc[m][n] = __builtin_amdgcn_mfma_f32_16x16x32_bf16(af[m][1], bfr[n][1], acc[m][n], 0, 0, 0);
      }
    __syncthreads();   // all reads done before next stage overwrites
  }

  // epilogue: C/D layout col = lane&15, row = (lane>>4)*4 + reg
  const int orow0 = m0 + wr*64, ocol0 = n0 + wc*64;
  #pragma unroll
  for (int n = 0; n < 4; ++n){
    int col = ocol0 + n*16 + fr;
    float bv = HASBIAS ? bias[col] : 0.f;
    #pragma unroll
    for (int m = 0; m < 4; ++m){
      int rbase = orow0 + m*16 + fg*4;
      #pragma unroll
      for (int r = 0; r < 4; ++r){
        float v = acc[m][n][r] + bv;
        if (ACT == 1) v = fmaxf(v, 0.f);
        size_t oi = (size_t)(rbase + r) * ldo + col;
        if (OMODE == 0)      ((bf16*)outp)[oi] = f2b(v);
        else if (OMODE == 1) ((float*)outp)[oi] = v;
        else                 ((float*)outp)[oi] += v;
      }
    }
  }
}

// ---------------- stem im2col: x -> conv_a patches (bf16) + maxpool (bf16) --
__global__ __launch_bounds__(256) void im2col_kernel(
    const float* __restrict__ x_flat, bf16* __restrict__ Aa, bf16* __restrict__ P)
{
  __shared__ float xs[512][8];
  const int n = blockIdx.x, tid = threadIdx.x;
  const float* xr = x_flat + (size_t)n * 3584;
  for (int i = tid; i < 3584; i += 256) xs[i / 7][i % 7] = xr[i];
  __syncthreads();
  bf16* Ar = Aa + (size_t)n * 4 * 1536;
  for (int i = tid; i < 6144; i += 256){
    int t = i / 1536, col = i - t*1536;
    int c = col / 3, kk = col - c*3;
    int p = 2*t - 1 + kk;
    float v = (p >= 0 && p < 7) ? xs[c][p] : 0.f;
    Ar[i] = f2b(v);
  }
  bf16* Pr = P + (size_t)n * 4 * 512;
  for (int i = tid; i < 2048; i += 256){
    int t = i >> 9, c = i & 511;
    int st = 2*t - 1;
    float m = -1e30f;
    #pragma unroll
    for (int k = 0; k < 3; ++k){ int p = st + k; if (p >= 0 && p < 7) m = fmaxf(m, xs[c][p]); }
    Pr[i] = f2b(m);
  }
}

// ---------------- SE: mean over t -> 2 matvecs -> sigmoid -> scale h in place
__global__ __launch_bounds__(256) void se_kernel(
    const float* __restrict__ sw1, const float* __restrict__ sb1,
    const float* __restrict__ sw2, const float* __restrict__ sb2,
    float* __restrict__ h)
{
  __shared__ float yms[512];
  __shared__ float s1s[32];
  const int n = blockIdx.x, tid = threadIdx.x;
  float* hb = h + (size_t)n * 2048;
  for (int c = tid; c < 512; c += 256)
    yms[c] = 0.25f * (hb[c] + hb[512+c] + hb[1024+c] + hb[1536+c]);
  __syncthreads();
  {
    // 32 outputs x 8 lanes each (lanes of a group are consecutive -> same wave)
    int o = tid >> 3, sl = tid & 7;
    const float* wr = sw1 + (size_t)o * 512 + sl*64;
    const float* ym = yms + sl*64;
    float a = 0.f;
    #pragma unroll 16
    for (int i = 0; i < 64; ++i) a += wr[i] * ym[i];
    a += __shfl_down(a, 4, 8);
    a += __shfl_down(a, 2, 8);
    a += __shfl_down(a, 1, 8);
    if (sl == 0) s1s[o] = fmaxf(a + sb1[o], 0.f);
  }
  __syncthreads();
  for (int c = tid; c < 512; c += 256){
    float a = sb2[c];
    const float* wr = sw2 + (size_t)c * 32;
    #pragma unroll
    for (int j = 0; j < 32; ++j) a += wr[j] * s1s[j];
    float s = 1.f / (1.f + __expf(-a));
    #pragma unroll
    for (int t = 0; t < 4; ++t) hb[t*512 + c] *= s;
  }
}

// ---------------- layernorm rows of 512: f32 in -> bf16 out ----------------
__global__ __launch_bounds__(256) void ln_kernel(
    const float* __restrict__ x, const float* __restrict__ g,
    const float* __restrict__ b, bf16* __restrict__ out)
{
  __shared__ float red[4];
  const int row = blockIdx.x, t = threadIdx.x;
  const float* xr = x + (size_t)row * 512;
  float v0 = xr[t], v1 = xr[t + 256];
  float s = block_sum256(v0 + v1, red);
  float mu = s * (1.f/512.f);
  float d0 = v0 - mu, d1 = v1 - mu;
  float sq = block_sum256(d0*d0 + d1*d1, red);
  float rstd = rsqrtf(sq * (1.f/512.f) + 1e-5f);
  out[(size_t)row*512 + t]       = f2b(d0*rstd*g[t]     + b[t]);
  out[(size_t)row*512 + t + 256] = f2b(d1*rstd*g[t+256] + b[t+256]);
}

// ---------------- final LN + mean over t -> feat bf16 [N][512] -------------
__global__ __launch_bounds__(256) void finalln_kernel(
    const float* __restrict__ h, const float* __restrict__ g,
    const float* __restrict__ b, bf16* __restrict__ feat)
{
  __shared__ float red[4];
  const int n = blockIdx.x, t = threadIdx.x;
  float a0 = 0.f, a1 = 0.f;
  for (int tt = 0; tt < 4; ++tt){
    const float* xr = h + ((size_t)n*4 + tt)*512;
    float v0 = xr[t], v1 = xr[t+256];
    float s = block_sum256(v0 + v1, red);
    float mu = s * (1.f/512.f);
    float d0 = v0 - mu, d1 = v1 - mu;
    float sq = block_sum256(d0*d0 + d1*d1, red);
    float rstd = rsqrtf(sq * (1.f/512.f) + 1e-5f);
    a0 += d0*rstd*g[t]     + b[t];
    a1 += d1*rstd*g[t+256] + b[t+256];
  }
  feat[(size_t)n*512 + t]       = f2b(a0 * 0.25f);
  feat[(size_t)n*512 + t + 256] = f2b(a1 * 0.25f);
}

// ---------------- causal depthwise conv (L=4,K=4) + silu, 4 ch/thread ------
__global__ __launch_bounds__(256) void dwconv_kernel(
    const bf16* __restrict__ xz, const float* __restrict__ cw,
    const float* __restrict__ cb, int d, bf16* __restrict__ u)
{
  const int n = blockIdx.x;
  const int c4 = threadIdx.x * 4;
  ushort4 in4[4];
  #pragma unroll
  for (int t = 0; t < 4; ++t){
    int ts = d ? (3 - t) : t;
    in4[t] = *reinterpret_cast<const ushort4*>(&xz[((size_t)n*4 + ts)*2048 + c4]);
  }
  float4 wv[4];
  #pragma unroll
  for (int j = 0; j < 4; ++j)
    wv[j] = *reinterpret_cast<const float4*>(&cw[(c4 + j)*4]);
  float4 bb = *reinterpret_cast<const float4*>(&cb[c4]);
  float bbv[4] = {bb.x, bb.y, bb.z, bb.w};
  ushort4 out[4];
  #pragma unroll
  for (int j = 0; j < 4; ++j){
    float x0 = u2f(j==0?in4[0].x:j==1?in4[0].y:j==2?in4[0].z:in4[0].w);
    float x1 = u2f(j==0?in4[1].x:j==1?in4[1].y:j==2?in4[1].z:in4[1].w);
    float x2 = u2f(j==0?in4[2].x:j==1?in4[2].y:j==2?in4[2].z:in4[2].w);
    float x3 = u2f(j==0?in4[3].x:j==1?in4[3].y:j==2?in4[3].z:in4[3].w);
    float w0 = wv[j].x, w1 = wv[j].y, w2 = wv[j].z, w3 = wv[j].w;
    float o[4];
    o[0] = x0*w3 + bbv[j];
    o[1] = x0*w2 + x1*w3 + bbv[j];
    o[2] = x0*w1 + x1*w2 + x2*w3 + bbv[j];
    o[3] = x0*w0 + x1*w1 + x2*w2 + x3*w3 + bbv[j];
    #pragma unroll
    for (int t = 0; t < 4; ++t){
      float v = o[t];
      float sv = v / (1.f + __expf(-v));
      unsigned short us = __bfloat16_as_ushort(f2b(sv));
      if (j==0) out[t].x = us; else if (j==1) out[t].y = us;
      else if (j==2) out[t].z = us; else out[t].w = us;
    }
  }
  #pragma unroll
  for (int t = 0; t < 4; ++t)
    *reinterpret_cast<ushort4*>(&u[((size_t)n*4 + t)*1024 + c4]) = out[t];
}

// ---------------- fused dt_proj + selective scan (L=4, S=16) + D term ------
// dbl (f32, ld=128): cols 0..31 dtr, 32..47 B, 48..63 C.
__global__ __launch_bounds__(256) void scan_kernel(
    const float* __restrict__ dbl, const float* __restrict__ dtw,
    const float* __restrict__ dtb, const bf16* __restrict__ u,
    const float* __restrict__ Alog, const float* __restrict__ Dp,
    int d, float* __restrict__ ybuf)
{
  __shared__ float dtr[4][32];
  __shared__ float Bs[4][16], Cs[4][16];
  const int n = blockIdx.x, g = blockIdx.y, tid = threadIdx.x;
  {
    int t = tid >> 6, j = tid & 63;
    float v = dbl[((size_t)n*4 + t)*128 + j];
    if (j < 32) dtr[t][j] = v;
    else if (j < 48) Bs[t][j-32] = v;
    else Cs[t][j-48] = v;
  }
  __syncthreads();
  const int c = g*256 + tid;
  float wdt[32];
  {
    const float4* wp4 = reinterpret_cast<const float4*>(dtw + (size_t)c*32);
    #pragma unroll
    for (int q = 0; q < 8; ++q){
      float4 v = wp4[q];
      wdt[q*4+0] = v.x; wdt[q*4+1] = v.y; wdt[q*4+2] = v.z; wdt[q*4+3] = v.w;
    }
  }
  const float dtbc = dtb[c];
  float A[16];
  #pragma unroll
  for (int s = 0; s < 16; ++s) A[s] = -__expf(Alog[(size_t)c*16 + s]);
  const float Dpc = Dp[c];
  float hs[16];
  #pragma unroll
  for (int s = 0; s < 16; ++s) hs[s] = 0.f;
  #pragma unroll
  for (int t = 0; t < 4; ++t){
    float raw = dtbc;
    #pragma unroll
    for (int k = 0; k < 32; ++k) raw += dtr[t][k] * wdt[k];
    float dtv = (raw > 20.f) ? raw : log1pf(__expf(raw));   // softplus
    float uv  = bfu(u[((size_t)n*4 + t)*1024 + c]);
    float du = dtv * uv;
    float y = 0.f;
    #pragma unroll
    for (int s = 0; s < 16; ++s){
      float dA = __expf(dtv * A[s]);
      hs[s] = dA * hs[s] + du * Bs[t][s];
      y += hs[s] * Cs[t][s];
    }
    float yd = y + uv * Dpc;
    int to = d ? (3 - t) : t;
    float* dst = &ybuf[((size_t)n*4 + to)*1024 + c];
    if (d == 0) *dst = yd; else *dst += yd;
  }
}

// ---------------- gate: gated = ybuf * silu(z), 4 elems/thread -------------
__global__ __launch_bounds__(256) void gate_kernel(
    const float* __restrict__ ybuf, const bf16* __restrict__ xz,
    bf16* __restrict__ gated)
{
  const int total4 = 8192 * 256;   // (8192*1024)/4
  for (int i = blockIdx.x*256 + threadIdx.x; i < total4; i += 2048*256){
    int row = i >> 8, c4 = (i & 255) << 2;
    float4 y = reinterpret_cast<const float4*>(ybuf)[i];
    ushort4 z4 = *reinterpret_cast<const ushort4*>(&xz[(size_t)row*2048 + 1024 + c4]);
    float z0 = u2f(z4.x), z1 = u2f(z4.y), z2 = u2f(z4.z), z3 = u2f(z4.w);
    ushort4 o;
    o.x = __bfloat16_as_ushort(f2b(y.x * z0 / (1.f + __expf(-z0))));
    o.y = __bfloat16_as_ushort(f2b(y.y * z1 / (1.f + __expf(-z1))));
    o.z = __bfloat16_as_ushort(f2b(y.z * z2 / (1.f + __expf(-z2))));
    o.w = __bfloat16_as_ushort(f2b(y.w * z3 / (1.f + __expf(-z3))));
    reinterpret_cast<ushort4*>(gated)[i] = o;
  }
}

// ---------------- launch ---------------------------------------------------
extern "C" void kernel_launch(void* const* d_in, const int* in_sizes, int n_in,
                              void* d_out, int out_size, void* d_ws, size_t ws_size,
                              hipStream_t stream)
{
  const float* x_flat    = (const float*)d_in[0];
  const float* conv_a_w  = (const float*)d_in[1];
  const float* conv_p_w  = (const float*)d_in[2];
  const float* se_w1     = (const float*)d_in[3];
  const float* se_b1     = (const float*)d_in[4];
  const float* se_w2     = (const float*)d_in[5];
  const float* se_b2     = (const float*)d_in[6];
  const float* ln_g      = (const float*)d_in[7];
  const float* ln_b      = (const float*)d_in[8];
  const float* in_proj_w = (const float*)d_in[9];
  const float* conv_w    = (const float*)d_in[10];
  const float* conv_b    = (const float*)d_in[11];
  const float* x_proj_w  = (const float*)d_in[12];
  const float* dt_proj_w = (const float*)d_in[13];
  const float* dt_proj_b = (const float*)d_in[14];
  const float* A_log     = (const float*)d_in[15];
  const float* D_param   = (const float*)d_in[16];
  const float* out_proj_w= (const float*)d_in[17];
  const float* out_ln_g  = (const float*)d_in[18];
  const float* out_ln_b  = (const float*)d_in[19];
  const float* mlp_w1    = (const float*)d_in[20];
  const float* mlp_b1    = (const float*)d_in[21];
  const float* mlp_w2    = (const float*)d_in[22];
  const float* mlp_b2    = (const float*)d_in[23];

  char* ws = (char*)d_ws;
  const size_t OFF_H    = 0;                       // f32  8192*512   = 16.78MB
  const size_t OFF_HN   = OFF_H    + 16777216;     // bf16 8192*512
  const size_t OFF_XZ   = OFF_HN   + 8388608;      // bf16 8192*2048
  const size_t OFF_U    = OFF_XZ   + 33554432;     // bf16 8192*1024 (also gated)
  const size_t OFF_DBL  = OFF_U    + 16777216;     // f32  8192*128  = 4.19MB
  const size_t OFF_SCR  = OFF_DBL  + 4194304;      // 25.17MB: Aa (stem) / wb1 (MLP)
  const size_t OFF_YB   = OFF_SCR  + 25165824;     // f32 8192*1024: ybuf / Pm+wa+wp / wb2
  const size_t OFF_WB   = OFF_YB   + 33554432;     // bf16 in_proj+out_proj
  const size_t OFF_WXP  = OFF_WB   + 6291456;      // bf16 4*128*1024 = 1MB
  // total = OFF_WXP + 1048576 = ~145.8MB

  float* h    = (float*)(ws + OFF_H);
  bf16*  hn   = (bf16*) (ws + OFF_HN);
  bf16*  xz   = (bf16*) (ws + OFF_XZ);
  bf16*  u    = (bf16*) (ws + OFF_U);
  float* dbl  = (float*)(ws + OFF_DBL);
  float* ybuf = (float*)(ws + OFF_YB);
  bf16*  feat = (bf16*) (ws + OFF_HN);   // overlay
  bf16*  z1   = (bf16*) (ws + OFF_XZ);   // overlay
  bf16*  wbi  = (bf16*) (ws + OFF_WB);               // 2*2048*512
  bf16*  wbo  = (bf16*) (ws + OFF_WB + 4194304);     // 2*512*1024
  bf16*  wxp  = (bf16*) (ws + OFF_WXP);              // 4*128*1024 padded x_proj
  bf16*  wb1  = (bf16*) (ws + OFF_SCR);  // overlay (MLP phase)
  bf16*  wb2  = (bf16*) (ws + OFF_YB);   // overlay (MLP phase)
  // stem-phase overlays
  bf16*  Aa   = (bf16*) (ws + OFF_SCR);                       // 8192*1536*2
  bf16*  Pm   = (bf16*) (ws + OFF_YB);                        // 8192*512*2
  bf16*  wa   = (bf16*) (ws + OFF_YB + 8388608);              // 256*1536*2
  bf16*  wp   = (bf16*) (ws + OFF_YB + 8388608 + 786432);     // 256*512*2
  float* outf = (float*)d_out;

  // weight conversions
  f2b4_kernel<<<512,  256, 0, stream>>>((const float4*)conv_a_w,   (ushort4*)wa,  98304);
  f2b4_kernel<<<256,  256, 0, stream>>>((const float4*)conv_p_w,   (ushort4*)wp,  32768);
  f2b4_kernel<<<2048, 256, 0, stream>>>((const float4*)in_proj_w,  (ushort4*)wbi, 524288);
  f2b4_kernel<<<1024, 256, 0, stream>>>((const float4*)out_proj_w, (ushort4*)wbo, 262144);
  xpw_pad_kernel<<<2048, 256, 0, stream>>>(x_proj_w, wxp);

  // stem: im2col + MFMA GEMMs + SE
  im2col_kernel<<<2048, 256, 0, stream>>>(x_flat, Aa, Pm);
  mgemm_kernel<1,1,false><<<dim3(64,2), 256, 0, stream>>>(
      Aa, wa, nullptr, h, 1536, 512);              // conv_a -> h cols 0..255
  mgemm_kernel<1,1,false><<<dim3(64,2), 256, 0, stream>>>(
      Pm, wp, nullptr, (float*)h + 256, 512, 512); // conv_p -> h cols 256..511
  se_kernel<<<2048, 256, 0, stream>>>(se_w1, se_b1, se_w2, se_b2, h);

  for (int l = 0; l < 2; ++l){
    ln_kernel<<<8192, 256, 0, stream>>>(h, ln_g + l*512, ln_b + l*512, hn);
    mgemm_kernel<0,0,false><<<dim3(64,16), 256, 0, stream>>>(
        hn, wbi + (size_t)l*2048*512, nullptr, xz, 512, 2048);
    for (int d = 0; d < 2; ++d){
      int ld = l*2 + d;
      dwconv_kernel<<<2048, 256, 0, stream>>>(
          xz, conv_w + (size_t)ld*4096, conv_b + (size_t)ld*1024, d, u);
      mgemm_kernel<0,1,false><<<dim3(64,1), 256, 0, stream>>>(
          u, wxp + (size_t)ld*131072, nullptr, dbl, 1024, 128);
      scan_kernel<<<dim3(2048,4), 256, 0, stream>>>(
          dbl, dt_proj_w + (size_t)ld*32768, dt_proj_b + (size_t)ld*1024,
          u, A_log + (size_t)ld*16384, D_param + (size_t)ld*1024, d, ybuf);
    }
    gate_kernel<<<2048, 256, 0, stream>>>(ybuf, xz, u /* gated overlays u */);
    mgemm_kernel<0,2,false><<<dim3(64,4), 256, 0, stream>>>(
        u, wbo + (size_t)l*512*1024, nullptr, h, 1024, 512);
  }

  finalln_kernel<<<2048, 256, 0, stream>>>(h, out_ln_g, out_ln_b, feat);

  // convert MLP weights into dead scratch regions
  f2b4_kernel<<<1024, 256, 0, stream>>>((const float4*)mlp_w1, (ushort4*)wb1, 524288);
  f2b4_kernel<<<2048, 256, 0, stream>>>((const float4*)mlp_w2, (ushort4*)wb2, 4194304);

  mgemm_kernel<1,0,true><<<dim3(16,32), 256, 0, stream>>>(
      feat, wb1, mlp_b1, z1, 512, 4096);
  mgemm_kernel<1,1,true><<<dim3(16,32), 256, 0, stream>>>(
      z1, wb2, mlp_b2, outf, 4096, 4096);
}

// Round 6
// 750.444 us; speedup vs baseline: 3.6275x; 1.0742x over previous
//
#include <hip/hip_runtime.h>
#include <hip/hip_bf16.h>

typedef __hip_bfloat16 bf16;
typedef __attribute__((ext_vector_type(8))) short s16x8;
typedef __attribute__((ext_vector_type(4))) float f32x4;

__device__ __forceinline__ float u2f(unsigned short u){
  union { unsigned int i; float f; } v; v.i = ((unsigned int)u) << 16; return v.f;
}
__device__ __forceinline__ float bfu(bf16 x){ return __bfloat162float(x); }
__device__ __forceinline__ bf16  f2b(float x){ return __float2bfloat16(x); }

__device__ __forceinline__ void gload16(const void* g, void* l){
  __builtin_amdgcn_global_load_lds(
      (const __attribute__((address_space(1))) void*)g,
      (__attribute__((address_space(3))) void*)l, 16, 0, 0);
}

// ---------------- block reduction (256 threads) ----------------
__device__ __forceinline__ float block_sum256(float v, float* red){
  #pragma unroll
  for (int o = 32; o > 0; o >>= 1) v += __shfl_down(v, o, 64);
  int lane = threadIdx.x & 63, wid = threadIdx.x >> 6;
  if (lane == 0) red[wid] = v;
  __syncthreads();
  float r = red[0] + red[1] + red[2] + red[3];
  __syncthreads();
  return r;
}

// ---------------- fp32 -> bf16 weight conversion (vectorized) --------------
__global__ __launch_bounds__(256) void f2b4_kernel(
    const float4* __restrict__ in, ushort4* __restrict__ out, int n4)
{
  int stride = gridDim.x * 256;
  for (int i = blockIdx.x*256 + threadIdx.x; i < n4; i += stride){
    float4 v = in[i];
    ushort4 o;
    o.x = __bfloat16_as_ushort(f2b(v.x));
    o.y = __bfloat16_as_ushort(f2b(v.y));
    o.z = __bfloat16_as_ushort(f2b(v.z));
    o.w = __bfloat16_as_ushort(f2b(v.w));
    out[i] = o;
  }
}

// ---------------- x_proj weights -> packed [L][2*128][1024] bf16, 0-pad ----
// out[l][d*128 + r][c] = (r<64) ? x_proj_w[l][d][r][c] : 0
__global__ __launch_bounds__(256) void xpw_pad_kernel(
    const float* __restrict__ xpw, bf16* __restrict__ out)
{
  int idx = blockIdx.x*256 + threadIdx.x;       // 2*256*1024 = 524288
  if (idx >= 524288) return;
  int l = idx >> 18, rem = idx & 262143, row = rem >> 10, c = rem & 1023;
  int d = row >> 7, r = row & 127;
  float v = (r < 64) ? xpw[(((size_t)l*2 + d)*64 + r)*1024 + c] : 0.f;
  out[idx] = f2b(v);
}

// ---------------- MFMA GEMM: out[m,n] = act(sum_k A[m,k]*W[n,k] + bias[n])
// A,W bf16 row-major (leading dim = K). 128x128 tile, BK=64, 4 waves.
// Grid (m-tiles, n-tiles); TOTAL BLOCKS MUST BE %8==0 (XCD swizzle).
// ACT: 0 none, 1 relu. OMODE: 0 bf16 store, 1 f32 store, 2 f32 +=.
template<int ACT, int OMODE, bool HASBIAS>
__global__ __launch_bounds__(256) void mgemm_kernel(
    const bf16* __restrict__ A, const bf16* __restrict__ W,
    const float* __restrict__ bias, void* __restrict__ outp,
    int K, int ldo)
{
  __shared__ char lsA[16384];
  __shared__ char lsB[16384];
  const int tid = threadIdx.x;
  const int w = tid >> 6, l = tid & 63;
  // XCD-aware bijective swizzle (nwg % 8 == 0 for all call sites)
  const int nwg = gridDim.x * gridDim.y;
  const int lin = blockIdx.y * gridDim.x + blockIdx.x;
  const int cpx = nwg >> 3;
  const int swz = (lin & 7) * cpx + (lin >> 3);
  const int m0 = (swz % gridDim.x) * 128, n0 = (swz / gridDim.x) * 128;
  const int wr = w >> 1, wc = w & 1;          // wave sub-tile origin (wr*64, wc*64)
  const size_t ldb = (size_t)K * 2;           // row stride in bytes
  const char* Ab = (const char*)A + (size_t)m0 * ldb;
  const char* Wb = (const char*)W + (size_t)n0 * ldb;

  const int srow = l >> 3;                     // row-within-8 = row&7
  const int scb  = ((l & 7) ^ srow) << 4;      // swizzled global col-byte

  const int fr = l & 15;                       // fragment row
  const int fg = l >> 4;                       // k-group
  const int fsw = (fr & 7) << 4;               // read-side swizzle

  f32x4 acc[4][4];
  #pragma unroll
  for (int m = 0; m < 4; ++m)
    #pragma unroll
    for (int n = 0; n < 4; ++n) acc[m][n] = (f32x4){0.f,0.f,0.f,0.f};

  const int nk = K >> 6;
  for (int kt = 0; kt < nk; ++kt){
    const char* As = Ab + (size_t)kt * 128;
    const char* Ws = Wb + (size_t)kt * 128;
    #pragma unroll
    for (int i = 0; i < 4; ++i){
      int row = (i*4 + w)*8 + srow;
      gload16(As + (size_t)row*ldb + scb, &lsA[(i*4 + w)*1024]);
    }
    #pragma unroll
    for (int i = 0; i < 4; ++i){
      int row = (i*4 + w)*8 + srow;
      gload16(Ws + (size_t)row*ldb + scb, &lsB[(i*4 + w)*1024]);
    }
    __syncthreads();

    s16x8 af[4][2], bfr[4][2];
    #pragma unroll
    for (int m = 0; m < 4; ++m){
      int row = wr*64 + m*16 + fr;
      af[m][0] = *(const s16x8*)&lsA[row*128 + (( 0 + fg*16) ^ fsw)];
      af[m][1] = *(const s16x8*)&lsA[row*128 + ((64 + fg*16) ^ fsw)];
    }
    #pragma unroll
    for (int n = 0; n < 4; ++n){
      int row = wc*64 + n*16 + fr;
      bfr[n][0] = *(const s16x8*)&lsB[row*128 + (( 0 + fg*16) ^ fsw)];
      bfr[n][1] = *(const s16x8*)&lsB[row*128 + ((64 + fg*16) ^ fsw)];
    }
    #pragma unroll
    for (int m = 0; m < 4; ++m)
      #pragma unroll
      for (int n = 0; n < 4; ++n){
        acc[m][n] = __builtin_amdgcn_mfma_f32_16x16x32_bf16(af[m][0], bfr[n][0], acc[m][n], 0, 0, 0);
        acc[m][n] = __builtin_amdgcn_mfma_f32_16x16x32_bf16(af[m][1], bfr[n][1], acc[m][n], 0, 0, 0);
      }
    __syncthreads();
  }

  const int orow0 = m0 + wr*64, ocol0 = n0 + wc*64;
  #pragma unroll
  for (int n = 0; n < 4; ++n){
    int col = ocol0 + n*16 + fr;
    float bv = HASBIAS ? bias[col] : 0.f;
    #pragma unroll
    for (int m = 0; m < 4; ++m){
      int rbase = orow0 + m*16 + fg*4;
      #pragma unroll
      for (int r = 0; r < 4; ++r){
        float v = acc[m][n][r] + bv;
        if (ACT == 1) v = fmaxf(v, 0.f);
        size_t oi = (size_t)(rbase + r) * ldo + col;
        if (OMODE == 0)      ((bf16*)outp)[oi] = f2b(v);
        else if (OMODE == 1) ((float*)outp)[oi] = v;
        else                 ((float*)outp)[oi] += v;
      }
    }
  }
}

// ---------------- batched x_proj GEMM: both directions in one launch -------
// grid (64, 2): y picks direction (after swizzle). A_d = A + d*8388608,
// W_d = W + d*131072 (padded 128x1024), out cols d*128..d*128+127, ldo=256.
__global__ __launch_bounds__(256) void bgemm_kernel(
    const bf16* __restrict__ A, const bf16* __restrict__ W,
    float* __restrict__ outp)
{
  __shared__ char lsA[16384];
  __shared__ char lsB[16384];
  const int tid = threadIdx.x;
  const int w = tid >> 6, l = tid & 63;
  const int nwg = gridDim.x * 2;
  const int lin = blockIdx.y * gridDim.x + blockIdx.x;
  const int cpx = nwg >> 3;
  const int swz = (lin & 7) * cpx + (lin >> 3);
  const int m0 = (swz % gridDim.x) * 128;
  const int d  = swz / gridDim.x;
  const int K = 1024, ldo = 256;
  const int wr = w >> 1, wc = w & 1;
  const size_t ldb = (size_t)K * 2;
  const char* Ab = (const char*)(A + (size_t)d*8388608) + (size_t)m0 * ldb;
  const char* Wb = (const char*)(W + (size_t)d*131072);

  const int srow = l >> 3;
  const int scb  = ((l & 7) ^ srow) << 4;
  const int fr = l & 15;
  const int fg = l >> 4;
  const int fsw = (fr & 7) << 4;

  f32x4 acc[4][4];
  #pragma unroll
  for (int m = 0; m < 4; ++m)
    #pragma unroll
    for (int n = 0; n < 4; ++n) acc[m][n] = (f32x4){0.f,0.f,0.f,0.f};

  const int nk = K >> 6;
  for (int kt = 0; kt < nk; ++kt){
    const char* As = Ab + (size_t)kt * 128;
    const char* Ws = Wb + (size_t)kt * 128;
    #pragma unroll
    for (int i = 0; i < 4; ++i){
      int row = (i*4 + w)*8 + srow;
      gload16(As + (size_t)row*ldb + scb, &lsA[(i*4 + w)*1024]);
    }
    #pragma unroll
    for (int i = 0; i < 4; ++i){
      int row = (i*4 + w)*8 + srow;
      gload16(Ws + (size_t)row*ldb + scb, &lsB[(i*4 + w)*1024]);
    }
    __syncthreads();

    s16x8 af[4][2], bfr[4][2];
    #pragma unroll
    for (int m = 0; m < 4; ++m){
      int row = wr*64 + m*16 + fr;
      af[m][0] = *(const s16x8*)&lsA[row*128 + (( 0 + fg*16) ^ fsw)];
      af[m][1] = *(const s16x8*)&lsA[row*128 + ((64 + fg*16) ^ fsw)];
    }
    #pragma unroll
    for (int n = 0; n < 4; ++n){
      int row = wc*64 + n*16 + fr;
      bfr[n][0] = *(const s16x8*)&lsB[row*128 + (( 0 + fg*16) ^ fsw)];
      bfr[n][1] = *(const s16x8*)&lsB[row*128 + ((64 + fg*16) ^ fsw)];
    }
    #pragma unroll
    for (int m = 0; m < 4; ++m)
      #pragma unroll
      for (int n = 0; n < 4; ++n){
        acc[m][n] = __builtin_amdgcn_mfma_f32_16x16x32_bf16(af[m][0], bfr[n][0], acc[m][n], 0, 0, 0);
        acc[m][n] = __builtin_amdgcn_mfma_f32_16x16x32_bf16(af[m][1], bfr[n][1], acc[m][n], 0, 0, 0);
      }
    __syncthreads();
  }

  const int orow0 = m0 + wr*64, ocol0 = d*128 + wc*64;
  #pragma unroll
  for (int n = 0; n < 4; ++n){
    int col = ocol0 + n*16 + fr;
    #pragma unroll
    for (int m = 0; m < 4; ++m){
      int rbase = orow0 + m*16 + fg*4;
      #pragma unroll
      for (int r = 0; r < 4; ++r)
        outp[(size_t)(rbase + r) * ldo + col] = acc[m][n][r];
    }
  }
}

// ---------------- stem im2col: x -> conv_a patches (bf16) + maxpool (bf16) --
__global__ __launch_bounds__(256) void im2col_kernel(
    const float* __restrict__ x_flat, bf16* __restrict__ Aa, bf16* __restrict__ P)
{
  __shared__ float xs[512][8];
  const int n = blockIdx.x, tid = threadIdx.x;
  const float* xr = x_flat + (size_t)n * 3584;
  for (int i = tid; i < 3584; i += 256) xs[i / 7][i % 7] = xr[i];
  __syncthreads();
  bf16* Ar = Aa + (size_t)n * 4 * 1536;
  for (int i = tid; i < 6144; i += 256){
    int t = i / 1536, col = i - t*1536;
    int c = col / 3, kk = col - c*3;
    int p = 2*t - 1 + kk;
    float v = (p >= 0 && p < 7) ? xs[c][p] : 0.f;
    Ar[i] = f2b(v);
  }
  bf16* Pr = P + (size_t)n * 4 * 512;
  for (int i = tid; i < 2048; i += 256){
    int t = i >> 9, c = i & 511;
    int st = 2*t - 1;
    float m = -1e30f;
    #pragma unroll
    for (int k = 0; k < 3; ++k){ int p = st + k; if (p >= 0 && p < 7) m = fmaxf(m, xs[c][p]); }
    Pr[i] = f2b(m);
  }
}

// ---------------- SE: mean over t -> 2 matvecs -> sigmoid -> scale h in place
__global__ __launch_bounds__(256) void se_kernel(
    const float* __restrict__ sw1, const float* __restrict__ sb1,
    const float* __restrict__ sw2, const float* __restrict__ sb2,
    float* __restrict__ h)
{
  __shared__ float yms[512];
  __shared__ float s1s[32];
  const int n = blockIdx.x, tid = threadIdx.x;
  float* hb = h + (size_t)n * 2048;
  for (int c = tid; c < 512; c += 256)
    yms[c] = 0.25f * (hb[c] + hb[512+c] + hb[1024+c] + hb[1536+c]);
  __syncthreads();
  {
    int o = tid >> 3, sl = tid & 7;
    const float* wr = sw1 + (size_t)o * 512 + sl*64;
    const float* ym = yms + sl*64;
    float a = 0.f;
    #pragma unroll 16
    for (int i = 0; i < 64; ++i) a += wr[i] * ym[i];
    a += __shfl_down(a, 4, 8);
    a += __shfl_down(a, 2, 8);
    a += __shfl_down(a, 1, 8);
    if (sl == 0) s1s[o] = fmaxf(a + sb1[o], 0.f);
  }
  __syncthreads();
  for (int c = tid; c < 512; c += 256){
    float a = sb2[c];
    const float* wr = sw2 + (size_t)c * 32;
    #pragma unroll
    for (int j = 0; j < 32; ++j) a += wr[j] * s1s[j];
    float s = 1.f / (1.f + __expf(-a));
    #pragma unroll
    for (int t = 0; t < 4; ++t) hb[t*512 + c] *= s;
  }
}

// ---------------- layernorm rows of 512: f32 in -> bf16 out ----------------
__global__ __launch_bounds__(256) void ln_kernel(
    const float* __restrict__ x, const float* __restrict__ g,
    const float* __restrict__ b, bf16* __restrict__ out)
{
  __shared__ float red[4];
  const int row = blockIdx.x, t = threadIdx.x;
  const float* xr = x + (size_t)row * 512;
  float v0 = xr[t], v1 = xr[t + 256];
  float s = block_sum256(v0 + v1, red);
  float mu = s * (1.f/512.f);
  float d0 = v0 - mu, d1 = v1 - mu;
  float sq = block_sum256(d0*d0 + d1*d1, red);
  float rstd = rsqrtf(sq * (1.f/512.f) + 1e-5f);
  out[(size_t)row*512 + t]       = f2b(d0*rstd*g[t]     + b[t]);
  out[(size_t)row*512 + t + 256] = f2b(d1*rstd*g[t+256] + b[t+256]);
}

// ---------------- final LN + mean over t -> feat bf16 [N][512] -------------
__global__ __launch_bounds__(256) void finalln_kernel(
    const float* __restrict__ h, const float* __restrict__ g,
    const float* __restrict__ b, bf16* __restrict__ feat)
{
  __shared__ float red[4];
  const int n = blockIdx.x, t = threadIdx.x;
  float a0 = 0.f, a1 = 0.f;
  for (int tt = 0; tt < 4; ++tt){
    const float* xr = h + ((size_t)n*4 + tt)*512;
    float v0 = xr[t], v1 = xr[t+256];
    float s = block_sum256(v0 + v1, red);
    float mu = s * (1.f/512.f);
    float d0 = v0 - mu, d1 = v1 - mu;
    float sq = block_sum256(d0*d0 + d1*d1, red);
    float rstd = rsqrtf(sq * (1.f/512.f) + 1e-5f);
    a0 += d0*rstd*g[t]     + b[t];
    a1 += d1*rstd*g[t+256] + b[t+256];
  }
  feat[(size_t)n*512 + t]       = f2b(a0 * 0.25f);
  feat[(size_t)n*512 + t + 256] = f2b(a1 * 0.25f);
}

// ---------------- causal dwconv (both dirs) + silu, 4 ch/thread ------------
// u[d][(n*4+t)*1024 + c]; dir1 = conv of time-reversed input.
__global__ __launch_bounds__(256) void dwconv2_kernel(
    const bf16* __restrict__ xz, const float* __restrict__ cw,
    const float* __restrict__ cb, bf16* __restrict__ u)
{
  const int n = blockIdx.x;
  const int c4 = threadIdx.x * 4;
  ushort4 in4[4];
  #pragma unroll
  for (int t = 0; t < 4; ++t)
    in4[t] = *reinterpret_cast<const ushort4*>(&xz[((size_t)n*4 + t)*2048 + c4]);
  #pragma unroll
  for (int d = 0; d < 2; ++d){
    const float* cwd = cw + d*4096;
    const float* cbd = cb + d*1024;
    ushort4 out[4];
    #pragma unroll
    for (int j = 0; j < 4; ++j){
      float xa[4];
      #pragma unroll
      for (int t = 0; t < 4; ++t){
        int ts = d ? 3 - t : t;
        unsigned short us = j==0?in4[ts].x : j==1?in4[ts].y : j==2?in4[ts].z : in4[ts].w;
        xa[t] = u2f(us);
      }
      float4 wv = *reinterpret_cast<const float4*>(&cwd[(c4 + j)*4]);
      float bb = cbd[c4 + j];
      float o[4];
      o[0] = xa[0]*wv.w + bb;
      o[1] = xa[0]*wv.z + xa[1]*wv.w + bb;
      o[2] = xa[0]*wv.y + xa[1]*wv.z + xa[2]*wv.w + bb;
      o[3] = xa[0]*wv.x + xa[1]*wv.y + xa[2]*wv.z + xa[3]*wv.w + bb;
      #pragma unroll
      for (int t = 0; t < 4; ++t){
        float v = o[t];
        float sv = v / (1.f + __expf(-v));
        unsigned short us = __bfloat16_as_ushort(f2b(sv));
        if (j==0) out[t].x = us; else if (j==1) out[t].y = us;
        else if (j==2) out[t].z = us; else out[t].w = us;
      }
    }
    #pragma unroll
    for (int t = 0; t < 4; ++t)
      *reinterpret_cast<ushort4*>(&u[(size_t)d*8388608 + ((size_t)n*4 + t)*1024 + c4]) = out[t];
  }
}

// ---------------- fused dt_proj + selective scan, grid (2048,4,2) ----------
// dbl (f32, ld=256): dir d cols d*128+{0..31 dtr, 32..47 B, 48..63 C}.
// y (bf16): separate halves per direction; gate sums them.
__global__ __launch_bounds__(256) void scan_kernel(
    const float* __restrict__ dbl, const float* __restrict__ dtw,
    const float* __restrict__ dtb, const bf16* __restrict__ u,
    const float* __restrict__ Alog, const float* __restrict__ Dp,
    bf16* __restrict__ y)
{
  __shared__ float dtr[4][32];
  __shared__ float Bs[4][16], Cs[4][16];
  const int n = blockIdx.x, g = blockIdx.y, d = blockIdx.z, tid = threadIdx.x;
  {
    int t = tid >> 6, j = tid & 63;
    float v = dbl[((size_t)n*4 + t)*256 + d*128 + j];
    if (j < 32) dtr[t][j] = v;
    else if (j < 48) Bs[t][j-32] = v;
    else Cs[t][j-48] = v;
  }
  __syncthreads();
  const int c = g*256 + tid;
  float wdt[32];
  {
    const float4* wp4 = reinterpret_cast<const float4*>(dtw + (size_t)d*32768 + (size_t)c*32);
    #pragma unroll
    for (int q = 0; q < 8; ++q){
      float4 v = wp4[q];
      wdt[q*4+0] = v.x; wdt[q*4+1] = v.y; wdt[q*4+2] = v.z; wdt[q*4+3] = v.w;
    }
  }
  const float dtbc = dtb[d*1024 + c];
  const float* Ald = Alog + (size_t)d*16384;
  float A[16];
  #pragma unroll
  for (int s = 0; s < 16; ++s) A[s] = -__expf(Ald[(size_t)c*16 + s]);
  const float Dpc = Dp[d*1024 + c];
  const bf16* ud = u + (size_t)d*8388608;
  bf16* yd = y + (size_t)d*8388608;
  float hs[16];
  #pragma unroll
  for (int s = 0; s < 16; ++s) hs[s] = 0.f;
  #pragma unroll
  for (int t = 0; t < 4; ++t){
    float raw = dtbc;
    #pragma unroll
    for (int k = 0; k < 32; ++k) raw += dtr[t][k] * wdt[k];
    float dtv = (raw > 20.f) ? raw : log1pf(__expf(raw));   // softplus
    float uv  = bfu(ud[((size_t)n*4 + t)*1024 + c]);
    float du = dtv * uv;
    float yv = 0.f;
    #pragma unroll
    for (int s = 0; s < 16; ++s){
      float dA = __expf(dtv * A[s]);
      hs[s] = dA * hs[s] + du * Bs[t][s];
      yv += hs[s] * Cs[t][s];
    }
    float out = yv + uv * Dpc;
    int to = d ? (3 - t) : t;
    yd[((size_t)n*4 + to)*1024 + c] = f2b(out);
  }
}

// ---------------- gate: gated = (y0+y1) * silu(z), 4 elems/thread ----------
__global__ __launch_bounds__(256) void gate_kernel(
    const bf16* __restrict__ y, const bf16* __restrict__ xz,
    bf16* __restrict__ gated)
{
  const int total4 = 8192 * 256;   // (8192*1024)/4
  for (int i = blockIdx.x*256 + threadIdx.x; i < total4; i += 2048*256){
    int row = i >> 8, c4 = (i & 255) << 2;
    ushort4 a4 = reinterpret_cast<const ushort4*>(y)[i];
    ushort4 b4 = reinterpret_cast<const ushort4*>(y + 8388608)[i];
    ushort4 z4 = *reinterpret_cast<const ushort4*>(&xz[(size_t)row*2048 + 1024 + c4]);
    float y0 = u2f(a4.x) + u2f(b4.x), y1 = u2f(a4.y) + u2f(b4.y);
    float y2 = u2f(a4.z) + u2f(b4.z), y3 = u2f(a4.w) + u2f(b4.w);
    float z0 = u2f(z4.x), z1 = u2f(z4.y), z2 = u2f(z4.z), z3 = u2f(z4.w);
    ushort4 o;
    o.x = __bfloat16_as_ushort(f2b(y0 * z0 / (1.f + __expf(-z0))));
    o.y = __bfloat16_as_ushort(f2b(y1 * z1 / (1.f + __expf(-z1))));
    o.z = __bfloat16_as_ushort(f2b(y2 * z2 / (1.f + __expf(-z2))));
    o.w = __bfloat16_as_ushort(f2b(y3 * z3 / (1.f + __expf(-z3))));
    reinterpret_cast<ushort4*>(gated)[i] = o;
  }
}

// ---------------- launch ---------------------------------------------------
extern "C" void kernel_launch(void* const* d_in, const int* in_sizes, int n_in,
                              void* d_out, int out_size, void* d_ws, size_t ws_size,
                              hipStream_t stream)
{
  const float* x_flat    = (const float*)d_in[0];
  const float* conv_a_w  = (const float*)d_in[1];
  const float* conv_p_w  = (const float*)d_in[2];
  const float* se_w1     = (const float*)d_in[3];
  const float* se_b1     = (const float*)d_in[4];
  const float* se_w2     = (const float*)d_in[5];
  const float* se_b2     = (const float*)d_in[6];
  const float* ln_g      = (const float*)d_in[7];
  const float* ln_b      = (const float*)d_in[8];
  const float* in_proj_w = (const float*)d_in[9];
  const float* conv_w    = (const float*)d_in[10];
  const float* conv_b    = (const float*)d_in[11];
  const float* x_proj_w  = (const float*)d_in[12];
  const float* dt_proj_w = (const float*)d_in[13];
  const float* dt_proj_b = (const float*)d_in[14];
  const float* A_log     = (const float*)d_in[15];
  const float* D_param   = (const float*)d_in[16];
  const float* out_proj_w= (const float*)d_in[17];
  const float* out_ln_g  = (const float*)d_in[18];
  const float* out_ln_b  = (const float*)d_in[19];
  const float* mlp_w1    = (const float*)d_in[20];
  const float* mlp_b1    = (const float*)d_in[21];
  const float* mlp_w2    = (const float*)d_in[22];
  const float* mlp_b2    = (const float*)d_in[23];

  char* ws = (char*)d_ws;
  const size_t OFF_H    = 0;                       // f32  8192*512  = 16.78MB
  const size_t OFF_HN   = OFF_H    + 16777216;     // bf16 8192*512  (feat overlay)
  const size_t OFF_XZ   = OFF_HN   + 8388608;      // bf16 8192*2048 (z1 overlay)
  const size_t OFF_U    = OFF_XZ   + 33554432;     // bf16 [2]*8192*1024 = 33.55MB
  const size_t OFF_SCR  = OFF_U    + 33554432;     // 25.17MB: Aa(stem)/dbl(layers)/wb1(MLP)
  const size_t OFF_YB   = OFF_SCR  + 25165824;     // 33.55MB: Pm+wa+wp(stem)/y(layers)/wb2(MLP)
  const size_t OFF_WB   = OFF_YB   + 33554432;     // bf16 in_proj+out_proj
  const size_t OFF_WXP  = OFF_WB   + 6291456;      // bf16 2*256*1024 packed x_proj
  // total = OFF_WXP + 1048576 = ~158.3MB

  float* h    = (float*)(ws + OFF_H);
  bf16*  hn   = (bf16*) (ws + OFF_HN);
  bf16*  xz   = (bf16*) (ws + OFF_XZ);
  bf16*  u    = (bf16*) (ws + OFF_U);
  float* dbl  = (float*)(ws + OFF_SCR);  // layer-phase overlay
  bf16*  y    = (bf16*) (ws + OFF_YB);   // layer-phase overlay
  bf16*  feat = (bf16*) (ws + OFF_HN);   // overlay
  bf16*  z1   = (bf16*) (ws + OFF_XZ);   // overlay
  bf16*  wbi  = (bf16*) (ws + OFF_WB);               // 2*2048*512
  bf16*  wbo  = (bf16*) (ws + OFF_WB + 4194304);     // 2*512*1024
  bf16*  wxp  = (bf16*) (ws + OFF_WXP);              // 2*256*1024 packed x_proj
  bf16*  wb1  = (bf16*) (ws + OFF_SCR);  // overlay (MLP phase)
  bf16*  wb2  = (bf16*) (ws + OFF_YB);   // overlay (MLP phase)
  // stem-phase overlays
  bf16*  Aa   = (bf16*) (ws + OFF_SCR);                       // 8192*1536*2
  bf16*  Pm   = (bf16*) (ws + OFF_YB);                        // 8192*512*2
  bf16*  wa   = (bf16*) (ws + OFF_YB + 8388608);              // 256*1536*2
  bf16*  wp   = (bf16*) (ws + OFF_YB + 8388608 + 786432);     // 256*512*2
  float* outf = (float*)d_out;

  // weight conversions
  f2b4_kernel<<<512,  256, 0, stream>>>((const float4*)conv_a_w,   (ushort4*)wa,  98304);
  f2b4_kernel<<<256,  256, 0, stream>>>((const float4*)conv_p_w,   (ushort4*)wp,  32768);
  f2b4_kernel<<<2048, 256, 0, stream>>>((const float4*)in_proj_w,  (ushort4*)wbi, 524288);
  f2b4_kernel<<<1024, 256, 0, stream>>>((const float4*)out_proj_w, (ushort4*)wbo, 262144);
  xpw_pad_kernel<<<2048, 256, 0, stream>>>(x_proj_w, wxp);

  // stem: im2col + MFMA GEMMs + SE
  im2col_kernel<<<2048, 256, 0, stream>>>(x_flat, Aa, Pm);
  mgemm_kernel<1,1,false><<<dim3(64,2), 256, 0, stream>>>(
      Aa, wa, nullptr, h, 1536, 512);              // conv_a -> h cols 0..255
  mgemm_kernel<1,1,false><<<dim3(64,2), 256, 0, stream>>>(
      Pm, wp, nullptr, (float*)h + 256, 512, 512); // conv_p -> h cols 256..511
  se_kernel<<<2048, 256, 0, stream>>>(se_w1, se_b1, se_w2, se_b2, h);

  for (int l = 0; l < 2; ++l){
    ln_kernel<<<8192, 256, 0, stream>>>(h, ln_g + l*512, ln_b + l*512, hn);
    mgemm_kernel<0,0,false><<<dim3(64,16), 256, 0, stream>>>(
        hn, wbi + (size_t)l*2048*512, nullptr, xz, 512, 2048);
    dwconv2_kernel<<<2048, 256, 0, stream>>>(
        xz, conv_w + (size_t)l*8192, conv_b + (size_t)l*2048, u);
    bgemm_kernel<<<dim3(64,2), 256, 0, stream>>>(
        u, wxp + (size_t)l*262144, dbl);
    scan_kernel<<<dim3(2048,4,2), 256, 0, stream>>>(
        dbl, dt_proj_w + (size_t)l*65536, dt_proj_b + (size_t)l*2048,
        u, A_log + (size_t)l*32768, D_param + (size_t)l*2048, y);
    gate_kernel<<<2048, 256, 0, stream>>>(y, xz, u /* gated overlays u dir0 */);
    mgemm_kernel<0,2,false><<<dim3(64,4), 256, 0, stream>>>(
        u, wbo + (size_t)l*512*1024, nullptr, h, 1024, 512);
  }

  finalln_kernel<<<2048, 256, 0, stream>>>(h, out_ln_g, out_ln_b, feat);

  // convert MLP weights into dead scratch regions
  f2b4_kernel<<<1024, 256, 0, stream>>>((const float4*)mlp_w1, (ushort4*)wb1, 524288);
  f2b4_kernel<<<2048, 256, 0, stream>>>((const float4*)mlp_w2, (ushort4*)wb2, 4194304);

  mgemm_kernel<1,0,true><<<dim3(16,32), 256, 0, stream>>>(
      feat, wb1, mlp_b1, z1, 512, 4096);
  mgemm_kernel<1,1,true><<<dim3(16,32), 256, 0, stream>>>(
      z1, wb2, mlp_b2, outf, 4096, 4096);
}

// Round 7
// 738.506 us; speedup vs baseline: 3.6861x; 1.0162x over previous
//
#include <hip/hip_runtime.h>
#include <hip/hip_bf16.h>

typedef __hip_bfloat16 bf16;
typedef __attribute__((ext_vector_type(8))) short s16x8;
typedef __attribute__((ext_vector_type(4))) float f32x4;

__device__ __forceinline__ float u2f(unsigned short u){
  union { unsigned int i; float f; } v; v.i = ((unsigned int)u) << 16; return v.f;
}
__device__ __forceinline__ float bfu(bf16 x){ return __bfloat162float(x); }
__device__ __forceinline__ bf16  f2b(float x){ return __float2bfloat16(x); }

__device__ __forceinline__ void gload16(const void* g, void* l){
  __builtin_amdgcn_global_load_lds(
      (const __attribute__((address_space(1))) void*)g,
      (__attribute__((address_space(3))) void*)l, 16, 0, 0);
}

// ---------------- block reduction (256 threads) ----------------
__device__ __forceinline__ float block_sum256(float v, float* red){
  #pragma unroll
  for (int o = 32; o > 0; o >>= 1) v += __shfl_down(v, o, 64);
  int lane = threadIdx.x & 63, wid = threadIdx.x >> 6;
  if (lane == 0) red[wid] = v;
  __syncthreads();
  float r = red[0] + red[1] + red[2] + red[3];
  __syncthreads();
  return r;
}

// ---------------- fp32 -> bf16 weight conversion (vectorized) --------------
__global__ __launch_bounds__(256) void f2b4_kernel(
    const float4* __restrict__ in, ushort4* __restrict__ out, int n4)
{
  int stride = gridDim.x * 256;
  for (int i = blockIdx.x*256 + threadIdx.x; i < n4; i += stride){
    float4 v = in[i];
    ushort4 o;
    o.x = __bfloat16_as_ushort(f2b(v.x));
    o.y = __bfloat16_as_ushort(f2b(v.y));
    o.z = __bfloat16_as_ushort(f2b(v.z));
    o.w = __bfloat16_as_ushort(f2b(v.w));
    out[i] = o;
  }
}

// ---------------- x_proj weights -> packed [L][2*128][1024] bf16, 0-pad ----
__global__ __launch_bounds__(256) void xpw_pad_kernel(
    const float* __restrict__ xpw, bf16* __restrict__ out)
{
  int idx = blockIdx.x*256 + threadIdx.x;       // 2*256*1024 = 524288
  if (idx >= 524288) return;
  int l = idx >> 18, rem = idx & 262143, row = rem >> 10, c = rem & 1023;
  int d = row >> 7, r = row & 127;
  float v = (r < 64) ? xpw[(((size_t)l*2 + d)*64 + r)*1024 + c] : 0.f;
  out[idx] = f2b(v);
}

// ---------------- dt_proj weights: [4][1024][32] f32 -> [4][1024][64] bf16 --
__global__ __launch_bounds__(256) void wdt_pad_kernel(
    const float* __restrict__ dtw, bf16* __restrict__ out)
{
  int idx = blockIdx.x*256 + threadIdx.x;       // 4*1024*64 = 262144
  if (idx >= 262144) return;
  int ld = idx >> 16, rem = idx & 65535, r = rem >> 6, c = rem & 63;
  float v = (c < 32) ? dtw[((size_t)ld*1024 + r)*32 + c] : 0.f;
  out[idx] = f2b(v);
}

// ---------------- A table: Atab = -exp(A_log), [4][1024][16] f32 -----------
__global__ __launch_bounds__(256) void atab_kernel(
    const float* __restrict__ Alog, float* __restrict__ Atab)
{
  int i = blockIdx.x*256 + threadIdx.x;         // 65536
  if (i < 65536) Atab[i] = -__expf(Alog[i]);
}

// ---------------- MFMA GEMM: out[m,n] = act(sum_k A[m,k]*W[n,k] + bias[n])
// A,W bf16 row-major (leading dim = K). 128x128 tile, BK=64, 4 waves.
// Grid (m-tiles, n-tiles); TOTAL BLOCKS MUST BE %8==0 (XCD swizzle).
// ACT: 0 none, 1 relu, 2 softplus. OMODE: 0 bf16, 1 f32, 2 f32 +=.
template<int ACT, int OMODE, bool HASBIAS>
__global__ __launch_bounds__(256) void mgemm_kernel(
    const bf16* __restrict__ A, const bf16* __restrict__ W,
    const float* __restrict__ bias, void* __restrict__ outp,
    int K, int ldo)
{
  __shared__ char lsA[16384];
  __shared__ char lsB[16384];
  const int tid = threadIdx.x;
  const int w = tid >> 6, l = tid & 63;
  const int nwg = gridDim.x * gridDim.y;
  const int lin = blockIdx.y * gridDim.x + blockIdx.x;
  const int cpx = nwg >> 3;
  const int swz = (lin & 7) * cpx + (lin >> 3);
  const int m0 = (swz % gridDim.x) * 128, n0 = (swz / gridDim.x) * 128;
  const int wr = w >> 1, wc = w & 1;
  const size_t ldb = (size_t)K * 2;
  const char* Ab = (const char*)A + (size_t)m0 * ldb;
  const char* Wb = (const char*)W + (size_t)n0 * ldb;

  const int srow = l >> 3;
  const int scb  = ((l & 7) ^ srow) << 4;
  const int fr = l & 15;
  const int fg = l >> 4;
  const int fsw = (fr & 7) << 4;

  f32x4 acc[4][4];
  #pragma unroll
  for (int m = 0; m < 4; ++m)
    #pragma unroll
    for (int n = 0; n < 4; ++n) acc[m][n] = (f32x4){0.f,0.f,0.f,0.f};

  const int nk = K >> 6;
  for (int kt = 0; kt < nk; ++kt){
    const char* As = Ab + (size_t)kt * 128;
    const char* Ws = Wb + (size_t)kt * 128;
    #pragma unroll
    for (int i = 0; i < 4; ++i){
      int row = (i*4 + w)*8 + srow;
      gload16(As + (size_t)row*ldb + scb, &lsA[(i*4 + w)*1024]);
    }
    #pragma unroll
    for (int i = 0; i < 4; ++i){
      int row = (i*4 + w)*8 + srow;
      gload16(Ws + (size_t)row*ldb + scb, &lsB[(i*4 + w)*1024]);
    }
    __syncthreads();

    s16x8 af[4][2], bfr[4][2];
    #pragma unroll
    for (int m = 0; m < 4; ++m){
      int row = wr*64 + m*16 + fr;
      af[m][0] = *(const s16x8*)&lsA[row*128 + (( 0 + fg*16) ^ fsw)];
      af[m][1] = *(const s16x8*)&lsA[row*128 + ((64 + fg*16) ^ fsw)];
    }
    #pragma unroll
    for (int n = 0; n < 4; ++n){
      int row = wc*64 + n*16 + fr;
      bfr[n][0] = *(const s16x8*)&lsB[row*128 + (( 0 + fg*16) ^ fsw)];
      bfr[n][1] = *(const s16x8*)&lsB[row*128 + ((64 + fg*16) ^ fsw)];
    }
    #pragma unroll
    for (int m = 0; m < 4; ++m)
      #pragma unroll
      for (int n = 0; n < 4; ++n){
        acc[m][n] = __builtin_amdgcn_mfma_f32_16x16x32_bf16(af[m][0], bfr[n][0], acc[m][n], 0, 0, 0);
        acc[m][n] = __builtin_amdgcn_mfma_f32_16x16x32_bf16(af[m][1], bfr[n][1], acc[m][n], 0, 0, 0);
      }
    __syncthreads();
  }

  const int orow0 = m0 + wr*64, ocol0 = n0 + wc*64;
  #pragma unroll
  for (int n = 0; n < 4; ++n){
    int col = ocol0 + n*16 + fr;
    float bv = HASBIAS ? bias[col] : 0.f;
    #pragma unroll
    for (int m = 0; m < 4; ++m){
      int rbase = orow0 + m*16 + fg*4;
      #pragma unroll
      for (int r = 0; r < 4; ++r){
        float v = acc[m][n][r] + bv;
        if (ACT == 1) v = fmaxf(v, 0.f);
        if (ACT == 2) v = (v > 20.f) ? v : log1pf(__expf(v));
        size_t oi = (size_t)(rbase + r) * ldo + col;
        if (OMODE == 0)      ((bf16*)outp)[oi] = f2b(v);
        else if (OMODE == 1) ((float*)outp)[oi] = v;
        else                 ((float*)outp)[oi] += v;
      }
    }
  }
}

// ---------------- batched x_proj GEMM: both directions in one launch -------
// Outputs: dtr_buf bf16 [2][8192][64] (cols 0..31 dtr, 32..63 zero-pad),
//          dbl f32 [8192][128] (per dir d: cols d*64+{0..15 B, 16..31 C}).
__global__ __launch_bounds__(256) void bgemm_kernel(
    const bf16* __restrict__ A, const bf16* __restrict__ W,
    bf16* __restrict__ dtr_buf, float* __restrict__ dbl)
{
  __shared__ char lsA[16384];
  __shared__ char lsB[16384];
  const int tid = threadIdx.x;
  const int w = tid >> 6, l = tid & 63;
  const int nwg = gridDim.x * 2;
  const int lin = blockIdx.y * gridDim.x + blockIdx.x;
  const int cpx = nwg >> 3;
  const int swz = (lin & 7) * cpx + (lin >> 3);
  const int m0 = (swz % gridDim.x) * 128;
  const int d  = swz / gridDim.x;
  const int K = 1024;
  const int wr = w >> 1, wc = w & 1;
  const size_t ldb = (size_t)K * 2;
  const char* Ab = (const char*)(A + (size_t)d*8388608) + (size_t)m0 * ldb;
  const char* Wb = (const char*)(W + (size_t)d*131072);

  const int srow = l >> 3;
  const int scb  = ((l & 7) ^ srow) << 4;
  const int fr = l & 15;
  const int fg = l >> 4;
  const int fsw = (fr & 7) << 4;

  f32x4 acc[4][4];
  #pragma unroll
  for (int m = 0; m < 4; ++m)
    #pragma unroll
    for (int n = 0; n < 4; ++n) acc[m][n] = (f32x4){0.f,0.f,0.f,0.f};

  const int nk = K >> 6;
  for (int kt = 0; kt < nk; ++kt){
    const char* As = Ab + (size_t)kt * 128;
    const char* Ws = Wb + (size_t)kt * 128;
    #pragma unroll
    for (int i = 0; i < 4; ++i){
      int row = (i*4 + w)*8 + srow;
      gload16(As + (size_t)row*ldb + scb, &lsA[(i*4 + w)*1024]);
    }
    #pragma unroll
    for (int i = 0; i < 4; ++i){
      int row = (i*4 + w)*8 + srow;
      gload16(Ws + (size_t)row*ldb + scb, &lsB[(i*4 + w)*1024]);
    }
    __syncthreads();

    s16x8 af[4][2], bfr[4][2];
    #pragma unroll
    for (int m = 0; m < 4; ++m){
      int row = wr*64 + m*16 + fr;
      af[m][0] = *(const s16x8*)&lsA[row*128 + (( 0 + fg*16) ^ fsw)];
      af[m][1] = *(const s16x8*)&lsA[row*128 + ((64 + fg*16) ^ fsw)];
    }
    #pragma unroll
    for (int n = 0; n < 4; ++n){
      int row = wc*64 + n*16 + fr;
      bfr[n][0] = *(const s16x8*)&lsB[row*128 + (( 0 + fg*16) ^ fsw)];
      bfr[n][1] = *(const s16x8*)&lsB[row*128 + ((64 + fg*16) ^ fsw)];
    }
    #pragma unroll
    for (int m = 0; m < 4; ++m)
      #pragma unroll
      for (int n = 0; n < 4; ++n){
        acc[m][n] = __builtin_amdgcn_mfma_f32_16x16x32_bf16(af[m][0], bfr[n][0], acc[m][n], 0, 0, 0);
        acc[m][n] = __builtin_amdgcn_mfma_f32_16x16x32_bf16(af[m][1], bfr[n][1], acc[m][n], 0, 0, 0);
      }
    __syncthreads();
  }

  const int orow0 = m0 + wr*64, c0 = wc*64;
  #pragma unroll
  for (int n = 0; n < 4; ++n){
    int col = c0 + n*16 + fr;                   // 0..127 within dir
    #pragma unroll
    for (int m = 0; m < 4; ++m){
      int rbase = orow0 + m*16 + fg*4;
      #pragma unroll
      for (int r = 0; r < 4; ++r){
        float v = acc[m][n][r];
        int row = rbase + r;
        if (col < 32)
          dtr_buf[((size_t)d*8192 + row)*64 + col] = f2b(v);
        else if (col < 64)
          dbl[(size_t)row*128 + d*64 + (col - 32)] = v;
        else if (col < 96)
          dtr_buf[((size_t)d*8192 + row)*64 + (col - 32)] = f2b(v);  // zeros (pad)
      }
    }
  }
}

// ---------------- stem im2col: x -> conv_a patches (bf16) + maxpool (bf16) --
__global__ __launch_bounds__(256) void im2col_kernel(
    const float* __restrict__ x_flat, bf16* __restrict__ Aa, bf16* __restrict__ P)
{
  __shared__ float xs[512][8];
  const int n = blockIdx.x, tid = threadIdx.x;
  const float* xr = x_flat + (size_t)n * 3584;
  for (int i = tid; i < 3584; i += 256) xs[i / 7][i % 7] = xr[i];
  __syncthreads();
  bf16* Ar = Aa + (size_t)n * 4 * 1536;
  for (int i = tid; i < 6144; i += 256){
    int t = i / 1536, col = i - t*1536;
    int c = col / 3, kk = col - c*3;
    int p = 2*t - 1 + kk;
    float v = (p >= 0 && p < 7) ? xs[c][p] : 0.f;
    Ar[i] = f2b(v);
  }
  bf16* Pr = P + (size_t)n * 4 * 512;
  for (int i = tid; i < 2048; i += 256){
    int t = i >> 9, c = i & 511;
    int st = 2*t - 1;
    float m = -1e30f;
    #pragma unroll
    for (int k = 0; k < 3; ++k){ int p = st + k; if (p >= 0 && p < 7) m = fmaxf(m, xs[c][p]); }
    Pr[i] = f2b(m);
  }
}

// ---------------- SE: mean over t -> 2 matvecs -> sigmoid -> scale h in place
__global__ __launch_bounds__(256) void se_kernel(
    const float* __restrict__ sw1, const float* __restrict__ sb1,
    const float* __restrict__ sw2, const float* __restrict__ sb2,
    float* __restrict__ h)
{
  __shared__ float yms[512];
  __shared__ float s1s[32];
  const int n = blockIdx.x, tid = threadIdx.x;
  float* hb = h + (size_t)n * 2048;
  for (int c = tid; c < 512; c += 256)
    yms[c] = 0.25f * (hb[c] + hb[512+c] + hb[1024+c] + hb[1536+c]);
  __syncthreads();
  {
    int o = tid >> 3, sl = tid & 7;
    const float* wr = sw1 + (size_t)o * 512 + sl*64;
    const float* ym = yms + sl*64;
    float a = 0.f;
    #pragma unroll 16
    for (int i = 0; i < 64; ++i) a += wr[i] * ym[i];
    a += __shfl_down(a, 4, 8);
    a += __shfl_down(a, 2, 8);
    a += __shfl_down(a, 1, 8);
    if (sl == 0) s1s[o] = fmaxf(a + sb1[o], 0.f);
  }
  __syncthreads();
  for (int c = tid; c < 512; c += 256){
    float a = sb2[c];
    const float* wr = sw2 + (size_t)c * 32;
    #pragma unroll
    for (int j = 0; j < 32; ++j) a += wr[j] * s1s[j];
    float s = 1.f / (1.f + __expf(-a));
    #pragma unroll
    for (int t = 0; t < 4; ++t) hb[t*512 + c] *= s;
  }
}

// ---------------- layernorm rows of 512: f32 in -> bf16 out ----------------
__global__ __launch_bounds__(256) void ln_kernel(
    const float* __restrict__ x, const float* __restrict__ g,
    const float* __restrict__ b, bf16* __restrict__ out)
{
  __shared__ float red[4];
  const int row = blockIdx.x, t = threadIdx.x;
  const float* xr = x + (size_t)row * 512;
  float v0 = xr[t], v1 = xr[t + 256];
  float s = block_sum256(v0 + v1, red);
  float mu = s * (1.f/512.f);
  float d0 = v0 - mu, d1 = v1 - mu;
  float sq = block_sum256(d0*d0 + d1*d1, red);
  float rstd = rsqrtf(sq * (1.f/512.f) + 1e-5f);
  out[(size_t)row*512 + t]       = f2b(d0*rstd*g[t]     + b[t]);
  out[(size_t)row*512 + t + 256] = f2b(d1*rstd*g[t+256] + b[t+256]);
}

// ---------------- final LN + mean over t -> feat bf16 [N][512] -------------
__global__ __launch_bounds__(256) void finalln_kernel(
    const float* __restrict__ h, const float* __restrict__ g,
    const float* __restrict__ b, bf16* __restrict__ feat)
{
  __shared__ float red[4];
  const int n = blockIdx.x, t = threadIdx.x;
  float a0 = 0.f, a1 = 0.f;
  for (int tt = 0; tt < 4; ++tt){
    const float* xr = h + ((size_t)n*4 + tt)*512;
    float v0 = xr[t], v1 = xr[t+256];
    float s = block_sum256(v0 + v1, red);
    float mu = s * (1.f/512.f);
    float d0 = v0 - mu, d1 = v1 - mu;
    float sq = block_sum256(d0*d0 + d1*d1, red);
    float rstd = rsqrtf(sq * (1.f/512.f) + 1e-5f);
    a0 += d0*rstd*g[t]     + b[t];
    a1 += d1*rstd*g[t+256] + b[t+256];
  }
  feat[(size_t)n*512 + t]       = f2b(a0 * 0.25f);
  feat[(size_t)n*512 + t + 256] = f2b(a1 * 0.25f);
}

// ---------------- causal dwconv (both dirs) + silu, 4 ch/thread ------------
__global__ __launch_bounds__(256) void dwconv2_kernel(
    const bf16* __restrict__ xz, const float* __restrict__ cw,
    const float* __restrict__ cb, bf16* __restrict__ u)
{
  const int n = blockIdx.x;
  const int c4 = threadIdx.x * 4;
  ushort4 in4[4];
  #pragma unroll
  for (int t = 0; t < 4; ++t)
    in4[t] = *reinterpret_cast<const ushort4*>(&xz[((size_t)n*4 + t)*2048 + c4]);
  #pragma unroll
  for (int d = 0; d < 2; ++d){
    const float* cwd = cw + d*4096;
    const float* cbd = cb + d*1024;
    ushort4 out[4];
    #pragma unroll
    for (int j = 0; j < 4; ++j){
      float xa[4];
      #pragma unroll
      for (int t = 0; t < 4; ++t){
        int ts = d ? 3 - t : t;
        unsigned short us = j==0?in4[ts].x : j==1?in4[ts].y : j==2?in4[ts].z : in4[ts].w;
        xa[t] = u2f(us);
      }
      float4 wv = *reinterpret_cast<const float4*>(&cwd[(c4 + j)*4]);
      float bb = cbd[c4 + j];
      float o[4];
      o[0] = xa[0]*wv.w + bb;
      o[1] = xa[0]*wv.z + xa[1]*wv.w + bb;
      o[2] = xa[0]*wv.y + xa[1]*wv.z + xa[2]*wv.w + bb;
      o[3] = xa[0]*wv.x + xa[1]*wv.y + xa[2]*wv.z + xa[3]*wv.w + bb;
      #pragma unroll
      for (int t = 0; t < 4; ++t){
        float v = o[t];
        float sv = v / (1.f + __expf(-v));
        unsigned short us = __bfloat16_as_ushort(f2b(sv));
        if (j==0) out[t].x = us; else if (j==1) out[t].y = us;
        else if (j==2) out[t].z = us; else out[t].w = us;
      }
    }
    #pragma unroll
    for (int t = 0; t < 4; ++t)
      *reinterpret_cast<ushort4*>(&u[(size_t)d*8388608 + ((size_t)n*4 + t)*1024 + c4]) = out[t];
  }
}

// ---------------- selective scan (L=4, S=16) + D term, per direction -------
// dbl f32 [8192][128]: dir d cols d*64+{0..15 B, 16..31 C}.
// dt (bf16 [8192][1024]): softplus-applied dt. Atab f32 [1024][16] = -exp(Alog).
__global__ __launch_bounds__(256) void scan_kernel(
    const float* __restrict__ dbl, const bf16* __restrict__ dt,
    const bf16* __restrict__ ud, const float* __restrict__ Atab,
    const float* __restrict__ Dp, int d, bf16* __restrict__ yd)
{
  __shared__ float Bs[4][16], Cs[4][16];
  const int n = blockIdx.x, g = blockIdx.y, tid = threadIdx.x;
  if (tid < 128){
    int t = tid >> 5, j = tid & 31;
    float v = dbl[((size_t)n*4 + t)*128 + d*64 + j];
    if (j < 16) Bs[t][j] = v; else Cs[t][j-16] = v;
  }
  __syncthreads();
  const int c = g*256 + tid;
  float A[16];
  {
    const float4* ap = reinterpret_cast<const float4*>(Atab + (size_t)c*16);
    #pragma unroll
    for (int q = 0; q < 4; ++q){
      float4 v = ap[q];
      A[q*4+0] = v.x; A[q*4+1] = v.y; A[q*4+2] = v.z; A[q*4+3] = v.w;
    }
  }
  const float Dpc = Dp[c];
  float hs[16];
  #pragma unroll
  for (int s = 0; s < 16; ++s) hs[s] = 0.f;
  #pragma unroll
  for (int t = 0; t < 4; ++t){
    float dtv = bfu(dt[((size_t)n*4 + t)*1024 + c]);
    float uv  = bfu(ud[((size_t)n*4 + t)*1024 + c]);
    float du = dtv * uv;
    float yv = 0.f;
    #pragma unroll
    for (int s = 0; s < 16; ++s){
      float dA = __expf(dtv * A[s]);
      hs[s] = dA * hs[s] + du * Bs[t][s];
      yv += hs[s] * Cs[t][s];
    }
    float out = yv + uv * Dpc;
    int to = d ? (3 - t) : t;
    yd[((size_t)n*4 + to)*1024 + c] = f2b(out);
  }
}

// ---------------- gate: gated = (y0+y1) * silu(z), 4 elems/thread ----------
__global__ __launch_bounds__(256) void gate_kernel(
    const bf16* __restrict__ y, const bf16* __restrict__ xz,
    bf16* __restrict__ gated)
{
  const int total4 = 8192 * 256;   // (8192*1024)/4
  for (int i = blockIdx.x*256 + threadIdx.x; i < total4; i += 2048*256){
    int row = i >> 8, c4 = (i & 255) << 2;
    ushort4 a4 = reinterpret_cast<const ushort4*>(y)[i];
    ushort4 b4 = reinterpret_cast<const ushort4*>(y + 8388608)[i];
    ushort4 z4 = *reinterpret_cast<const ushort4*>(&xz[(size_t)row*2048 + 1024 + c4]);
    float y0 = u2f(a4.x) + u2f(b4.x), y1 = u2f(a4.y) + u2f(b4.y);
    float y2 = u2f(a4.z) + u2f(b4.z), y3 = u2f(a4.w) + u2f(b4.w);
    float z0 = u2f(z4.x), z1 = u2f(z4.y), z2 = u2f(z4.z), z3 = u2f(z4.w);
    ushort4 o;
    o.x = __bfloat16_as_ushort(f2b(y0 * z0 / (1.f + __expf(-z0))));
    o.y = __bfloat16_as_ushort(f2b(y1 * z1 / (1.f + __expf(-z1))));
    o.z = __bfloat16_as_ushort(f2b(y2 * z2 / (1.f + __expf(-z2))));
    o.w = __bfloat16_as_ushort(f2b(y3 * z3 / (1.f + __expf(-z3))));
    reinterpret_cast<ushort4*>(gated)[i] = o;
  }
}

// ---------------- launch ---------------------------------------------------
extern "C" void kernel_launch(void* const* d_in, const int* in_sizes, int n_in,
                              void* d_out, int out_size, void* d_ws, size_t ws_size,
                              hipStream_t stream)
{
  const float* x_flat    = (const float*)d_in[0];
  const float* conv_a_w  = (const float*)d_in[1];
  const float* conv_p_w  = (const float*)d_in[2];
  const float* se_w1     = (const float*)d_in[3];
  const float* se_b1     = (const float*)d_in[4];
  const float* se_w2     = (const float*)d_in[5];
  const float* se_b2     = (const float*)d_in[6];
  const float* ln_g      = (const float*)d_in[7];
  const float* ln_b      = (const float*)d_in[8];
  const float* in_proj_w = (const float*)d_in[9];
  const float* conv_w    = (const float*)d_in[10];
  const float* conv_b    = (const float*)d_in[11];
  const float* x_proj_w  = (const float*)d_in[12];
  const float* dt_proj_w = (const float*)d_in[13];
  const float* dt_proj_b = (const float*)d_in[14];
  const float* A_log     = (const float*)d_in[15];
  const float* D_param   = (const float*)d_in[16];
  const float* out_proj_w= (const float*)d_in[17];
  const float* out_ln_g  = (const float*)d_in[18];
  const float* out_ln_b  = (const float*)d_in[19];
  const float* mlp_w1    = (const float*)d_in[20];
  const float* mlp_b1    = (const float*)d_in[21];
  const float* mlp_w2    = (const float*)d_in[22];
  const float* mlp_b2    = (const float*)d_in[23];

  char* ws = (char*)d_ws;
  const size_t OFF_H    = 0;                       // f32  8192*512  = 16.78MB
  const size_t OFF_HN   = OFF_H    + 16777216;     // bf16 8192*512  (feat overlay)
  const size_t OFF_XZ   = OFF_HN   + 8388608;      // bf16 8192*2048 (z1 overlay)
  const size_t OFF_U    = OFF_XZ   + 33554432;     // bf16 [2]*8192*1024 = 33.55MB
  const size_t OFF_SCR  = OFF_U    + 33554432;     // 25.17MB: Aa(stem)/dbl+dtr+dt(layers)/wb1(MLP)
  const size_t OFF_YB   = OFF_SCR  + 25165824;     // 33.55MB: Pm+wa+wp(stem)/y(layers)/wb2(MLP)
  const size_t OFF_WB   = OFF_YB   + 33554432;     // bf16 in_proj+out_proj
  const size_t OFF_WXP  = OFF_WB   + 6291456;      // bf16 2*256*1024 packed x_proj
  const size_t OFF_WDT  = OFF_WXP  + 1048576;      // bf16 4*1024*64 padded dt_proj
  const size_t OFF_ATAB = OFF_WDT  + 524288;       // f32  4*1024*16
  // total = OFF_ATAB + 262144 = ~160MB

  float* h    = (float*)(ws + OFF_H);
  bf16*  hn   = (bf16*) (ws + OFF_HN);
  bf16*  xz   = (bf16*) (ws + OFF_XZ);
  bf16*  u    = (bf16*) (ws + OFF_U);
  float* dbl  = (float*)(ws + OFF_SCR);                 // [8192][128] f32 = 4.19MB
  bf16*  dtrb = (bf16*) (ws + OFF_SCR + 4194304);       // [2][8192][64] bf16 = 2.10MB
  bf16*  dtb_ = (bf16*) (ws + OFF_SCR + 6291456);       // [8192][1024] bf16 = 16.78MB
  bf16*  y    = (bf16*) (ws + OFF_YB);
  bf16*  feat = (bf16*) (ws + OFF_HN);   // overlay
  bf16*  z1   = (bf16*) (ws + OFF_XZ);   // overlay
  bf16*  wbi  = (bf16*) (ws + OFF_WB);               // 2*2048*512
  bf16*  wbo  = (bf16*) (ws + OFF_WB + 4194304);     // 2*512*1024
  bf16*  wxp  = (bf16*) (ws + OFF_WXP);
  bf16*  wdtp = (bf16*) (ws + OFF_WDT);
  float* Atab = (float*)(ws + OFF_ATAB);
  bf16*  wb1  = (bf16*) (ws + OFF_SCR);  // overlay (MLP phase)
  bf16*  wb2  = (bf16*) (ws + OFF_YB);   // overlay (MLP phase)
  // stem-phase overlays
  bf16*  Aa   = (bf16*) (ws + OFF_SCR);                       // 8192*1536*2
  bf16*  Pm   = (bf16*) (ws + OFF_YB);                        // 8192*512*2
  bf16*  wa   = (bf16*) (ws + OFF_YB + 8388608);              // 256*1536*2
  bf16*  wp   = (bf16*) (ws + OFF_YB + 8388608 + 786432);     // 256*512*2
  float* outf = (float*)d_out;

  // weight conversions / tables
  f2b4_kernel<<<512,  256, 0, stream>>>((const float4*)conv_a_w,   (ushort4*)wa,  98304);
  f2b4_kernel<<<256,  256, 0, stream>>>((const float4*)conv_p_w,   (ushort4*)wp,  32768);
  f2b4_kernel<<<2048, 256, 0, stream>>>((const float4*)in_proj_w,  (ushort4*)wbi, 524288);
  f2b4_kernel<<<1024, 256, 0, stream>>>((const float4*)out_proj_w, (ushort4*)wbo, 262144);
  xpw_pad_kernel<<<2048, 256, 0, stream>>>(x_proj_w, wxp);
  wdt_pad_kernel<<<1024, 256, 0, stream>>>(dt_proj_w, wdtp);
  atab_kernel<<<256, 256, 0, stream>>>(A_log, Atab);

  // stem: im2col + MFMA GEMMs + SE
  im2col_kernel<<<2048, 256, 0, stream>>>(x_flat, Aa, Pm);
  mgemm_kernel<1,1,false><<<dim3(64,2), 256, 0, stream>>>(
      Aa, wa, nullptr, h, 1536, 512);
  mgemm_kernel<1,1,false><<<dim3(64,2), 256, 0, stream>>>(
      Pm, wp, nullptr, (float*)h + 256, 512, 512);
  se_kernel<<<2048, 256, 0, stream>>>(se_w1, se_b1, se_w2, se_b2, h);

  for (int l = 0; l < 2; ++l){
    ln_kernel<<<8192, 256, 0, stream>>>(h, ln_g + l*512, ln_b + l*512, hn);
    mgemm_kernel<0,0,false><<<dim3(64,16), 256, 0, stream>>>(
        hn, wbi + (size_t)l*2048*512, nullptr, xz, 512, 2048);
    dwconv2_kernel<<<2048, 256, 0, stream>>>(
        xz, conv_w + (size_t)l*8192, conv_b + (size_t)l*2048, u);
    bgemm_kernel<<<dim3(64,2), 256, 0, stream>>>(
        u, wxp + (size_t)l*262144, dtrb, dbl);
    for (int d = 0; d < 2; ++d){
      int ld = l*2 + d;
      mgemm_kernel<2,0,true><<<dim3(64,8), 256, 0, stream>>>(
          dtrb + (size_t)d*8192*64, wdtp + (size_t)ld*65536,
          dt_proj_b + (size_t)ld*1024, dtb_, 64, 1024);
      scan_kernel<<<dim3(2048,4), 256, 0, stream>>>(
          dbl, dtb_, u + (size_t)d*8388608, Atab + (size_t)ld*16384,
          D_param + (size_t)ld*1024, d, y + (size_t)d*8388608);
    }
    gate_kernel<<<2048, 256, 0, stream>>>(y, xz, u /* gated overlays u dir0 */);
    mgemm_kernel<0,2,false><<<dim3(64,4), 256, 0, stream>>>(
        u, wbo + (size_t)l*512*1024, nullptr, h, 1024, 512);
  }

  finalln_kernel<<<2048, 256, 0, stream>>>(h, out_ln_g, out_ln_b, feat);

  f2b4_kernel<<<1024, 256, 0, stream>>>((const float4*)mlp_w1, (ushort4*)wb1, 524288);
  f2b4_kernel<<<2048, 256, 0, stream>>>((const float4*)mlp_w2, (ushort4*)wb2, 4194304);

  mgemm_kernel<1,0,true><<<dim3(16,32), 256, 0, stream>>>(
      feat, wb1, mlp_b1, z1, 512, 4096);
  mgemm_kernel<1,1,true><<<dim3(16,32), 256, 0, stream>>>(
      z1, wb2, mlp_b2, outf, 4096, 4096);
}

// Round 9
// 717.146 us; speedup vs baseline: 3.7959x; 1.0298x over previous
//
#include <hip/hip_runtime.h>
#include <hip/hip_bf16.h>

typedef __hip_bfloat16 bf16;
typedef __attribute__((ext_vector_type(8))) short s16x8;
typedef __attribute__((ext_vector_type(4))) float f32x4;

__device__ __forceinline__ float u2f(unsigned short u){
  union { unsigned int i; float f; } v; v.i = ((unsigned int)u) << 16; return v.f;
}
__device__ __forceinline__ float bfu(bf16 x){ return __bfloat162float(x); }
__device__ __forceinline__ bf16  f2b(float x){ return __float2bfloat16(x); }

__device__ __forceinline__ void gload16(const void* g, void* l){
  __builtin_amdgcn_global_load_lds(
      (const __attribute__((address_space(1))) void*)g,
      (__attribute__((address_space(3))) void*)l, 16, 0, 0);
}

// ---------------- block reduction (256 threads) ----------------
__device__ __forceinline__ float block_sum256(float v, float* red){
  #pragma unroll
  for (int o = 32; o > 0; o >>= 1) v += __shfl_down(v, o, 64);
  int lane = threadIdx.x & 63, wid = threadIdx.x >> 6;
  if (lane == 0) red[wid] = v;
  __syncthreads();
  float r = red[0] + red[1] + red[2] + red[3];
  __syncthreads();
  return r;
}

// ---------------- fp32 -> bf16 weight conversion (vectorized) --------------
__global__ __launch_bounds__(256) void f2b4_kernel(
    const float4* __restrict__ in, ushort4* __restrict__ out, int n4)
{
  int stride = gridDim.x * 256;
  for (int i = blockIdx.x*256 + threadIdx.x; i < n4; i += stride){
    float4 v = in[i];
    ushort4 o;
    o.x = __bfloat16_as_ushort(f2b(v.x));
    o.y = __bfloat16_as_ushort(f2b(v.y));
    o.z = __bfloat16_as_ushort(f2b(v.z));
    o.w = __bfloat16_as_ushort(f2b(v.w));
    out[i] = o;
  }
}

// ---------------- x_proj weights -> packed [L][2*128][1024] bf16, 0-pad ----
__global__ __launch_bounds__(256) void xpw_pad_kernel(
    const float* __restrict__ xpw, bf16* __restrict__ out)
{
  int idx = blockIdx.x*256 + threadIdx.x;       // 2*256*1024 = 524288
  if (idx >= 524288) return;
  int l = idx >> 18, rem = idx & 262143, row = rem >> 10, c = rem & 1023;
  int d = row >> 7, r = row & 127;
  float v = (r < 64) ? xpw[(((size_t)l*2 + d)*64 + r)*1024 + c] : 0.f;
  out[idx] = f2b(v);
}

// ---------------- dt_proj weights: [4][1024][32] f32 -> [4][1024][64] bf16 --
__global__ __launch_bounds__(256) void wdt_pad_kernel(
    const float* __restrict__ dtw, bf16* __restrict__ out)
{
  int idx = blockIdx.x*256 + threadIdx.x;       // 4*1024*64 = 262144
  if (idx >= 262144) return;
  int ld = idx >> 16, rem = idx & 65535, r = rem >> 6, c = rem & 63;
  float v = (c < 32) ? dtw[((size_t)ld*1024 + r)*32 + c] : 0.f;
  out[idx] = f2b(v);
}

// ---------------- A table: Atab = -exp(A_log)*log2(e), [4][1024][16] f32 ---
__global__ __launch_bounds__(256) void atab_kernel(
    const float* __restrict__ Alog, float* __restrict__ Atab)
{
  int i = blockIdx.x*256 + threadIdx.x;         // 65536
  if (i < 65536) Atab[i] = -__expf(Alog[i]) * 1.44269504088896f;
}

// ---------------- MFMA GEMM: out[m,n] = act(sum_k A[m,k]*W[n,k] + bias[n])
// A,W bf16 row-major (leading dim = K). 128x128 tile, BK=64, 4 waves.
// Grid (m-tiles, n-tiles); TOTAL BLOCKS MUST BE %8==0 (XCD swizzle).
// ACT: 0 none, 1 relu, 2 softplus. OMODE: 0 bf16, 1 f32, 2 f32 +=.
template<int ACT, int OMODE, bool HASBIAS>
__global__ __launch_bounds__(256) void mgemm_kernel(
    const bf16* __restrict__ A, const bf16* __restrict__ W,
    const float* __restrict__ bias, void* __restrict__ outp,
    int K, int ldo)
{
  __shared__ char lsA[16384];
  __shared__ char lsB[16384];
  const int tid = threadIdx.x;
  const int w = tid >> 6, l = tid & 63;
  const int nwg = gridDim.x * gridDim.y;
  const int lin = blockIdx.y * gridDim.x + blockIdx.x;
  const int cpx = nwg >> 3;
  const int swz = (lin & 7) * cpx + (lin >> 3);
  const int m0 = (swz % gridDim.x) * 128, n0 = (swz / gridDim.x) * 128;
  const int wr = w >> 1, wc = w & 1;
  const size_t ldb = (size_t)K * 2;
  const char* Ab = (const char*)A + (size_t)m0 * ldb;
  const char* Wb = (const char*)W + (size_t)n0 * ldb;

  const int srow = l >> 3;
  const int scb  = ((l & 7) ^ srow) << 4;
  const int fr = l & 15;
  const int fg = l >> 4;
  const int fsw = (fr & 7) << 4;

  f32x4 acc[4][4];
  #pragma unroll
  for (int m = 0; m < 4; ++m)
    #pragma unroll
    for (int n = 0; n < 4; ++n) acc[m][n] = (f32x4){0.f,0.f,0.f,0.f};

  const int nk = K >> 6;
  for (int kt = 0; kt < nk; ++kt){
    const char* As = Ab + (size_t)kt * 128;
    const char* Ws = Wb + (size_t)kt * 128;
    #pragma unroll
    for (int i = 0; i < 4; ++i){
      int row = (i*4 + w)*8 + srow;
      gload16(As + (size_t)row*ldb + scb, &lsA[(i*4 + w)*1024]);
    }
    #pragma unroll
    for (int i = 0; i < 4; ++i){
      int row = (i*4 + w)*8 + srow;
      gload16(Ws + (size_t)row*ldb + scb, &lsB[(i*4 + w)*1024]);
    }
    __syncthreads();

    s16x8 af[4][2], bfr[4][2];
    #pragma unroll
    for (int m = 0; m < 4; ++m){
      int row = wr*64 + m*16 + fr;
      af[m][0] = *(const s16x8*)&lsA[row*128 + (( 0 + fg*16) ^ fsw)];
      af[m][1] = *(const s16x8*)&lsA[row*128 + ((64 + fg*16) ^ fsw)];
    }
    #pragma unroll
    for (int n = 0; n < 4; ++n){
      int row = wc*64 + n*16 + fr;
      bfr[n][0] = *(const s16x8*)&lsB[row*128 + (( 0 + fg*16) ^ fsw)];
      bfr[n][1] = *(const s16x8*)&lsB[row*128 + ((64 + fg*16) ^ fsw)];
    }
    #pragma unroll
    for (int m = 0; m < 4; ++m)
      #pragma unroll
      for (int n = 0; n < 4; ++n){
        acc[m][n] = __builtin_amdgcn_mfma_f32_16x16x32_bf16(af[m][0], bfr[n][0], acc[m][n], 0, 0, 0);
        acc[m][n] = __builtin_amdgcn_mfma_f32_16x16x32_bf16(af[m][1], bfr[n][1], acc[m][n], 0, 0, 0);
      }
    __syncthreads();
  }

  const int orow0 = m0 + wr*64, ocol0 = n0 + wc*64;
  #pragma unroll
  for (int n = 0; n < 4; ++n){
    int col = ocol0 + n*16 + fr;
    float bv = HASBIAS ? bias[col] : 0.f;
    #pragma unroll
    for (int m = 0; m < 4; ++m){
      int rbase = orow0 + m*16 + fg*4;
      #pragma unroll
      for (int r = 0; r < 4; ++r){
        float v = acc[m][n][r] + bv;
        if (ACT == 1) v = fmaxf(v, 0.f);
        if (ACT == 2) v = (v > 20.f) ? v : log1pf(__expf(v));
        size_t oi = (size_t)(rbase + r) * ldo + col;
        if (OMODE == 0)      ((bf16*)outp)[oi] = f2b(v);
        else if (OMODE == 1) ((float*)outp)[oi] = v;
        else                 ((float*)outp)[oi] += v;
      }
    }
  }
}

// ---------------- batched x_proj GEMM: both directions in one launch -------
// Outputs: dtr_buf bf16 [2][8192][64] (cols 0..31 dtr, 32..63 zero-pad),
//          dbl f32 [8192][128] (per dir d: cols d*64+{0..15 B, 16..31 C}).
__global__ __launch_bounds__(256) void bgemm_kernel(
    const bf16* __restrict__ A, const bf16* __restrict__ W,
    bf16* __restrict__ dtr_buf, float* __restrict__ dbl)
{
  __shared__ char lsA[16384];
  __shared__ char lsB[16384];
  const int tid = threadIdx.x;
  const int w = tid >> 6, l = tid & 63;
  const int nwg = gridDim.x * 2;
  const int lin = blockIdx.y * gridDim.x + blockIdx.x;
  const int cpx = nwg >> 3;
  const int swz = (lin & 7) * cpx + (lin >> 3);
  const int m0 = (swz % gridDim.x) * 128;
  const int d  = swz / gridDim.x;
  const int K = 1024;
  const int wr = w >> 1, wc = w & 1;
  const size_t ldb = (size_t)K * 2;
  const char* Ab = (const char*)(A + (size_t)d*8388608) + (size_t)m0 * ldb;
  const char* Wb = (const char*)(W + (size_t)d*131072);

  const int srow = l >> 3;
  const int scb  = ((l & 7) ^ srow) << 4;
  const int fr = l & 15;
  const int fg = l >> 4;
  const int fsw = (fr & 7) << 4;

  f32x4 acc[4][4];
  #pragma unroll
  for (int m = 0; m < 4; ++m)
    #pragma unroll
    for (int n = 0; n < 4; ++n) acc[m][n] = (f32x4){0.f,0.f,0.f,0.f};

  const int nk = K >> 6;
  for (int kt = 0; kt < nk; ++kt){
    const char* As = Ab + (size_t)kt * 128;
    const char* Ws = Wb + (size_t)kt * 128;
    #pragma unroll
    for (int i = 0; i < 4; ++i){
      int row = (i*4 + w)*8 + srow;
      gload16(As + (size_t)row*ldb + scb, &lsA[(i*4 + w)*1024]);
    }
    #pragma unroll
    for (int i = 0; i < 4; ++i){
      int row = (i*4 + w)*8 + srow;
      gload16(Ws + (size_t)row*ldb + scb, &lsB[(i*4 + w)*1024]);
    }
    __syncthreads();

    s16x8 af[4][2], bfr[4][2];
    #pragma unroll
    for (int m = 0; m < 4; ++m){
      int row = wr*64 + m*16 + fr;
      af[m][0] = *(const s16x8*)&lsA[row*128 + (( 0 + fg*16) ^ fsw)];
      af[m][1] = *(const s16x8*)&lsA[row*128 + ((64 + fg*16) ^ fsw)];
    }
    #pragma unroll
    for (int n = 0; n < 4; ++n){
      int row = wc*64 + n*16 + fr;
      bfr[n][0] = *(const s16x8*)&lsB[row*128 + (( 0 + fg*16) ^ fsw)];
      bfr[n][1] = *(const s16x8*)&lsB[row*128 + ((64 + fg*16) ^ fsw)];
    }
    #pragma unroll
    for (int m = 0; m < 4; ++m)
      #pragma unroll
      for (int n = 0; n < 4; ++n){
        acc[m][n] = __builtin_amdgcn_mfma_f32_16x16x32_bf16(af[m][0], bfr[n][0], acc[m][n], 0, 0, 0);
        acc[m][n] = __builtin_amdgcn_mfma_f32_16x16x32_bf16(af[m][1], bfr[n][1], acc[m][n], 0, 0, 0);
      }
    __syncthreads();
  }

  const int orow0 = m0 + wr*64, c0 = wc*64;
  #pragma unroll
  for (int n = 0; n < 4; ++n){
    int col = c0 + n*16 + fr;                   // 0..127 within dir
    #pragma unroll
    for (int m = 0; m < 4; ++m){
      int rbase = orow0 + m*16 + fg*4;
      #pragma unroll
      for (int r = 0; r < 4; ++r){
        float v = acc[m][n][r];
        int row = rbase + r;
        if (col < 32)
          dtr_buf[((size_t)d*8192 + row)*64 + col] = f2b(v);
        else if (col < 64)
          dbl[(size_t)row*128 + d*64 + (col - 32)] = v;
        else if (col < 96)
          dtr_buf[((size_t)d*8192 + row)*64 + (col - 32)] = f2b(v);  // zeros (pad)
      }
    }
  }
}

// ---------------- stem im2col: x -> conv_a patches (bf16) + maxpool (bf16) --
__global__ __launch_bounds__(256) void im2col_kernel(
    const float* __restrict__ x_flat, bf16* __restrict__ Aa, bf16* __restrict__ P)
{
  __shared__ float xs[512][8];
  const int n = blockIdx.x, tid = threadIdx.x;
  const float* xr = x_flat + (size_t)n * 3584;
  for (int i = tid; i < 3584; i += 256) xs[i / 7][i % 7] = xr[i];
  __syncthreads();
  bf16* Ar = Aa + (size_t)n * 4 * 1536;
  for (int i = tid; i < 6144; i += 256){
    int t = i / 1536, col = i - t*1536;
    int c = col / 3, kk = col - c*3;
    int p = 2*t - 1 + kk;
    float v = (p >= 0 && p < 7) ? xs[c][p] : 0.f;
    Ar[i] = f2b(v);
  }
  bf16* Pr = P + (size_t)n * 4 * 512;
  for (int i = tid; i < 2048; i += 256){
    int t = i >> 9, c = i & 511;
    int st = 2*t - 1;
    float m = -1e30f;
    #pragma unroll
    for (int k = 0; k < 3; ++k){ int p = st + k; if (p >= 0 && p < 7) m = fmaxf(m, xs[c][p]); }
    Pr[i] = f2b(m);
  }
}

// ---------------- SE: mean over t -> 2 matvecs -> sigmoid -> scale h in place
__global__ __launch_bounds__(256) void se_kernel(
    const float* __restrict__ sw1, const float* __restrict__ sb1,
    const float* __restrict__ sw2, const float* __restrict__ sb2,
    float* __restrict__ h)
{
  __shared__ float yms[512];
  __shared__ float s1s[32];
  const int n = blockIdx.x, tid = threadIdx.x;
  float* hb = h + (size_t)n * 2048;
  for (int c = tid; c < 512; c += 256)
    yms[c] = 0.25f * (hb[c] + hb[512+c] + hb[1024+c] + hb[1536+c]);
  __syncthreads();
  {
    int o = tid >> 3, sl = tid & 7;
    const float* wr = sw1 + (size_t)o * 512 + sl*64;
    const float* ym = yms + sl*64;
    float a = 0.f;
    #pragma unroll 16
    for (int i = 0; i < 64; ++i) a += wr[i] * ym[i];
    a += __shfl_down(a, 4, 8);
    a += __shfl_down(a, 2, 8);
    a += __shfl_down(a, 1, 8);
    if (sl == 0) s1s[o] = fmaxf(a + sb1[o], 0.f);
  }
  __syncthreads();
  for (int c = tid; c < 512; c += 256){
    float a = sb2[c];
    const float* wr = sw2 + (size_t)c * 32;
    #pragma unroll
    for (int j = 0; j < 32; ++j) a += wr[j] * s1s[j];
    float s = 1.f / (1.f + __expf(-a));
    #pragma unroll
    for (int t = 0; t < 4; ++t) hb[t*512 + c] *= s;
  }
}

// ---------------- layernorm rows of 512: f32 in -> bf16 out ----------------
__global__ __launch_bounds__(256) void ln_kernel(
    const float* __restrict__ x, const float* __restrict__ g,
    const float* __restrict__ b, bf16* __restrict__ out)
{
  __shared__ float red[4];
  const int row = blockIdx.x, t = threadIdx.x;
  const float* xr = x + (size_t)row * 512;
  float v0 = xr[t], v1 = xr[t + 256];
  float s = block_sum256(v0 + v1, red);
  float mu = s * (1.f/512.f);
  float d0 = v0 - mu, d1 = v1 - mu;
  float sq = block_sum256(d0*d0 + d1*d1, red);
  float rstd = rsqrtf(sq * (1.f/512.f) + 1e-5f);
  out[(size_t)row*512 + t]       = f2b(d0*rstd*g[t]     + b[t]);
  out[(size_t)row*512 + t + 256] = f2b(d1*rstd*g[t+256] + b[t+256]);
}

// ---------------- final LN + mean over t -> feat bf16 [N][512] -------------
__global__ __launch_bounds__(256) void finalln_kernel(
    const float* __restrict__ h, const float* __restrict__ g,
    const float* __restrict__ b, bf16* __restrict__ feat)
{
  __shared__ float red[4];
  const int n = blockIdx.x, t = threadIdx.x;
  float a0 = 0.f, a1 = 0.f;
  for (int tt = 0; tt < 4; ++tt){
    const float* xr = h + ((size_t)n*4 + tt)*512;
    float v0 = xr[t], v1 = xr[t+256];
    float s = block_sum256(v0 + v1, red);
    float mu = s * (1.f/512.f);
    float d0 = v0 - mu, d1 = v1 - mu;
    float sq = block_sum256(d0*d0 + d1*d1, red);
    float rstd = rsqrtf(sq * (1.f/512.f) + 1e-5f);
    a0 += d0*rstd*g[t]     + b[t];
    a1 += d1*rstd*g[t+256] + b[t+256];
  }
  feat[(size_t)n*512 + t]       = f2b(a0 * 0.25f);
  feat[(size_t)n*512 + t + 256] = f2b(a1 * 0.25f);
}

// ---------------- causal dwconv (both dirs) + silu, 4 ch/thread ------------
__global__ __launch_bounds__(256) void dwconv2_kernel(
    const bf16* __restrict__ xz, const float* __restrict__ cw,
    const float* __restrict__ cb, bf16* __restrict__ u)
{
  const int n = blockIdx.x;
  const int c4 = threadIdx.x * 4;
  ushort4 in4[4];
  #pragma unroll
  for (int t = 0; t < 4; ++t)
    in4[t] = *reinterpret_cast<const ushort4*>(&xz[((size_t)n*4 + t)*2048 + c4]);
  #pragma unroll
  for (int d = 0; d < 2; ++d){
    const float* cwd = cw + d*4096;
    const float* cbd = cb + d*1024;
    ushort4 out[4];
    #pragma unroll
    for (int j = 0; j < 4; ++j){
      float xa[4];
      #pragma unroll
      for (int t = 0; t < 4; ++t){
        int ts = d ? 3 - t : t;
        unsigned short us = j==0?in4[ts].x : j==1?in4[ts].y : j==2?in4[ts].z : in4[ts].w;
        xa[t] = u2f(us);
      }
      float4 wv = *reinterpret_cast<const float4*>(&cwd[(c4 + j)*4]);
      float bb = cbd[c4 + j];
      float o[4];
      o[0] = xa[0]*wv.w + bb;
      o[1] = xa[0]*wv.z + xa[1]*wv.w + bb;
      o[2] = xa[0]*wv.y + xa[1]*wv.z + xa[2]*wv.w + bb;
      o[3] = xa[0]*wv.x + xa[1]*wv.y + xa[2]*wv.z + xa[3]*wv.w + bb;
      #pragma unroll
      for (int t = 0; t < 4; ++t){
        float v = o[t];
        float sv = v / (1.f + __expf(-v));
        unsigned short us = __bfloat16_as_ushort(f2b(sv));
        if (j==0) out[t].x = us; else if (j==1) out[t].y = us;
        else if (j==2) out[t].z = us; else out[t].w = us;
      }
    }
    #pragma unroll
    for (int t = 0; t < 4; ++t)
      *reinterpret_cast<ushort4*>(&u[(size_t)d*8388608 + ((size_t)n*4 + t)*1024 + c4]) = out[t];
  }
}

// ---------------- fused bidirectional scan + gate --------------------------
// dbl f32 [8192][128]: dir d cols d*64+{0..15 B, 16..31 C}.
// dt2 bf16 [2][8192][1024] (softplus applied). Atab2 (pre-scaled by log2e):
// dir0 at +0, dir1 at +16384. Output gated (over u dir0):
// gated[t][c] = (y0[t] + y1[t]) * silu(z[t][c]).
__global__ __launch_bounds__(256) void scan2_kernel(
    const float* __restrict__ dbl, const bf16* __restrict__ dt2,
    const bf16* __restrict__ u, const bf16* __restrict__ xz,
    const float* __restrict__ Atab2, const float* __restrict__ Dp,
    bf16* __restrict__ gated)
{
  __shared__ float Bs[2][4][16], Cs[2][4][16];
  const int n = blockIdx.x, g = blockIdx.y, tid = threadIdx.x;
  {
    int t = tid >> 6, j = tid & 63;      // 256 threads: t 0..3, j 0..63
    int d = j >> 5, jj = j & 31;
    float v = dbl[((size_t)n*4 + t)*128 + d*64 + jj];
    if (jj < 16) Bs[d][t][jj] = v; else Cs[d][t][jj-16] = v;
  }
  __syncthreads();
  const int c = g*256 + tid;
  const size_t base = (size_t)n*4*1024 + c;
  float yo0[4], yo1[4];
  float hs[16];
  // ---- direction 0 ----
  {
    float A[16];
    const float4* ap = reinterpret_cast<const float4*>(Atab2 + (size_t)c*16);
    #pragma unroll
    for (int q = 0; q < 4; ++q){
      float4 v = ap[q];
      A[q*4+0]=v.x; A[q*4+1]=v.y; A[q*4+2]=v.z; A[q*4+3]=v.w;
    }
    const float Dpc = Dp[c];
    #pragma unroll
    for (int s = 0; s < 16; ++s) hs[s] = 0.f;
    #pragma unroll
    for (int t = 0; t < 4; ++t){
      float dtv = bfu(dt2[base + (size_t)t*1024]);
      float uv  = bfu(u  [base + (size_t)t*1024]);
      float du = dtv * uv;
      float yv = 0.f;
      #pragma unroll
      for (int s = 0; s < 16; ++s){
        float dA = __builtin_amdgcn_exp2f(dtv * A[s]);
        hs[s] = dA * hs[s] + du * Bs[0][t][s];
        yv += hs[s] * Cs[0][t][s];
      }
      yo0[t] = yv + uv * Dpc;
    }
  }
  // ---- direction 1 (time-reversed input; output flipped) ----
  {
    float A[16];
    const float4* ap = reinterpret_cast<const float4*>(Atab2 + 16384 + (size_t)c*16);
    #pragma unroll
    for (int q = 0; q < 4; ++q){
      float4 v = ap[q];
      A[q*4+0]=v.x; A[q*4+1]=v.y; A[q*4+2]=v.z; A[q*4+3]=v.w;
    }
    const float Dpc = Dp[1024 + c];
    #pragma unroll
    for (int s = 0; s < 16; ++s) hs[s] = 0.f;
    #pragma unroll
    for (int t = 0; t < 4; ++t){
      float dtv = bfu(dt2[8388608 + base + (size_t)t*1024]);
      float uv  = bfu(u  [8388608 + base + (size_t)t*1024]);
      float du = dtv * uv;
      float yv = 0.f;
      #pragma unroll
      for (int s = 0; s < 16; ++s){
        float dA = __builtin_amdgcn_exp2f(dtv * A[s]);
        hs[s] = dA * hs[s] + du * Bs[1][t][s];
        yv += hs[s] * Cs[1][t][s];
      }
      yo1[3 - t] = yv + uv * Dpc;
    }
  }
  // ---- gate + store (overwrites u dir0; same thread wrote/read only c) ----
  #pragma unroll
  for (int t = 0; t < 4; ++t){
    float z = bfu(xz[(size_t)(n*4 + t)*2048 + 1024 + c]);
    float sv = z / (1.f + __expf(-z));
    gated[base + (size_t)t*1024] = f2b((yo0[t] + yo1[t]) * sv);
  }
}

// ---------------- launch ---------------------------------------------------
extern "C" void kernel_launch(void* const* d_in, const int* in_sizes, int n_in,
                              void* d_out, int out_size, void* d_ws, size_t ws_size,
                              hipStream_t stream)
{
  const float* x_flat    = (const float*)d_in[0];
  const float* conv_a_w  = (const float*)d_in[1];
  const float* conv_p_w  = (const float*)d_in[2];
  const float* se_w1     = (const float*)d_in[3];
  const float* se_b1     = (const float*)d_in[4];
  const float* se_w2     = (const float*)d_in[5];
  const float* se_b2     = (const float*)d_in[6];
  const float* ln_g      = (const float*)d_in[7];
  const float* ln_b      = (const float*)d_in[8];
  const float* in_proj_w = (const float*)d_in[9];
  const float* conv_w    = (const float*)d_in[10];
  const float* conv_b    = (const float*)d_in[11];
  const float* x_proj_w  = (const float*)d_in[12];
  const float* dt_proj_w = (const float*)d_in[13];
  const float* dt_proj_b = (const float*)d_in[14];
  const float* A_log     = (const float*)d_in[15];
  const float* D_param   = (const float*)d_in[16];
  const float* out_proj_w= (const float*)d_in[17];
  const float* out_ln_g  = (const float*)d_in[18];
  const float* out_ln_b  = (const float*)d_in[19];
  const float* mlp_w1    = (const float*)d_in[20];
  const float* mlp_b1    = (const float*)d_in[21];
  const float* mlp_w2    = (const float*)d_in[22];
  const float* mlp_b2    = (const float*)d_in[23];

  char* ws = (char*)d_ws;
  const size_t OFF_H    = 0;                       // f32  8192*512  = 16.78MB
  const size_t OFF_HN   = OFF_H    + 16777216;     // bf16 8192*512  (feat overlay)
  const size_t OFF_XZ   = OFF_HN   + 8388608;      // bf16 8192*2048 (z1 overlay)
  const size_t OFF_U    = OFF_XZ   + 33554432;     // bf16 [2]*8192*1024 = 33.55MB
  const size_t OFF_SCR  = OFF_U    + 33554432;     // 25.17MB: Aa(stem)/dbl+dtrb(layers)/wb1(MLP)
  const size_t OFF_YB   = OFF_SCR  + 25165824;     // 33.55MB: Pm+wa+wp(stem)/dt2(layers)/wb2(MLP)
  const size_t OFF_WB   = OFF_YB   + 33554432;     // bf16 in_proj+out_proj
  const size_t OFF_WXP  = OFF_WB   + 6291456;      // bf16 2*256*1024 packed x_proj
  const size_t OFF_WDT  = OFF_WXP  + 1048576;      // bf16 4*1024*64 padded dt_proj
  const size_t OFF_ATAB = OFF_WDT  + 524288;       // f32  4*1024*16
  // total = OFF_ATAB + 262144 = ~160MB

  float* h    = (float*)(ws + OFF_H);
  bf16*  hn   = (bf16*) (ws + OFF_HN);
  bf16*  xz   = (bf16*) (ws + OFF_XZ);
  bf16*  u    = (bf16*) (ws + OFF_U);
  float* dbl  = (float*)(ws + OFF_SCR);                 // [8192][128] f32 = 4.19MB
  bf16*  dtrb = (bf16*) (ws + OFF_SCR + 4194304);       // [2][8192][64] bf16 = 2.10MB
  bf16*  dt2  = (bf16*) (ws + OFF_YB);                  // [2][8192][1024] bf16 = 33.55MB
  bf16*  feat = (bf16*) (ws + OFF_HN);   // overlay
  bf16*  z1   = (bf16*) (ws + OFF_XZ);   // overlay
  bf16*  wbi  = (bf16*) (ws + OFF_WB);               // 2*2048*512
  bf16*  wbo  = (bf16*) (ws + OFF_WB + 4194304);     // 2*512*1024
  bf16*  wxp  = (bf16*) (ws + OFF_WXP);
  bf16*  wdtp = (bf16*) (ws + OFF_WDT);
  float* Atab = (float*)(ws + OFF_ATAB);
  bf16*  wb1  = (bf16*) (ws + OFF_SCR);  // overlay (MLP phase)
  bf16*  wb2  = (bf16*) (ws + OFF_YB);   // overlay (MLP phase)
  // stem-phase overlays
  bf16*  Aa   = (bf16*) (ws + OFF_SCR);                       // 8192*1536*2
  bf16*  Pm   = (bf16*) (ws + OFF_YB);                        // 8192*512*2
  bf16*  wa   = (bf16*) (ws + OFF_YB + 8388608);              // 256*1536*2
  bf16*  wp   = (bf16*) (ws + OFF_YB + 8388608 + 786432);     // 256*512*2
  float* outf = (float*)d_out;

  // weight conversions / tables
  f2b4_kernel<<<512,  256, 0, stream>>>((const float4*)conv_a_w,   (ushort4*)wa,  98304);
  f2b4_kernel<<<256,  256, 0, stream>>>((const float4*)conv_p_w,   (ushort4*)wp,  32768);
  f2b4_kernel<<<2048, 256, 0, stream>>>((const float4*)in_proj_w,  (ushort4*)wbi, 524288);
  f2b4_kernel<<<1024, 256, 0, stream>>>((const float4*)out_proj_w, (ushort4*)wbo, 262144);
  xpw_pad_kernel<<<2048, 256, 0, stream>>>(x_proj_w, wxp);
  wdt_pad_kernel<<<1024, 256, 0, stream>>>(dt_proj_w, wdtp);
  atab_kernel<<<256, 256, 0, stream>>>(A_log, Atab);

  // stem: im2col + MFMA GEMMs + SE
  im2col_kernel<<<2048, 256, 0, stream>>>(x_flat, Aa, Pm);
  mgemm_kernel<1,1,false><<<dim3(64,2), 256, 0, stream>>>(
      Aa, wa, nullptr, h, 1536, 512);
  mgemm_kernel<1,1,false><<<dim3(64,2), 256, 0, stream>>>(
      Pm, wp, nullptr, (float*)h + 256, 512, 512);
  se_kernel<<<2048, 256, 0, stream>>>(se_w1, se_b1, se_w2, se_b2, h);

  for (int l = 0; l < 2; ++l){
    ln_kernel<<<8192, 256, 0, stream>>>(h, ln_g + l*512, ln_b + l*512, hn);
    mgemm_kernel<0,0,false><<<dim3(64,16), 256, 0, stream>>>(
        hn, wbi + (size_t)l*2048*512, nullptr, xz, 512, 2048);
    dwconv2_kernel<<<2048, 256, 0, stream>>>(
        xz, conv_w + (size_t)l*8192, conv_b + (size_t)l*2048, u);
    bgemm_kernel<<<dim3(64,2), 256, 0, stream>>>(
        u, wxp + (size_t)l*262144, dtrb, dbl);
    for (int d = 0; d < 2; ++d){
      int ld = l*2 + d;
      mgemm_kernel<2,0,true><<<dim3(64,8), 256, 0, stream>>>(
          dtrb + (size_t)d*8192*64, wdtp + (size_t)ld*65536,
          dt_proj_b + (size_t)ld*1024, dt2 + (size_t)d*8388608, 64, 1024);
    }
    scan2_kernel<<<dim3(2048,4), 256, 0, stream>>>(
        dbl, dt2, u, xz, Atab + (size_t)l*32768, D_param + (size_t)l*2048,
        u /* gated overlays u dir0 */);
    mgemm_kernel<0,2,false><<<dim3(64,4), 256, 0, stream>>>(
        u, wbo + (size_t)l*512*1024, nullptr, h, 1024, 512);
  }

  finalln_kernel<<<2048, 256, 0, stream>>>(h, out_ln_g, out_ln_b, feat);

  f2b4_kernel<<<1024, 256, 0, stream>>>((const float4*)mlp_w1, (ushort4*)wb1, 524288);
  f2b4_kernel<<<2048, 256, 0, stream>>>((const float4*)mlp_w2, (ushort4*)wb2, 4194304);

  mgemm_kernel<1,0,true><<<dim3(16,32), 256, 0, stream>>>(
      feat, wb1, mlp_b1, z1, 512, 4096);
  mgemm_kernel<1,1,true><<<dim3(16,32), 256, 0, stream>>>(
      z1, wb2, mlp_b2, outf, 4096, 4096);
}

// Round 10
// 715.265 us; speedup vs baseline: 3.8059x; 1.0026x over previous
//
#include <hip/hip_runtime.h>
#include <hip/hip_bf16.h>

typedef __hip_bfloat16 bf16;
typedef __attribute__((ext_vector_type(8))) short s16x8;
typedef __attribute__((ext_vector_type(4))) float f32x4;

__device__ __forceinline__ float u2f(unsigned short u){
  union { unsigned int i; float f; } v; v.i = ((unsigned int)u) << 16; return v.f;
}
__device__ __forceinline__ float bfu(bf16 x){ return __bfloat162float(x); }
__device__ __forceinline__ bf16  f2b(float x){ return __float2bfloat16(x); }

__device__ __forceinline__ void gload16(const void* g, void* l){
  __builtin_amdgcn_global_load_lds(
      (const __attribute__((address_space(1))) void*)g,
      (__attribute__((address_space(3))) void*)l, 16, 0, 0);
}

// ---------------- block reduction (256 threads) ----------------
__device__ __forceinline__ float block_sum256(float v, float* red){
  #pragma unroll
  for (int o = 32; o > 0; o >>= 1) v += __shfl_down(v, o, 64);
  int lane = threadIdx.x & 63, wid = threadIdx.x >> 6;
  if (lane == 0) red[wid] = v;
  __syncthreads();
  float r = red[0] + red[1] + red[2] + red[3];
  __syncthreads();
  return r;
}

__device__ __forceinline__ ushort4 cvt4(float4 v){
  ushort4 o;
  o.x = __bfloat16_as_ushort(f2b(v.x));
  o.y = __bfloat16_as_ushort(f2b(v.y));
  o.z = __bfloat16_as_ushort(f2b(v.z));
  o.w = __bfloat16_as_ushort(f2b(v.w));
  return o;
}

// ---------------- unified prep: all weight conversions in ONE dispatch -----
// segs (f4 units): wa 98304 | wp 32768 | wbi 524288 | wbo 262144  (sum 917504)
// then elems: xpw-pad 524288 | wdt-pad 262144 | atab 65536   total 1769472
__global__ __launch_bounds__(256) void prep_kernel(
    const float* __restrict__ caw, const float* __restrict__ cpw,
    const float* __restrict__ ipw, const float* __restrict__ opw,
    const float* __restrict__ xpw, const float* __restrict__ dtw,
    const float* __restrict__ alog,
    bf16* __restrict__ wa, bf16* __restrict__ wp,
    bf16* __restrict__ wbi, bf16* __restrict__ wbo,
    bf16* __restrict__ wxp, bf16* __restrict__ wdtp,
    float* __restrict__ atab)
{
  for (int i = blockIdx.x*256 + threadIdx.x; i < 1769472; i += gridDim.x*256){
    if (i < 917504){
      int j = i;
      const float4* src; ushort4* dst;
      if (j < 98304)      { src = (const float4*)caw; dst = (ushort4*)wa; }
      else if (j < 131072){ j -= 98304;  src = (const float4*)cpw; dst = (ushort4*)wp; }
      else if (j < 655360){ j -= 131072; src = (const float4*)ipw; dst = (ushort4*)wbi; }
      else                { j -= 655360; src = (const float4*)opw; dst = (ushort4*)wbo; }
      dst[j] = cvt4(src[j]);
    } else if (i < 1441792){
      int idx = i - 917504;                 // xpw pad: [L][2*128][1024]
      int l = idx >> 18, rem = idx & 262143, row = rem >> 10, c = rem & 1023;
      int d = row >> 7, r = row & 127;
      float v = (r < 64) ? xpw[(((size_t)l*2 + d)*64 + r)*1024 + c] : 0.f;
      wxp[idx] = f2b(v);
    } else if (i < 1703936){
      int idx = i - 1441792;                // wdt pad: [4][1024][64]
      int ld = idx >> 16, rem = idx & 65535, r = rem >> 6, cc = rem & 63;
      float v = (cc < 32) ? dtw[((size_t)ld*1024 + r)*32 + cc] : 0.f;
      wdtp[idx] = f2b(v);
    } else {
      int idx = i - 1703936;                // atab
      atab[idx] = -__expf(alog[idx]) * 1.44269504088896f;
    }
  }
}

// ---------------- MLP weight conversion (one dispatch) ---------------------
__global__ __launch_bounds__(256) void mlpprep_kernel(
    const float4* __restrict__ w1, const float4* __restrict__ w2,
    ushort4* __restrict__ o1, ushort4* __restrict__ o2)
{
  for (int i = blockIdx.x*256 + threadIdx.x; i < 4718592; i += gridDim.x*256){
    if (i < 524288) o1[i] = cvt4(w1[i]);
    else            o2[i - 524288] = cvt4(w2[i - 524288]);
  }
}

// ---------------- MFMA GEMM: out[m,n] = act(sum_k A[m,k]*W[n,k] + bias[n])
// A,W bf16 row-major (ld = K). 128x128 tile, BK=64, 4 waves. nwg%8==0.
// ACT: 0 none, 1 relu, 2 softplus. OMODE: 0 bf16, 1 f32, 2 f32 +=.
template<int ACT, int OMODE, bool HASBIAS>
__global__ __launch_bounds__(256) void mgemm_kernel(
    const bf16* __restrict__ A, const bf16* __restrict__ W,
    const float* __restrict__ bias, void* __restrict__ outp,
    int K, int ldo)
{
  __shared__ char lsA[16384];
  __shared__ char lsB[16384];
  const int tid = threadIdx.x;
  const int w = tid >> 6, l = tid & 63;
  const int nwg = gridDim.x * gridDim.y;
  const int lin = blockIdx.y * gridDim.x + blockIdx.x;
  const int cpx = nwg >> 3;
  const int swz = (lin & 7) * cpx + (lin >> 3);
  const int m0 = (swz % gridDim.x) * 128, n0 = (swz / gridDim.x) * 128;
  const int wr = w >> 1, wc = w & 1;
  const size_t ldb = (size_t)K * 2;
  const char* Ab = (const char*)A + (size_t)m0 * ldb;
  const char* Wb = (const char*)W + (size_t)n0 * ldb;

  const int srow = l >> 3;
  const int scb  = ((l & 7) ^ srow) << 4;
  const int fr = l & 15;
  const int fg = l >> 4;
  const int fsw = (fr & 7) << 4;

  f32x4 acc[4][4];
  #pragma unroll
  for (int m = 0; m < 4; ++m)
    #pragma unroll
    for (int n = 0; n < 4; ++n) acc[m][n] = (f32x4){0.f,0.f,0.f,0.f};

  const int nk = K >> 6;
  for (int kt = 0; kt < nk; ++kt){
    const char* As = Ab + (size_t)kt * 128;
    const char* Ws = Wb + (size_t)kt * 128;
    #pragma unroll
    for (int i = 0; i < 4; ++i){
      int row = (i*4 + w)*8 + srow;
      gload16(As + (size_t)row*ldb + scb, &lsA[(i*4 + w)*1024]);
    }
    #pragma unroll
    for (int i = 0; i < 4; ++i){
      int row = (i*4 + w)*8 + srow;
      gload16(Ws + (size_t)row*ldb + scb, &lsB[(i*4 + w)*1024]);
    }
    __syncthreads();

    s16x8 af[4][2], bfr[4][2];
    #pragma unroll
    for (int m = 0; m < 4; ++m){
      int row = wr*64 + m*16 + fr;
      af[m][0] = *(const s16x8*)&lsA[row*128 + (( 0 + fg*16) ^ fsw)];
      af[m][1] = *(const s16x8*)&lsA[row*128 + ((64 + fg*16) ^ fsw)];
    }
    #pragma unroll
    for (int n = 0; n < 4; ++n){
      int row = wc*64 + n*16 + fr;
      bfr[n][0] = *(const s16x8*)&lsB[row*128 + (( 0 + fg*16) ^ fsw)];
      bfr[n][1] = *(const s16x8*)&lsB[row*128 + ((64 + fg*16) ^ fsw)];
    }
    #pragma unroll
    for (int m = 0; m < 4; ++m)
      #pragma unroll
      for (int n = 0; n < 4; ++n){
        acc[m][n] = __builtin_amdgcn_mfma_f32_16x16x32_bf16(af[m][0], bfr[n][0], acc[m][n], 0, 0, 0);
        acc[m][n] = __builtin_amdgcn_mfma_f32_16x16x32_bf16(af[m][1], bfr[n][1], acc[m][n], 0, 0, 0);
      }
    __syncthreads();
  }

  const int orow0 = m0 + wr*64, ocol0 = n0 + wc*64;
  #pragma unroll
  for (int n = 0; n < 4; ++n){
    int col = ocol0 + n*16 + fr;
    float bv = HASBIAS ? bias[col] : 0.f;
    #pragma unroll
    for (int m = 0; m < 4; ++m){
      int rbase = orow0 + m*16 + fg*4;
      #pragma unroll
      for (int r = 0; r < 4; ++r){
        float v = acc[m][n][r] + bv;
        if (ACT == 1) v = fmaxf(v, 0.f);
        if (ACT == 2) v = (v > 20.f) ? v : log1pf(__expf(v));
        size_t oi = (size_t)(rbase + r) * ldo + col;
        if (OMODE == 0)      ((bf16*)outp)[oi] = f2b(v);
        else if (OMODE == 1) ((float*)outp)[oi] = v;
        else                 ((float*)outp)[oi] += v;
      }
    }
  }
}

// ---------------- bgemm2: x_proj GEMM with dwconv+silu fused into A-staging
// A[row= n*4+t][ch] = silu(causal_dwconv(xz)[t][ch]) computed in regs,
// ds_written in the SAME swizzled layout the gload16 path produced
// (LDS[row][c16] = global[c16 ^ (row&7)]).
// Outputs: dtr_buf bf16 [2][8192][64], dbl f32 [8192][128].
__global__ __launch_bounds__(256) void bgemm2_kernel(
    const bf16* __restrict__ xz, const bf16* __restrict__ W,
    const float* __restrict__ cw, const float* __restrict__ cb,
    bf16* __restrict__ dtr_buf, float* __restrict__ dbl)
{
  __shared__ char lsA[16384];
  __shared__ char lsB[16384];
  const int tid = threadIdx.x;
  const int w = tid >> 6, l = tid & 63;
  const int nwg = gridDim.x * 2;
  const int lin = blockIdx.y * gridDim.x + blockIdx.x;
  const int cpx = nwg >> 3;
  const int swz = (lin & 7) * cpx + (lin >> 3);
  const int m0 = (swz % gridDim.x) * 128;
  const int d  = swz / gridDim.x;
  const int K = 1024;
  const int wr = w >> 1, wc = w & 1;
  const size_t ldb = (size_t)K * 2;
  const char* Wb = (const char*)(W + (size_t)d*131072);
  const float* cwd = cw + d*4096;
  const float* cbd = cb + d*1024;
  const int n_base = m0 >> 2;          // 32 samples per tile

  const int srow = l >> 3;
  const int scb  = ((l & 7) ^ srow) << 4;
  const int fr = l & 15;
  const int fg = l >> 4;
  const int fsw = (fr & 7) << 4;

  // A-staging geometry: thread -> (sample a_n 0..31, channel-group a_j8 0..7)
  const int a_n  = tid >> 3;
  const int a_j8 = tid & 7;

  f32x4 acc[4][4];
  #pragma unroll
  for (int m = 0; m < 4; ++m)
    #pragma unroll
    for (int n = 0; n < 4; ++n) acc[m][n] = (f32x4){0.f,0.f,0.f,0.f};

  for (int kt = 0; kt < 16; ++kt){
    const int ch = kt*64 + a_j8*8;
    // load 4 time rows x 8 channels of xi
    s16x8 xr[4];
    #pragma unroll
    for (int tp = 0; tp < 4; ++tp)
      xr[tp] = *(const s16x8*)&xz[((size_t)(n_base + a_n)*4 + tp)*2048 + ch];
    // conv + silu per channel
    s16x8 ot[4];
    #pragma unroll
    for (int jj = 0; jj < 8; ++jj){
      float xv[4];
      #pragma unroll
      for (int tp = 0; tp < 4; ++tp) xv[tp] = u2f((unsigned short)xr[tp][jj]);
      float xa[4];
      #pragma unroll
      for (int tp = 0; tp < 4; ++tp) xa[tp] = d ? xv[3-tp] : xv[tp];
      float4 w4 = *(const float4*)&cwd[(ch + jj)*4];
      float bb = cbd[ch + jj];
      float o[4];
      o[0] = xa[0]*w4.w + bb;
      o[1] = xa[0]*w4.z + xa[1]*w4.w + bb;
      o[2] = xa[0]*w4.y + xa[1]*w4.z + xa[2]*w4.w + bb;
      o[3] = xa[0]*w4.x + xa[1]*w4.y + xa[2]*w4.z + xa[3]*w4.w + bb;
      #pragma unroll
      for (int t = 0; t < 4; ++t){
        float v = o[t];
        float sv = v / (1.f + __expf(-v));
        ot[t][jj] = (short)__bfloat16_as_ushort(f2b(sv));
      }
    }
    // swizzled ds_write (matches read-side XOR)
    #pragma unroll
    for (int t = 0; t < 4; ++t){
      int row = a_n*4 + t;
      *(s16x8*)&lsA[row*128 + ((a_j8 << 4) ^ ((row & 7) << 4))] = ot[t];
    }
    // B staging unchanged
    const char* Ws = Wb + (size_t)kt * 128;
    #pragma unroll
    for (int i = 0; i < 4; ++i){
      int row = (i*4 + w)*8 + srow;
      gload16(Ws + (size_t)row*ldb + scb, &lsB[(i*4 + w)*1024]);
    }
    __syncthreads();

    s16x8 af[4][2], bfr[4][2];
    #pragma unroll
    for (int m = 0; m < 4; ++m){
      int row = wr*64 + m*16 + fr;
      af[m][0] = *(const s16x8*)&lsA[row*128 + (( 0 + fg*16) ^ fsw)];
      af[m][1] = *(const s16x8*)&lsA[row*128 + ((64 + fg*16) ^ fsw)];
    }
    #pragma unroll
    for (int n = 0; n < 4; ++n){
      int row = wc*64 + n*16 + fr;
      bfr[n][0] = *(const s16x8*)&lsB[row*128 + (( 0 + fg*16) ^ fsw)];
      bfr[n][1] = *(const s16x8*)&lsB[row*128 + ((64 + fg*16) ^ fsw)];
    }
    #pragma unroll
    for (int m = 0; m < 4; ++m)
      #pragma unroll
      for (int n = 0; n < 4; ++n){
        acc[m][n] = __builtin_amdgcn_mfma_f32_16x16x32_bf16(af[m][0], bfr[n][0], acc[m][n], 0, 0, 0);
        acc[m][n] = __builtin_amdgcn_mfma_f32_16x16x32_bf16(af[m][1], bfr[n][1], acc[m][n], 0, 0, 0);
      }
    __syncthreads();
  }

  const int orow0 = m0 + wr*64, c0 = wc*64;
  #pragma unroll
  for (int n = 0; n < 4; ++n){
    int col = c0 + n*16 + fr;
    #pragma unroll
    for (int m = 0; m < 4; ++m){
      int rbase = orow0 + m*16 + fg*4;
      #pragma unroll
      for (int r = 0; r < 4; ++r){
        float v = acc[m][n][r];
        int row = rbase + r;
        if (col < 32)
          dtr_buf[((size_t)d*8192 + row)*64 + col] = f2b(v);
        else if (col < 64)
          dbl[(size_t)row*128 + d*64 + (col - 32)] = v;
        else if (col < 96)
          dtr_buf[((size_t)d*8192 + row)*64 + (col - 32)] = f2b(v);  // pad zeros
      }
    }
  }
}

// ---------------- dt_proj GEMM, both dirs in one dispatch ------------------
// A = dtrb [16384][64] (rows 0..8191 dir0). grid (128,8). K=64 (one step).
__global__ __launch_bounds__(256) void dtgemm_kernel(
    const bf16* __restrict__ A, const bf16* __restrict__ W2,
    const float* __restrict__ bias2, bf16* __restrict__ out2)
{
  __shared__ char lsA[16384];
  __shared__ char lsB[16384];
  const int tid = threadIdx.x;
  const int w = tid >> 6, l = tid & 63;
  const int nwg = gridDim.x * gridDim.y;          // 1024
  const int lin = blockIdx.y * gridDim.x + blockIdx.x;
  const int cpx = nwg >> 3;
  const int swz = (lin & 7) * cpx + (lin >> 3);
  const int m0 = (swz % gridDim.x) * 128, n0 = (swz / gridDim.x) * 128;
  const int d  = (m0 >= 8192) ? 1 : 0;
  const int wr = w >> 1, wc = w & 1;
  const size_t ldb = 128;
  const char* Ab = (const char*)A + (size_t)m0 * ldb;
  const char* Wb = (const char*)(W2 + (size_t)d*65536) + (size_t)n0 * ldb;
  const float* bias = bias2 + d*1024;
  bf16* outp = out2 + (size_t)d*8388608;

  const int srow = l >> 3;
  const int scb  = ((l & 7) ^ srow) << 4;
  const int fr = l & 15, fg = l >> 4;
  const int fsw = (fr & 7) << 4;

  f32x4 acc[4][4];
  #pragma unroll
  for (int m = 0; m < 4; ++m)
    #pragma unroll
    for (int n = 0; n < 4; ++n) acc[m][n] = (f32x4){0.f,0.f,0.f,0.f};

  #pragma unroll
  for (int i = 0; i < 4; ++i){
    int row = (i*4 + w)*8 + srow;
    gload16(Ab + (size_t)row*ldb + scb, &lsA[(i*4 + w)*1024]);
  }
  #pragma unroll
  for (int i = 0; i < 4; ++i){
    int row = (i*4 + w)*8 + srow;
    gload16(Wb + (size_t)row*ldb + scb, &lsB[(i*4 + w)*1024]);
  }
  __syncthreads();

  s16x8 af[4][2], bfr[4][2];
  #pragma unroll
  for (int m = 0; m < 4; ++m){
    int row = wr*64 + m*16 + fr;
    af[m][0] = *(const s16x8*)&lsA[row*128 + (( 0 + fg*16) ^ fsw)];
    af[m][1] = *(const s16x8*)&lsA[row*128 + ((64 + fg*16) ^ fsw)];
  }
  #pragma unroll
  for (int n = 0; n < 4; ++n){
    int row = wc*64 + n*16 + fr;
    bfr[n][0] = *(const s16x8*)&lsB[row*128 + (( 0 + fg*16) ^ fsw)];
    bfr[n][1] = *(const s16x8*)&lsB[row*128 + ((64 + fg*16) ^ fsw)];
  }
  #pragma unroll
  for (int m = 0; m < 4; ++m)
    #pragma unroll
    for (int n = 0; n < 4; ++n){
      acc[m][n] = __builtin_amdgcn_mfma_f32_16x16x32_bf16(af[m][0], bfr[n][0], acc[m][n], 0, 0, 0);
      acc[m][n] = __builtin_amdgcn_mfma_f32_16x16x32_bf16(af[m][1], bfr[n][1], acc[m][n], 0, 0, 0);
    }

  const int orow0 = (m0 - d*8192) + wr*64, ocol0 = n0 + wc*64;
  #pragma unroll
  for (int n = 0; n < 4; ++n){
    int col = ocol0 + n*16 + fr;
    float bv = bias[col];
    #pragma unroll
    for (int m = 0; m < 4; ++m){
      int rbase = orow0 + m*16 + fg*4;
      #pragma unroll
      for (int r = 0; r < 4; ++r){
        float v = acc[m][n][r] + bv;
        v = (v > 20.f) ? v : log1pf(__expf(v));          // softplus
        outp[(size_t)(rbase + r) * 1024 + col] = f2b(v);
      }
    }
  }
}

// ---------------- stem im2col: x -> conv_a patches (bf16) + maxpool (bf16) --
__global__ __launch_bounds__(256) void im2col_kernel(
    const float* __restrict__ x_flat, bf16* __restrict__ Aa, bf16* __restrict__ P)
{
  __shared__ float xs[512][8];
  const int n = blockIdx.x, tid = threadIdx.x;
  const float* xr = x_flat + (size_t)n * 3584;
  for (int i = tid; i < 3584; i += 256) xs[i / 7][i % 7] = xr[i];
  __syncthreads();
  bf16* Ar = Aa + (size_t)n * 4 * 1536;
  for (int i = tid; i < 6144; i += 256){
    int t = i / 1536, col = i - t*1536;
    int c = col / 3, kk = col - c*3;
    int p = 2*t - 1 + kk;
    float v = (p >= 0 && p < 7) ? xs[c][p] : 0.f;
    Ar[i] = f2b(v);
  }
  bf16* Pr = P + (size_t)n * 4 * 512;
  for (int i = tid; i < 2048; i += 256){
    int t = i >> 9, c = i & 511;
    int st = 2*t - 1;
    float m = -1e30f;
    #pragma unroll
    for (int k = 0; k < 3; ++k){ int p = st + k; if (p >= 0 && p < 7) m = fmaxf(m, xs[c][p]); }
    Pr[i] = f2b(m);
  }
}

// ---------------- SE: mean over t -> 2 matvecs -> sigmoid -> scale h in place
__global__ __launch_bounds__(256) void se_kernel(
    const float* __restrict__ sw1, const float* __restrict__ sb1,
    const float* __restrict__ sw2, const float* __restrict__ sb2,
    float* __restrict__ h)
{
  __shared__ float yms[512];
  __shared__ float s1s[32];
  const int n = blockIdx.x, tid = threadIdx.x;
  float* hb = h + (size_t)n * 2048;
  for (int c = tid; c < 512; c += 256)
    yms[c] = 0.25f * (hb[c] + hb[512+c] + hb[1024+c] + hb[1536+c]);
  __syncthreads();
  {
    int o = tid >> 3, sl = tid & 7;
    const float* wr = sw1 + (size_t)o * 512 + sl*64;
    const float* ym = yms + sl*64;
    float a = 0.f;
    #pragma unroll 16
    for (int i = 0; i < 64; ++i) a += wr[i] * ym[i];
    a += __shfl_down(a, 4, 8);
    a += __shfl_down(a, 2, 8);
    a += __shfl_down(a, 1, 8);
    if (sl == 0) s1s[o] = fmaxf(a + sb1[o], 0.f);
  }
  __syncthreads();
  for (int c = tid; c < 512; c += 256){
    float a = sb2[c];
    const float* wr = sw2 + (size_t)c * 32;
    #pragma unroll
    for (int j = 0; j < 32; ++j) a += wr[j] * s1s[j];
    float s = 1.f / (1.f + __expf(-a));
    #pragma unroll
    for (int t = 0; t < 4; ++t) hb[t*512 + c] *= s;
  }
}

// ---------------- layernorm rows of 512: f32 in -> bf16 out ----------------
__global__ __launch_bounds__(256) void ln_kernel(
    const float* __restrict__ x, const float* __restrict__ g,
    const float* __restrict__ b, bf16* __restrict__ out)
{
  __shared__ float red[4];
  const int row = blockIdx.x, t = threadIdx.x;
  const float* xr = x + (size_t)row * 512;
  float v0 = xr[t], v1 = xr[t + 256];
  float s = block_sum256(v0 + v1, red);
  float mu = s * (1.f/512.f);
  float d0 = v0 - mu, d1 = v1 - mu;
  float sq = block_sum256(d0*d0 + d1*d1, red);
  float rstd = rsqrtf(sq * (1.f/512.f) + 1e-5f);
  out[(size_t)row*512 + t]       = f2b(d0*rstd*g[t]     + b[t]);
  out[(size_t)row*512 + t + 256] = f2b(d1*rstd*g[t+256] + b[t+256]);
}

// ---------------- final LN + mean over t -> feat bf16 [N][512] -------------
__global__ __launch_bounds__(256) void finalln_kernel(
    const float* __restrict__ h, const float* __restrict__ g,
    const float* __restrict__ b, bf16* __restrict__ feat)
{
  __shared__ float red[4];
  const int n = blockIdx.x, t = threadIdx.x;
  float a0 = 0.f, a1 = 0.f;
  for (int tt = 0; tt < 4; ++tt){
    const float* xr = h + ((size_t)n*4 + tt)*512;
    float v0 = xr[t], v1 = xr[t+256];
    float s = block_sum256(v0 + v1, red);
    float mu = s * (1.f/512.f);
    float d0 = v0 - mu, d1 = v1 - mu;
    float sq = block_sum256(d0*d0 + d1*d1, red);
    float rstd = rsqrtf(sq * (1.f/512.f) + 1e-5f);
    a0 += d0*rstd*g[t]     + b[t];
    a1 += d1*rstd*g[t+256] + b[t+256];
  }
  feat[(size_t)n*512 + t]       = f2b(a0 * 0.25f);
  feat[(size_t)n*512 + t + 256] = f2b(a1 * 0.25f);
}

// ---------------- fused bidirectional scan + gate (u recomputed inline) ----
// dbl f32 [8192][128]; dt2 bf16 [2][8192][1024]; Atab2 pre-scaled by log2e.
__global__ __launch_bounds__(256) void scan2_kernel(
    const float* __restrict__ dbl, const bf16* __restrict__ dt2,
    const bf16* __restrict__ xz, const float* __restrict__ cw,
    const float* __restrict__ cb, const float* __restrict__ Atab2,
    const float* __restrict__ Dp, bf16* __restrict__ gated)
{
  __shared__ float Bs[2][4][16], Cs[2][4][16];
  const int n = blockIdx.x, g = blockIdx.y, tid = threadIdx.x;
  {
    int t = tid >> 6, j = tid & 63;
    int d = j >> 5, jj = j & 31;
    float v = dbl[((size_t)n*4 + t)*128 + d*64 + jj];
    if (jj < 16) Bs[d][t][jj] = v; else Cs[d][t][jj-16] = v;
  }
  __syncthreads();
  const int c = g*256 + tid;
  const size_t base = (size_t)n*4*1024 + c;
  // recompute u (both dirs) from xz
  float xv[4];
  #pragma unroll
  for (int t = 0; t < 4; ++t) xv[t] = bfu(xz[((size_t)(n*4 + t))*2048 + c]);
  float4 w0 = *(const float4*)&cw[(size_t)c*4];
  float4 w1 = *(const float4*)&cw[4096 + (size_t)c*4];
  float b0v = cb[c], b1v = cb[1024 + c];
  float uu0[4], uu1[4];
  uu0[0] = xv[0]*w0.w + b0v;
  uu0[1] = xv[0]*w0.z + xv[1]*w0.w + b0v;
  uu0[2] = xv[0]*w0.y + xv[1]*w0.z + xv[2]*w0.w + b0v;
  uu0[3] = xv[0]*w0.x + xv[1]*w0.y + xv[2]*w0.z + xv[3]*w0.w + b0v;
  uu1[0] = xv[3]*w1.w + b1v;
  uu1[1] = xv[3]*w1.z + xv[2]*w1.w + b1v;
  uu1[2] = xv[3]*w1.y + xv[2]*w1.z + xv[1]*w1.w + b1v;
  uu1[3] = xv[3]*w1.x + xv[2]*w1.y + xv[1]*w1.z + xv[0]*w1.w + b1v;
  #pragma unroll
  for (int t = 0; t < 4; ++t){
    uu0[t] = uu0[t] / (1.f + __expf(-uu0[t]));
    uu1[t] = uu1[t] / (1.f + __expf(-uu1[t]));
  }
  float yo0[4], yo1[4];
  float hs[16];
  // ---- direction 0 ----
  {
    float A[16];
    const float4* ap = reinterpret_cast<const float4*>(Atab2 + (size_t)c*16);
    #pragma unroll
    for (int q = 0; q < 4; ++q){
      float4 v = ap[q];
      A[q*4+0]=v.x; A[q*4+1]=v.y; A[q*4+2]=v.z; A[q*4+3]=v.w;
    }
    const float Dpc = Dp[c];
    #pragma unroll
    for (int s = 0; s < 16; ++s) hs[s] = 0.f;
    #pragma unroll
    for (int t = 0; t < 4; ++t){
      float dtv = bfu(dt2[base + (size_t)t*1024]);
      float du = dtv * uu0[t];
      float yv = 0.f;
      #pragma unroll
      for (int s = 0; s < 16; ++s){
        float dA = __builtin_amdgcn_exp2f(dtv * A[s]);
        hs[s] = dA * hs[s] + du * Bs[0][t][s];
        yv += hs[s] * Cs[0][t][s];
      }
      yo0[t] = yv + uu0[t] * Dpc;
    }
  }
  // ---- direction 1 ----
  {
    float A[16];
    const float4* ap = reinterpret_cast<const float4*>(Atab2 + 16384 + (size_t)c*16);
    #pragma unroll
    for (int q = 0; q < 4; ++q){
      float4 v = ap[q];
      A[q*4+0]=v.x; A[q*4+1]=v.y; A[q*4+2]=v.z; A[q*4+3]=v.w;
    }
    const float Dpc = Dp[1024 + c];
    #pragma unroll
    for (int s = 0; s < 16; ++s) hs[s] = 0.f;
    #pragma unroll
    for (int t = 0; t < 4; ++t){
      float dtv = bfu(dt2[8388608 + base + (size_t)t*1024]);
      float du = dtv * uu1[t];
      float yv = 0.f;
      #pragma unroll
      for (int s = 0; s < 16; ++s){
        float dA = __builtin_amdgcn_exp2f(dtv * A[s]);
        hs[s] = dA * hs[s] + du * Bs[1][t][s];
        yv += hs[s] * Cs[1][t][s];
      }
      yo1[3 - t] = yv + uu1[t] * Dpc;
    }
  }
  // ---- gate + store ----
  #pragma unroll
  for (int t = 0; t < 4; ++t){
    float z = bfu(xz[(size_t)(n*4 + t)*2048 + 1024 + c]);
    float sv = z / (1.f + __expf(-z));
    gated[base + (size_t)t*1024] = f2b((yo0[t] + yo1[t]) * sv);
  }
}

// ---------------- launch ---------------------------------------------------
extern "C" void kernel_launch(void* const* d_in, const int* in_sizes, int n_in,
                              void* d_out, int out_size, void* d_ws, size_t ws_size,
                              hipStream_t stream)
{
  const float* x_flat    = (const float*)d_in[0];
  const float* conv_a_w  = (const float*)d_in[1];
  const float* conv_p_w  = (const float*)d_in[2];
  const float* se_w1     = (const float*)d_in[3];
  const float* se_b1     = (const float*)d_in[4];
  const float* se_w2     = (const float*)d_in[5];
  const float* se_b2     = (const float*)d_in[6];
  const float* ln_g      = (const float*)d_in[7];
  const float* ln_b      = (const float*)d_in[8];
  const float* in_proj_w = (const float*)d_in[9];
  const float* conv_w    = (const float*)d_in[10];
  const float* conv_b    = (const float*)d_in[11];
  const float* x_proj_w  = (const float*)d_in[12];
  const float* dt_proj_w = (const float*)d_in[13];
  const float* dt_proj_b = (const float*)d_in[14];
  const float* A_log     = (const float*)d_in[15];
  const float* D_param   = (const float*)d_in[16];
  const float* out_proj_w= (const float*)d_in[17];
  const float* out_ln_g  = (const float*)d_in[18];
  const float* out_ln_b  = (const float*)d_in[19];
  const float* mlp_w1    = (const float*)d_in[20];
  const float* mlp_b1    = (const float*)d_in[21];
  const float* mlp_w2    = (const float*)d_in[22];
  const float* mlp_b2    = (const float*)d_in[23];

  char* ws = (char*)d_ws;
  const size_t OFF_H    = 0;                       // f32  8192*512  = 16.78MB
  const size_t OFF_HN   = OFF_H    + 16777216;     // bf16 8192*512  (feat overlay)
  const size_t OFF_XZ   = OFF_HN   + 8388608;      // bf16 8192*2048 (z1 overlay)
  const size_t OFF_U    = OFF_XZ   + 33554432;     // bf16 gated 8192*1024 (+spare)
  const size_t OFF_SCR  = OFF_U    + 33554432;     // 25.17MB: Aa(stem)/dbl+dtrb(layers)/wb1(MLP)
  const size_t OFF_YB   = OFF_SCR  + 25165824;     // 33.55MB: Pm+wa+wp(stem)/dt2(layers)/wb2(MLP)
  const size_t OFF_WB   = OFF_YB   + 33554432;     // bf16 in_proj+out_proj
  const size_t OFF_WXP  = OFF_WB   + 6291456;      // bf16 2*256*1024 packed x_proj
  const size_t OFF_WDT  = OFF_WXP  + 1048576;      // bf16 4*1024*64 padded dt_proj
  const size_t OFF_ATAB = OFF_WDT  + 524288;       // f32  4*1024*16
  // total = OFF_ATAB + 262144 = ~160MB

  float* h    = (float*)(ws + OFF_H);
  bf16*  hn   = (bf16*) (ws + OFF_HN);
  bf16*  xz   = (bf16*) (ws + OFF_XZ);
  bf16*  gated= (bf16*) (ws + OFF_U);
  float* dbl  = (float*)(ws + OFF_SCR);                 // [8192][128] f32
  bf16*  dtrb = (bf16*) (ws + OFF_SCR + 4194304);       // [2][8192][64]
  bf16*  dt2  = (bf16*) (ws + OFF_YB);                  // [2][8192][1024]
  bf16*  feat = (bf16*) (ws + OFF_HN);   // overlay
  bf16*  z1   = (bf16*) (ws + OFF_XZ);   // overlay
  bf16*  wbi  = (bf16*) (ws + OFF_WB);
  bf16*  wbo  = (bf16*) (ws + OFF_WB + 4194304);
  bf16*  wxp  = (bf16*) (ws + OFF_WXP);
  bf16*  wdtp = (bf16*) (ws + OFF_WDT);
  float* Atab = (float*)(ws + OFF_ATAB);
  bf16*  wb1  = (bf16*) (ws + OFF_SCR);  // overlay (MLP phase)
  bf16*  wb2  = (bf16*) (ws + OFF_YB);   // overlay (MLP phase)
  // stem-phase overlays
  bf16*  Aa   = (bf16*) (ws + OFF_SCR);
  bf16*  Pm   = (bf16*) (ws + OFF_YB);
  bf16*  wa   = (bf16*) (ws + OFF_YB + 8388608);
  bf16*  wp   = (bf16*) (ws + OFF_YB + 8388608 + 786432);
  float* outf = (float*)d_out;

  // all weight prep in one dispatch
  prep_kernel<<<2048, 256, 0, stream>>>(
      conv_a_w, conv_p_w, in_proj_w, out_proj_w, x_proj_w, dt_proj_w, A_log,
      wa, wp, wbi, wbo, wxp, wdtp, Atab);

  // stem
  im2col_kernel<<<2048, 256, 0, stream>>>(x_flat, Aa, Pm);
  mgemm_kernel<1,1,false><<<dim3(64,2), 256, 0, stream>>>(
      Aa, wa, nullptr, h, 1536, 512);
  mgemm_kernel<1,1,false><<<dim3(64,2), 256, 0, stream>>>(
      Pm, wp, nullptr, (float*)h + 256, 512, 512);
  se_kernel<<<2048, 256, 0, stream>>>(se_w1, se_b1, se_w2, se_b2, h);

  for (int l = 0; l < 2; ++l){
    const float* cw_l = conv_w + (size_t)l*8192;
    const float* cb_l = conv_b + (size_t)l*2048;
    ln_kernel<<<8192, 256, 0, stream>>>(h, ln_g + l*512, ln_b + l*512, hn);
    mgemm_kernel<0,0,false><<<dim3(64,16), 256, 0, stream>>>(
        hn, wbi + (size_t)l*2048*512, nullptr, xz, 512, 2048);
    bgemm2_kernel<<<dim3(64,2), 256, 0, stream>>>(
        xz, wxp + (size_t)l*262144, cw_l, cb_l, dtrb, dbl);
    dtgemm_kernel<<<dim3(128,8), 256, 0, stream>>>(
        dtrb, wdtp + (size_t)l*131072, dt_proj_b + (size_t)l*2048, dt2);
    scan2_kernel<<<dim3(2048,4), 256, 0, stream>>>(
        dbl, dt2, xz, cw_l, cb_l, Atab + (size_t)l*32768,
        D_param + (size_t)l*2048, gated);
    mgemm_kernel<0,2,false><<<dim3(64,4), 256, 0, stream>>>(
        gated, wbo + (size_t)l*512*1024, nullptr, h, 1024, 512);
  }

  finalln_kernel<<<2048, 256, 0, stream>>>(h, out_ln_g, out_ln_b, feat);

  mlpprep_kernel<<<4096, 256, 0, stream>>>(
      (const float4*)mlp_w1, (const float4*)mlp_w2, (ushort4*)wb1, (ushort4*)wb2);

  mgemm_kernel<1,0,true><<<dim3(16,32), 256, 0, stream>>>(
      feat, wb1, mlp_b1, z1, 512, 4096);
  mgemm_kernel<1,1,true><<<dim3(16,32), 256, 0, stream>>>(
      z1, wb2, mlp_b2, outf, 4096, 4096);
}

// Round 11
// 679.500 us; speedup vs baseline: 4.0062x; 1.0526x over previous
//
#include <hip/hip_runtime.h>
#include <hip/hip_bf16.h>

typedef __hip_bfloat16 bf16;
typedef __attribute__((ext_vector_type(8))) short s16x8;
typedef __attribute__((ext_vector_type(4))) float f32x4;

__device__ __forceinline__ float u2f(unsigned short u){
  union { unsigned int i; float f; } v; v.i = ((unsigned int)u) << 16; return v.f;
}
__device__ __forceinline__ float bfu(bf16 x){ return __bfloat162float(x); }
__device__ __forceinline__ bf16  f2b(float x){ return __float2bfloat16(x); }

__device__ __forceinline__ void gload16(const void* g, void* l){
  __builtin_amdgcn_global_load_lds(
      (const __attribute__((address_space(1))) void*)g,
      (__attribute__((address_space(3))) void*)l, 16, 0, 0);
}

// ---------------- block reduction (256 threads) ----------------
__device__ __forceinline__ float block_sum256(float v, float* red){
  #pragma unroll
  for (int o = 32; o > 0; o >>= 1) v += __shfl_down(v, o, 64);
  int lane = threadIdx.x & 63, wid = threadIdx.x >> 6;
  if (lane == 0) red[wid] = v;
  __syncthreads();
  float r = red[0] + red[1] + red[2] + red[3];
  __syncthreads();
  return r;
}

__device__ __forceinline__ ushort4 cvt4(float4 v){
  ushort4 o;
  o.x = __bfloat16_as_ushort(f2b(v.x));
  o.y = __bfloat16_as_ushort(f2b(v.y));
  o.z = __bfloat16_as_ushort(f2b(v.z));
  o.w = __bfloat16_as_ushort(f2b(v.w));
  return o;
}

// ---------------- unified prep: all weight conversions in ONE dispatch -----
// segs (f4 units): wa 98304 | wp 32768 | wbi 524288 | wbo 262144  (sum 917504)
// then elems: xpw-pad 524288 | wdt-pad 262144 | atab 65536   total 1769472
__global__ __launch_bounds__(256) void prep_kernel(
    const float* __restrict__ caw, const float* __restrict__ cpw,
    const float* __restrict__ ipw, const float* __restrict__ opw,
    const float* __restrict__ xpw, const float* __restrict__ dtw,
    const float* __restrict__ alog,
    bf16* __restrict__ wa, bf16* __restrict__ wp,
    bf16* __restrict__ wbi, bf16* __restrict__ wbo,
    bf16* __restrict__ wxp, bf16* __restrict__ wdtp,
    float* __restrict__ atab)
{
  for (int i = blockIdx.x*256 + threadIdx.x; i < 1769472; i += gridDim.x*256){
    if (i < 917504){
      int j = i;
      const float4* src; ushort4* dst;
      if (j < 98304)      { src = (const float4*)caw; dst = (ushort4*)wa; }
      else if (j < 131072){ j -= 98304;  src = (const float4*)cpw; dst = (ushort4*)wp; }
      else if (j < 655360){ j -= 131072; src = (const float4*)ipw; dst = (ushort4*)wbi; }
      else                { j -= 655360; src = (const float4*)opw; dst = (ushort4*)wbo; }
      dst[j] = cvt4(src[j]);
    } else if (i < 1441792){
      int idx = i - 917504;                 // xpw pad: [L][2*128][1024]
      int l = idx >> 18, rem = idx & 262143, row = rem >> 10, c = rem & 1023;
      int d = row >> 7, r = row & 127;
      float v = (r < 64) ? xpw[(((size_t)l*2 + d)*64 + r)*1024 + c] : 0.f;
      wxp[idx] = f2b(v);
    } else if (i < 1703936){
      int idx = i - 1441792;                // wdt pad: [4][1024][64]
      int ld = idx >> 16, rem = idx & 65535, r = rem >> 6, cc = rem & 63;
      float v = (cc < 32) ? dtw[((size_t)ld*1024 + r)*32 + cc] : 0.f;
      wdtp[idx] = f2b(v);
    } else {
      int idx = i - 1703936;                // atab (pre-scaled by log2 e)
      atab[idx] = -__expf(alog[idx]) * 1.44269504088896f;
    }
  }
}

// ---------------- MLP weight conversion (one dispatch) ---------------------
__global__ __launch_bounds__(256) void mlpprep_kernel(
    const float4* __restrict__ w1, const float4* __restrict__ w2,
    ushort4* __restrict__ o1, ushort4* __restrict__ o2)
{
  for (int i = blockIdx.x*256 + threadIdx.x; i < 4718592; i += gridDim.x*256){
    if (i < 524288) o1[i] = cvt4(w1[i]);
    else            o2[i - 524288] = cvt4(w2[i - 524288]);
  }
}

// ---------------- MFMA GEMM: out[m,n] = act(sum_k A[m,k]*W[n,k] + bias[n])
// A,W bf16 row-major (ld = K). 128x128 tile, BK=64, 4 waves. nwg%8==0.
// ACT: 0 none, 1 relu, 2 softplus. OMODE: 0 bf16, 1 f32, 2 f32 +=.
template<int ACT, int OMODE, bool HASBIAS>
__global__ __launch_bounds__(256) void mgemm_kernel(
    const bf16* __restrict__ A, const bf16* __restrict__ W,
    const float* __restrict__ bias, void* __restrict__ outp,
    int K, int ldo)
{
  __shared__ char lsA[16384];
  __shared__ char lsB[16384];
  const int tid = threadIdx.x;
  const int w = tid >> 6, l = tid & 63;
  const int nwg = gridDim.x * gridDim.y;
  const int lin = blockIdx.y * gridDim.x + blockIdx.x;
  const int cpx = nwg >> 3;
  const int swz = (lin & 7) * cpx + (lin >> 3);
  const int m0 = (swz % gridDim.x) * 128, n0 = (swz / gridDim.x) * 128;
  const int wr = w >> 1, wc = w & 1;
  const size_t ldb = (size_t)K * 2;
  const char* Ab = (const char*)A + (size_t)m0 * ldb;
  const char* Wb = (const char*)W + (size_t)n0 * ldb;

  const int srow = l >> 3;
  const int scb  = ((l & 7) ^ srow) << 4;
  const int fr = l & 15;
  const int fg = l >> 4;
  const int fsw = (fr & 7) << 4;

  f32x4 acc[4][4];
  #pragma unroll
  for (int m = 0; m < 4; ++m)
    #pragma unroll
    for (int n = 0; n < 4; ++n) acc[m][n] = (f32x4){0.f,0.f,0.f,0.f};

  const int nk = K >> 6;
  for (int kt = 0; kt < nk; ++kt){
    const char* As = Ab + (size_t)kt * 128;
    const char* Ws = Wb + (size_t)kt * 128;
    #pragma unroll
    for (int i = 0; i < 4; ++i){
      int row = (i*4 + w)*8 + srow;
      gload16(As + (size_t)row*ldb + scb, &lsA[(i*4 + w)*1024]);
    }
    #pragma unroll
    for (int i = 0; i < 4; ++i){
      int row = (i*4 + w)*8 + srow;
      gload16(Ws + (size_t)row*ldb + scb, &lsB[(i*4 + w)*1024]);
    }
    __syncthreads();

    s16x8 af[4][2], bfr[4][2];
    #pragma unroll
    for (int m = 0; m < 4; ++m){
      int row = wr*64 + m*16 + fr;
      af[m][0] = *(const s16x8*)&lsA[row*128 + (( 0 + fg*16) ^ fsw)];
      af[m][1] = *(const s16x8*)&lsA[row*128 + ((64 + fg*16) ^ fsw)];
    }
    #pragma unroll
    for (int n = 0; n < 4; ++n){
      int row = wc*64 + n*16 + fr;
      bfr[n][0] = *(const s16x8*)&lsB[row*128 + (( 0 + fg*16) ^ fsw)];
      bfr[n][1] = *(const s16x8*)&lsB[row*128 + ((64 + fg*16) ^ fsw)];
    }
    #pragma unroll
    for (int m = 0; m < 4; ++m)
      #pragma unroll
      for (int n = 0; n < 4; ++n){
        acc[m][n] = __builtin_amdgcn_mfma_f32_16x16x32_bf16(af[m][0], bfr[n][0], acc[m][n], 0, 0, 0);
        acc[m][n] = __builtin_amdgcn_mfma_f32_16x16x32_bf16(af[m][1], bfr[n][1], acc[m][n], 0, 0, 0);
      }
    __syncthreads();
  }

  const int orow0 = m0 + wr*64, ocol0 = n0 + wc*64;
  #pragma unroll
  for (int n = 0; n < 4; ++n){
    int col = ocol0 + n*16 + fr;
    float bv = HASBIAS ? bias[col] : 0.f;
    #pragma unroll
    for (int m = 0; m < 4; ++m){
      int rbase = orow0 + m*16 + fg*4;
      #pragma unroll
      for (int r = 0; r < 4; ++r){
        float v = acc[m][n][r] + bv;
        if (ACT == 1) v = fmaxf(v, 0.f);
        if (ACT == 2) v = (v > 20.f) ? v : log1pf(__expf(v));
        size_t oi = (size_t)(rbase + r) * ldo + col;
        if (OMODE == 0)      ((bf16*)outp)[oi] = f2b(v);
        else if (OMODE == 1) ((float*)outp)[oi] = v;
        else                 ((float*)outp)[oi] += v;
      }
    }
  }
}

// ---------------- batched x_proj GEMM: both directions in one launch -------
// A = u [2][8192][1024]. Outputs: dtr_buf bf16 [2][8192][64] (cols 0..31 dtr,
// 32..63 zero-pad), dbl f32 [8192][128] (dir d cols d*64+{B,C}).
__global__ __launch_bounds__(256) void bgemm_kernel(
    const bf16* __restrict__ A, const bf16* __restrict__ W,
    bf16* __restrict__ dtr_buf, float* __restrict__ dbl)
{
  __shared__ char lsA[16384];
  __shared__ char lsB[16384];
  const int tid = threadIdx.x;
  const int w = tid >> 6, l = tid & 63;
  const int nwg = gridDim.x * 2;
  const int lin = blockIdx.y * gridDim.x + blockIdx.x;
  const int cpx = nwg >> 3;
  const int swz = (lin & 7) * cpx + (lin >> 3);
  const int m0 = (swz % gridDim.x) * 128;
  const int d  = swz / gridDim.x;
  const int K = 1024;
  const int wr = w >> 1, wc = w & 1;
  const size_t ldb = (size_t)K * 2;
  const char* Ab = (const char*)(A + (size_t)d*8388608) + (size_t)m0 * ldb;
  const char* Wb = (const char*)(W + (size_t)d*131072);

  const int srow = l >> 3;
  const int scb  = ((l & 7) ^ srow) << 4;
  const int fr = l & 15;
  const int fg = l >> 4;
  const int fsw = (fr & 7) << 4;

  f32x4 acc[4][4];
  #pragma unroll
  for (int m = 0; m < 4; ++m)
    #pragma unroll
    for (int n = 0; n < 4; ++n) acc[m][n] = (f32x4){0.f,0.f,0.f,0.f};

  const int nk = K >> 6;
  for (int kt = 0; kt < nk; ++kt){
    const char* As = Ab + (size_t)kt * 128;
    const char* Ws = Wb + (size_t)kt * 128;
    #pragma unroll
    for (int i = 0; i < 4; ++i){
      int row = (i*4 + w)*8 + srow;
      gload16(As + (size_t)row*ldb + scb, &lsA[(i*4 + w)*1024]);
    }
    #pragma unroll
    for (int i = 0; i < 4; ++i){
      int row = (i*4 + w)*8 + srow;
      gload16(Ws + (size_t)row*ldb + scb, &lsB[(i*4 + w)*1024]);
    }
    __syncthreads();

    s16x8 af[4][2], bfr[4][2];
    #pragma unroll
    for (int m = 0; m < 4; ++m){
      int row = wr*64 + m*16 + fr;
      af[m][0] = *(const s16x8*)&lsA[row*128 + (( 0 + fg*16) ^ fsw)];
      af[m][1] = *(const s16x8*)&lsA[row*128 + ((64 + fg*16) ^ fsw)];
    }
    #pragma unroll
    for (int n = 0; n < 4; ++n){
      int row = wc*64 + n*16 + fr;
      bfr[n][0] = *(const s16x8*)&lsB[row*128 + (( 0 + fg*16) ^ fsw)];
      bfr[n][1] = *(const s16x8*)&lsB[row*128 + ((64 + fg*16) ^ fsw)];
    }
    #pragma unroll
    for (int m = 0; m < 4; ++m)
      #pragma unroll
      for (int n = 0; n < 4; ++n){
        acc[m][n] = __builtin_amdgcn_mfma_f32_16x16x32_bf16(af[m][0], bfr[n][0], acc[m][n], 0, 0, 0);
        acc[m][n] = __builtin_amdgcn_mfma_f32_16x16x32_bf16(af[m][1], bfr[n][1], acc[m][n], 0, 0, 0);
      }
    __syncthreads();
  }

  const int orow0 = m0 + wr*64, c0 = wc*64;
  #pragma unroll
  for (int n = 0; n < 4; ++n){
    int col = c0 + n*16 + fr;                   // 0..127 within dir
    #pragma unroll
    for (int m = 0; m < 4; ++m){
      int rbase = orow0 + m*16 + fg*4;
      #pragma unroll
      for (int r = 0; r < 4; ++r){
        float v = acc[m][n][r];
        int row = rbase + r;
        if (col < 32)
          dtr_buf[((size_t)d*8192 + row)*64 + col] = f2b(v);
        else if (col < 64)
          dbl[(size_t)row*128 + d*64 + (col - 32)] = v;
        else if (col < 96)
          dtr_buf[((size_t)d*8192 + row)*64 + (col - 32)] = f2b(v);  // pad zeros
      }
    }
  }
}

// ---------------- dt_proj GEMM, both dirs in one dispatch ------------------
// A = dtrb [16384][64] (rows 0..8191 dir0). grid (128,8). K=64 (one step).
__global__ __launch_bounds__(256) void dtgemm_kernel(
    const bf16* __restrict__ A, const bf16* __restrict__ W2,
    const float* __restrict__ bias2, bf16* __restrict__ out2)
{
  __shared__ char lsA[16384];
  __shared__ char lsB[16384];
  const int tid = threadIdx.x;
  const int w = tid >> 6, l = tid & 63;
  const int nwg = gridDim.x * gridDim.y;          // 1024
  const int lin = blockIdx.y * gridDim.x + blockIdx.x;
  const int cpx = nwg >> 3;
  const int swz = (lin & 7) * cpx + (lin >> 3);
  const int m0 = (swz % gridDim.x) * 128, n0 = (swz / gridDim.x) * 128;
  const int d  = (m0 >= 8192) ? 1 : 0;
  const int wr = w >> 1, wc = w & 1;
  const size_t ldb = 128;
  const char* Ab = (const char*)A + (size_t)m0 * ldb;
  const char* Wb = (const char*)(W2 + (size_t)d*65536) + (size_t)n0 * ldb;
  const float* bias = bias2 + d*1024;
  bf16* outp = out2 + (size_t)d*8388608;

  const int srow = l >> 3;
  const int scb  = ((l & 7) ^ srow) << 4;
  const int fr = l & 15, fg = l >> 4;
  const int fsw = (fr & 7) << 4;

  f32x4 acc[4][4];
  #pragma unroll
  for (int m = 0; m < 4; ++m)
    #pragma unroll
    for (int n = 0; n < 4; ++n) acc[m][n] = (f32x4){0.f,0.f,0.f,0.f};

  #pragma unroll
  for (int i = 0; i < 4; ++i){
    int row = (i*4 + w)*8 + srow;
    gload16(Ab + (size_t)row*ldb + scb, &lsA[(i*4 + w)*1024]);
  }
  #pragma unroll
  for (int i = 0; i < 4; ++i){
    int row = (i*4 + w)*8 + srow;
    gload16(Wb + (size_t)row*ldb + scb, &lsB[(i*4 + w)*1024]);
  }
  __syncthreads();

  s16x8 af[4][2], bfr[4][2];
  #pragma unroll
  for (int m = 0; m < 4; ++m){
    int row = wr*64 + m*16 + fr;
    af[m][0] = *(const s16x8*)&lsA[row*128 + (( 0 + fg*16) ^ fsw)];
    af[m][1] = *(const s16x8*)&lsA[row*128 + ((64 + fg*16) ^ fsw)];
  }
  #pragma unroll
  for (int n = 0; n < 4; ++n){
    int row = wc*64 + n*16 + fr;
    bfr[n][0] = *(const s16x8*)&lsB[row*128 + (( 0 + fg*16) ^ fsw)];
    bfr[n][1] = *(const s16x8*)&lsB[row*128 + ((64 + fg*16) ^ fsw)];
  }
  #pragma unroll
  for (int m = 0; m < 4; ++m)
    #pragma unroll
    for (int n = 0; n < 4; ++n){
      acc[m][n] = __builtin_amdgcn_mfma_f32_16x16x32_bf16(af[m][0], bfr[n][0], acc[m][n], 0, 0, 0);
      acc[m][n] = __builtin_amdgcn_mfma_f32_16x16x32_bf16(af[m][1], bfr[n][1], acc[m][n], 0, 0, 0);
    }

  const int orow0 = (m0 - d*8192) + wr*64, ocol0 = n0 + wc*64;
  #pragma unroll
  for (int n = 0; n < 4; ++n){
    int col = ocol0 + n*16 + fr;
    float bv = bias[col];
    #pragma unroll
    for (int m = 0; m < 4; ++m){
      int rbase = orow0 + m*16 + fg*4;
      #pragma unroll
      for (int r = 0; r < 4; ++r){
        float v = acc[m][n][r] + bv;
        v = (v > 20.f) ? v : log1pf(__expf(v));          // softplus
        outp[(size_t)(rbase + r) * 1024 + col] = f2b(v);
      }
    }
  }
}

// ---------------- stem im2col: x -> conv_a patches (bf16) + maxpool (bf16) --
__global__ __launch_bounds__(256) void im2col_kernel(
    const float* __restrict__ x_flat, bf16* __restrict__ Aa, bf16* __restrict__ P)
{
  __shared__ float xs[512][8];
  const int n = blockIdx.x, tid = threadIdx.x;
  const float* xr = x_flat + (size_t)n * 3584;
  for (int i = tid; i < 3584; i += 256) xs[i / 7][i % 7] = xr[i];
  __syncthreads();
  bf16* Ar = Aa + (size_t)n * 4 * 1536;
  for (int i = tid; i < 6144; i += 256){
    int t = i / 1536, col = i - t*1536;
    int c = col / 3, kk = col - c*3;
    int p = 2*t - 1 + kk;
    float v = (p >= 0 && p < 7) ? xs[c][p] : 0.f;
    Ar[i] = f2b(v);
  }
  bf16* Pr = P + (size_t)n * 4 * 512;
  for (int i = tid; i < 2048; i += 256){
    int t = i >> 9, c = i & 511;
    int st = 2*t - 1;
    float m = -1e30f;
    #pragma unroll
    for (int k = 0; k < 3; ++k){ int p = st + k; if (p >= 0 && p < 7) m = fmaxf(m, xs[c][p]); }
    Pr[i] = f2b(m);
  }
}

// ---------------- SE: mean over t -> 2 matvecs -> sigmoid -> scale h in place
__global__ __launch_bounds__(256) void se_kernel(
    const float* __restrict__ sw1, const float* __restrict__ sb1,
    const float* __restrict__ sw2, const float* __restrict__ sb2,
    float* __restrict__ h)
{
  __shared__ float yms[512];
  __shared__ float s1s[32];
  const int n = blockIdx.x, tid = threadIdx.x;
  float* hb = h + (size_t)n * 2048;
  for (int c = tid; c < 512; c += 256)
    yms[c] = 0.25f * (hb[c] + hb[512+c] + hb[1024+c] + hb[1536+c]);
  __syncthreads();
  {
    int o = tid >> 3, sl = tid & 7;
    const float* wr = sw1 + (size_t)o * 512 + sl*64;
    const float* ym = yms + sl*64;
    float a = 0.f;
    #pragma unroll 16
    for (int i = 0; i < 64; ++i) a += wr[i] * ym[i];
    a += __shfl_down(a, 4, 8);
    a += __shfl_down(a, 2, 8);
    a += __shfl_down(a, 1, 8);
    if (sl == 0) s1s[o] = fmaxf(a + sb1[o], 0.f);
  }
  __syncthreads();
  for (int c = tid; c < 512; c += 256){
    float a = sb2[c];
    const float* wr = sw2 + (size_t)c * 32;
    #pragma unroll
    for (int j = 0; j < 32; ++j) a += wr[j] * s1s[j];
    float s = 1.f / (1.f + __expf(-a));
    #pragma unroll
    for (int t = 0; t < 4; ++t) hb[t*512 + c] *= s;
  }
}

// ---------------- layernorm rows of 512: f32 in -> bf16 out ----------------
__global__ __launch_bounds__(256) void ln_kernel(
    const float* __restrict__ x, const float* __restrict__ g,
    const float* __restrict__ b, bf16* __restrict__ out)
{
  __shared__ float red[4];
  const int row = blockIdx.x, t = threadIdx.x;
  const float* xr = x + (size_t)row * 512;
  float v0 = xr[t], v1 = xr[t + 256];
  float s = block_sum256(v0 + v1, red);
  float mu = s * (1.f/512.f);
  float d0 = v0 - mu, d1 = v1 - mu;
  float sq = block_sum256(d0*d0 + d1*d1, red);
  float rstd = rsqrtf(sq * (1.f/512.f) + 1e-5f);
  out[(size_t)row*512 + t]       = f2b(d0*rstd*g[t]     + b[t]);
  out[(size_t)row*512 + t + 256] = f2b(d1*rstd*g[t+256] + b[t+256]);
}

// ---------------- final LN + mean over t -> feat bf16 [N][512] -------------
__global__ __launch_bounds__(256) void finalln_kernel(
    const float* __restrict__ h, const float* __restrict__ g,
    const float* __restrict__ b, bf16* __restrict__ feat)
{
  __shared__ float red[4];
  const int n = blockIdx.x, t = threadIdx.x;
  float a0 = 0.f, a1 = 0.f;
  for (int tt = 0; tt < 4; ++tt){
    const float* xr = h + ((size_t)n*4 + tt)*512;
    float v0 = xr[t], v1 = xr[t+256];
    float s = block_sum256(v0 + v1, red);
    float mu = s * (1.f/512.f);
    float d0 = v0 - mu, d1 = v1 - mu;
    float sq = block_sum256(d0*d0 + d1*d1, red);
    float rstd = rsqrtf(sq * (1.f/512.f) + 1e-5f);
    a0 += d0*rstd*g[t]     + b[t];
    a1 += d1*rstd*g[t+256] + b[t+256];
  }
  feat[(size_t)n*512 + t]       = f2b(a0 * 0.25f);
  feat[(size_t)n*512 + t + 256] = f2b(a1 * 0.25f);
}

// ---------------- causal dwconv (both dirs) + silu, 4 ch/thread ------------
__global__ __launch_bounds__(256) void dwconv2_kernel(
    const bf16* __restrict__ xz, const float* __restrict__ cw,
    const float* __restrict__ cb, bf16* __restrict__ u)
{
  const int n = blockIdx.x;
  const int c4 = threadIdx.x * 4;
  ushort4 in4[4];
  #pragma unroll
  for (int t = 0; t < 4; ++t)
    in4[t] = *reinterpret_cast<const ushort4*>(&xz[((size_t)n*4 + t)*2048 + c4]);
  #pragma unroll
  for (int d = 0; d < 2; ++d){
    const float* cwd = cw + d*4096;
    const float* cbd = cb + d*1024;
    ushort4 out[4];
    #pragma unroll
    for (int j = 0; j < 4; ++j){
      float xa[4];
      #pragma unroll
      for (int t = 0; t < 4; ++t){
        int ts = d ? 3 - t : t;
        unsigned short us = j==0?in4[ts].x : j==1?in4[ts].y : j==2?in4[ts].z : in4[ts].w;
        xa[t] = u2f(us);
      }
      float4 wv = *reinterpret_cast<const float4*>(&cwd[(c4 + j)*4]);
      float bb = cbd[c4 + j];
      float o[4];
      o[0] = xa[0]*wv.w + bb;
      o[1] = xa[0]*wv.z + xa[1]*wv.w + bb;
      o[2] = xa[0]*wv.y + xa[1]*wv.z + xa[2]*wv.w + bb;
      o[3] = xa[0]*wv.x + xa[1]*wv.y + xa[2]*wv.z + xa[3]*wv.w + bb;
      #pragma unroll
      for (int t = 0; t < 4; ++t){
        float v = o[t];
        float sv = v / (1.f + __expf(-v));
        unsigned short us = __bfloat16_as_ushort(f2b(sv));
        if (j==0) out[t].x = us; else if (j==1) out[t].y = us;
        else if (j==2) out[t].z = us; else out[t].w = us;
      }
    }
    #pragma unroll
    for (int t = 0; t < 4; ++t)
      *reinterpret_cast<ushort4*>(&u[(size_t)d*8388608 + ((size_t)n*4 + t)*1024 + c4]) = out[t];
  }
}

// ---------------- fused bidirectional scan + gate --------------------------
// dbl f32 [8192][128]: dir d cols d*64+{0..15 B, 16..31 C}.
// dt2 bf16 [2][8192][1024] (softplus applied). Atab2 pre-scaled by log2e.
// Output gated (overlays u dir0): gated[t][c] = (y0[t]+y1[t]) * silu(z[t][c]).
__global__ __launch_bounds__(256) void scan2_kernel(
    const float* __restrict__ dbl, const bf16* __restrict__ dt2,
    const bf16* __restrict__ u, const bf16* __restrict__ xz,
    const float* __restrict__ Atab2, const float* __restrict__ Dp,
    bf16* __restrict__ gated)
{
  __shared__ float Bs[2][4][16], Cs[2][4][16];
  const int n = blockIdx.x, g = blockIdx.y, tid = threadIdx.x;
  {
    int t = tid >> 6, j = tid & 63;      // 256 threads: t 0..3, j 0..63
    int d = j >> 5, jj = j & 31;
    float v = dbl[((size_t)n*4 + t)*128 + d*64 + jj];
    if (jj < 16) Bs[d][t][jj] = v; else Cs[d][t][jj-16] = v;
  }
  __syncthreads();
  const int c = g*256 + tid;
  const size_t base = (size_t)n*4*1024 + c;
  float yo0[4], yo1[4];
  float hs[16];
  // ---- direction 0 ----
  {
    float A[16];
    const float4* ap = reinterpret_cast<const float4*>(Atab2 + (size_t)c*16);
    #pragma unroll
    for (int q = 0; q < 4; ++q){
      float4 v = ap[q];
      A[q*4+0]=v.x; A[q*4+1]=v.y; A[q*4+2]=v.z; A[q*4+3]=v.w;
    }
    const float Dpc = Dp[c];
    #pragma unroll
    for (int s = 0; s < 16; ++s) hs[s] = 0.f;
    #pragma unroll
    for (int t = 0; t < 4; ++t){
      float dtv = bfu(dt2[base + (size_t)t*1024]);
      float uv  = bfu(u  [base + (size_t)t*1024]);
      float du = dtv * uv;
      float yv = 0.f;
      #pragma unroll
      for (int s = 0; s < 16; ++s){
        float dA = __builtin_amdgcn_exp2f(dtv * A[s]);
        hs[s] = dA * hs[s] + du * Bs[0][t][s];
        yv += hs[s] * Cs[0][t][s];
      }
      yo0[t] = yv + uv * Dpc;
    }
  }
  // ---- direction 1 (time-reversed input; output flipped) ----
  {
    float A[16];
    const float4* ap = reinterpret_cast<const float4*>(Atab2 + 16384 + (size_t)c*16);
    #pragma unroll
    for (int q = 0; q < 4; ++q){
      float4 v = ap[q];
      A[q*4+0]=v.x; A[q*4+1]=v.y; A[q*4+2]=v.z; A[q*4+3]=v.w;
    }
    const float Dpc = Dp[1024 + c];
    #pragma unroll
    for (int s = 0; s < 16; ++s) hs[s] = 0.f;
    #pragma unroll
    for (int t = 0; t < 4; ++t){
      float dtv = bfu(dt2[8388608 + base + (size_t)t*1024]);
      float uv  = bfu(u  [8388608 + base + (size_t)t*1024]);
      float du = dtv * uv;
      float yv = 0.f;
      #pragma unroll
      for (int s = 0; s < 16; ++s){
        float dA = __builtin_amdgcn_exp2f(dtv * A[s]);
        hs[s] = dA * hs[s] + du * Bs[1][t][s];
        yv += hs[s] * Cs[1][t][s];
      }
      yo1[3 - t] = yv + uv * Dpc;
    }
  }
  // ---- gate + store (same thread wrote/read only channel c) ----
  #pragma unroll
  for (int t = 0; t < 4; ++t){
    float z = bfu(xz[(size_t)(n*4 + t)*2048 + 1024 + c]);
    float sv = z / (1.f + __expf(-z));
    gated[base + (size_t)t*1024] = f2b((yo0[t] + yo1[t]) * sv);
  }
}

// ---------------- launch ---------------------------------------------------
extern "C" void kernel_launch(void* const* d_in, const int* in_sizes, int n_in,
                              void* d_out, int out_size, void* d_ws, size_t ws_size,
                              hipStream_t stream)
{
  const float* x_flat    = (const float*)d_in[0];
  const float* conv_a_w  = (const float*)d_in[1];
  const float* conv_p_w  = (const float*)d_in[2];
  const float* se_w1     = (const float*)d_in[3];
  const float* se_b1     = (const float*)d_in[4];
  const float* se_w2     = (const float*)d_in[5];
  const float* se_b2     = (const float*)d_in[6];
  const float* ln_g      = (const float*)d_in[7];
  const float* ln_b      = (const float*)d_in[8];
  const float* in_proj_w = (const float*)d_in[9];
  const float* conv_w    = (const float*)d_in[10];
  const float* conv_b    = (const float*)d_in[11];
  const float* x_proj_w  = (const float*)d_in[12];
  const float* dt_proj_w = (const float*)d_in[13];
  const float* dt_proj_b = (const float*)d_in[14];
  const float* A_log     = (const float*)d_in[15];
  const float* D_param   = (const float*)d_in[16];
  const float* out_proj_w= (const float*)d_in[17];
  const float* out_ln_g  = (const float*)d_in[18];
  const float* out_ln_b  = (const float*)d_in[19];
  const float* mlp_w1    = (const float*)d_in[20];
  const float* mlp_b1    = (const float*)d_in[21];
  const float* mlp_w2    = (const float*)d_in[22];
  const float* mlp_b2    = (const float*)d_in[23];

  char* ws = (char*)d_ws;
  const size_t OFF_H    = 0;                       // f32  8192*512  = 16.78MB
  const size_t OFF_HN   = OFF_H    + 16777216;     // bf16 8192*512  (feat overlay)
  const size_t OFF_XZ   = OFF_HN   + 8388608;      // bf16 8192*2048 (z1 overlay)
  const size_t OFF_U    = OFF_XZ   + 33554432;     // bf16 u[2] 8192*1024 = 33.55MB
  const size_t OFF_SCR  = OFF_U    + 33554432;     // 25.17MB: Aa(stem)/dbl+dtrb(layers)/wb1(MLP)
  const size_t OFF_YB   = OFF_SCR  + 25165824;     // 33.55MB: Pm+wa+wp(stem)/dt2(layers)/wb2(MLP)
  const size_t OFF_WB   = OFF_YB   + 33554432;     // bf16 in_proj+out_proj
  const size_t OFF_WXP  = OFF_WB   + 6291456;      // bf16 2*256*1024 packed x_proj
  const size_t OFF_WDT  = OFF_WXP  + 1048576;      // bf16 4*1024*64 padded dt_proj
  const size_t OFF_ATAB = OFF_WDT  + 524288;       // f32  4*1024*16
  // total = OFF_ATAB + 262144 = ~160MB

  float* h    = (float*)(ws + OFF_H);
  bf16*  hn   = (bf16*) (ws + OFF_HN);
  bf16*  xz   = (bf16*) (ws + OFF_XZ);
  bf16*  u    = (bf16*) (ws + OFF_U);
  float* dbl  = (float*)(ws + OFF_SCR);                 // [8192][128] f32
  bf16*  dtrb = (bf16*) (ws + OFF_SCR + 4194304);       // [2][8192][64]
  bf16*  dt2  = (bf16*) (ws + OFF_YB);                  // [2][8192][1024]
  bf16*  feat = (bf16*) (ws + OFF_HN);   // overlay
  bf16*  z1   = (bf16*) (ws + OFF_XZ);   // overlay
  bf16*  wbi  = (bf16*) (ws + OFF_WB);
  bf16*  wbo  = (bf16*) (ws + OFF_WB + 4194304);
  bf16*  wxp  = (bf16*) (ws + OFF_WXP);
  bf16*  wdtp = (bf16*) (ws + OFF_WDT);
  float* Atab = (float*)(ws + OFF_ATAB);
  bf16*  wb1  = (bf16*) (ws + OFF_SCR);  // overlay (MLP phase)
  bf16*  wb2  = (bf16*) (ws + OFF_YB);   // overlay (MLP phase)
  // stem-phase overlays
  bf16*  Aa   = (bf16*) (ws + OFF_SCR);
  bf16*  Pm   = (bf16*) (ws + OFF_YB);
  bf16*  wa   = (bf16*) (ws + OFF_YB + 8388608);
  bf16*  wp   = (bf16*) (ws + OFF_YB + 8388608 + 786432);
  float* outf = (float*)d_out;

  // all weight prep in one dispatch
  prep_kernel<<<2048, 256, 0, stream>>>(
      conv_a_w, conv_p_w, in_proj_w, out_proj_w, x_proj_w, dt_proj_w, A_log,
      wa, wp, wbi, wbo, wxp, wdtp, Atab);

  // stem
  im2col_kernel<<<2048, 256, 0, stream>>>(x_flat, Aa, Pm);
  mgemm_kernel<1,1,false><<<dim3(64,2), 256, 0, stream>>>(
      Aa, wa, nullptr, h, 1536, 512);
  mgemm_kernel<1,1,false><<<dim3(64,2), 256, 0, stream>>>(
      Pm, wp, nullptr, (float*)h + 256, 512, 512);
  se_kernel<<<2048, 256, 0, stream>>>(se_w1, se_b1, se_w2, se_b2, h);

  for (int l = 0; l < 2; ++l){
    ln_kernel<<<8192, 256, 0, stream>>>(h, ln_g + l*512, ln_b + l*512, hn);
    mgemm_kernel<0,0,false><<<dim3(64,16), 256, 0, stream>>>(
        hn, wbi + (size_t)l*2048*512, nullptr, xz, 512, 2048);
    dwconv2_kernel<<<2048, 256, 0, stream>>>(
        xz, conv_w + (size_t)l*8192, conv_b + (size_t)l*2048, u);
    bgemm_kernel<<<dim3(64,2), 256, 0, stream>>>(
        u, wxp + (size_t)l*262144, dtrb, dbl);
    dtgemm_kernel<<<dim3(128,8), 256, 0, stream>>>(
        dtrb, wdtp + (size_t)l*131072, dt_proj_b + (size_t)l*2048, dt2);
    scan2_kernel<<<dim3(2048,4), 256, 0, stream>>>(
        dbl, dt2, u, xz, Atab + (size_t)l*32768, D_param + (size_t)l*2048,
        u /* gated overlays u dir0 */);
    mgemm_kernel<0,2,false><<<dim3(64,4), 256, 0, stream>>>(
        u, wbo + (size_t)l*512*1024, nullptr, h, 1024, 512);
  }

  finalln_kernel<<<2048, 256, 0, stream>>>(h, out_ln_g, out_ln_b, feat);

  mlpprep_kernel<<<4096, 256, 0, stream>>>(
      (const float4*)mlp_w1, (const float4*)mlp_w2, (ushort4*)wb1, (ushort4*)wb2);

  mgemm_kernel<1,0,true><<<dim3(16,32), 256, 0, stream>>>(
      feat, wb1, mlp_b1, z1, 512, 4096);
  mgemm_kernel<1,1,true><<<dim3(16,32), 256, 0, stream>>>(
      z1, wb2, mlp_b2, outf, 4096, 4096);
}

// Round 12
// 653.602 us; speedup vs baseline: 4.1649x; 1.0396x over previous
//
#include <hip/hip_runtime.h>
#include <hip/hip_bf16.h>

typedef __hip_bfloat16 bf16;
typedef __attribute__((ext_vector_type(8))) short s16x8;
typedef __attribute__((ext_vector_type(4))) float f32x4;

__device__ __forceinline__ float u2f(unsigned short u){
  union { unsigned int i; float f; } v; v.i = ((unsigned int)u) << 16; return v.f;
}
__device__ __forceinline__ float bfu(bf16 x){ return __bfloat162float(x); }
__device__ __forceinline__ bf16  f2b(float x){ return __float2bfloat16(x); }

__device__ __forceinline__ void gload16(const void* g, void* l){
  __builtin_amdgcn_global_load_lds(
      (const __attribute__((address_space(1))) void*)g,
      (__attribute__((address_space(3))) void*)l, 16, 0, 0);
}

// ---------------- block reduction (256 threads) ----------------
__device__ __forceinline__ float block_sum256(float v, float* red){
  #pragma unroll
  for (int o = 32; o > 0; o >>= 1) v += __shfl_down(v, o, 64);
  int lane = threadIdx.x & 63, wid = threadIdx.x >> 6;
  if (lane == 0) red[wid] = v;
  __syncthreads();
  float r = red[0] + red[1] + red[2] + red[3];
  __syncthreads();
  return r;
}

__device__ __forceinline__ float wave_sum(float v){
  #pragma unroll
  for (int o = 1; o < 64; o <<= 1) v += __shfl_xor(v, o, 64);
  return v;
}

__device__ __forceinline__ ushort4 cvt4(float4 v){
  ushort4 o;
  o.x = __bfloat16_as_ushort(f2b(v.x));
  o.y = __bfloat16_as_ushort(f2b(v.y));
  o.z = __bfloat16_as_ushort(f2b(v.z));
  o.w = __bfloat16_as_ushort(f2b(v.w));
  return o;
}

// ---------------- unified prep: all weight conversions in ONE dispatch -----
__global__ __launch_bounds__(256) void prep_kernel(
    const float* __restrict__ caw, const float* __restrict__ cpw,
    const float* __restrict__ ipw, const float* __restrict__ opw,
    const float* __restrict__ xpw, const float* __restrict__ dtw,
    const float* __restrict__ alog,
    bf16* __restrict__ wa, bf16* __restrict__ wp,
    bf16* __restrict__ wbi, bf16* __restrict__ wbo,
    bf16* __restrict__ wxp, bf16* __restrict__ wdtp,
    float* __restrict__ atab)
{
  for (int i = blockIdx.x*256 + threadIdx.x; i < 1769472; i += gridDim.x*256){
    if (i < 917504){
      int j = i;
      const float4* src; ushort4* dst;
      if (j < 98304)      { src = (const float4*)caw; dst = (ushort4*)wa; }
      else if (j < 131072){ j -= 98304;  src = (const float4*)cpw; dst = (ushort4*)wp; }
      else if (j < 655360){ j -= 131072; src = (const float4*)ipw; dst = (ushort4*)wbi; }
      else                { j -= 655360; src = (const float4*)opw; dst = (ushort4*)wbo; }
      dst[j] = cvt4(src[j]);
    } else if (i < 1441792){
      int idx = i - 917504;                 // xpw pad: [L][2*128][1024]
      int l = idx >> 18, rem = idx & 262143, row = rem >> 10, c = rem & 1023;
      int d = row >> 7, r = row & 127;
      float v = (r < 64) ? xpw[(((size_t)l*2 + d)*64 + r)*1024 + c] : 0.f;
      wxp[idx] = f2b(v);
    } else if (i < 1703936){
      int idx = i - 1441792;                // wdt pad: [4][1024][64]
      int ld = idx >> 16, rem = idx & 65535, r = rem >> 6, cc = rem & 63;
      float v = (cc < 32) ? dtw[((size_t)ld*1024 + r)*32 + cc] : 0.f;
      wdtp[idx] = f2b(v);
    } else {
      int idx = i - 1703936;                // atab (pre-scaled by log2 e)
      atab[idx] = -__expf(alog[idx]) * 1.44269504088896f;
    }
  }
}

// ---------------- MLP weight conversion (one dispatch) ---------------------
__global__ __launch_bounds__(256) void mlpprep_kernel(
    const float4* __restrict__ w1, const float4* __restrict__ w2,
    ushort4* __restrict__ o1, ushort4* __restrict__ o2)
{
  for (int i = blockIdx.x*256 + threadIdx.x; i < 4718592; i += gridDim.x*256){
    if (i < 524288) o1[i] = cvt4(w1[i]);
    else            o2[i - 524288] = cvt4(w2[i - 524288]);
  }
}

// ---------------- MFMA GEMM (BK=64): out = act(A·Wᵀ + bias) ---------------
// A,W bf16 row-major (ld = K). 128x128 tile, 4 waves. nwg%8==0.
// ACT: 0 none, 1 relu, 2 softplus. OMODE: 0 bf16, 1 f32, 2 f32 +=.
template<int ACT, int OMODE, bool HASBIAS>
__global__ __launch_bounds__(256) void mgemm_kernel(
    const bf16* __restrict__ A, const bf16* __restrict__ W,
    const float* __restrict__ bias, void* __restrict__ outp,
    int K, int ldo)
{
  __shared__ char lsA[16384];
  __shared__ char lsB[16384];
  const int tid = threadIdx.x;
  const int w = tid >> 6, l = tid & 63;
  const int nwg = gridDim.x * gridDim.y;
  const int lin = blockIdx.y * gridDim.x + blockIdx.x;
  const int cpx = nwg >> 3;
  const int swz = (lin & 7) * cpx + (lin >> 3);
  const int m0 = (swz % gridDim.x) * 128, n0 = (swz / gridDim.x) * 128;
  const int wr = w >> 1, wc = w & 1;
  const size_t ldb = (size_t)K * 2;
  const char* Ab = (const char*)A + (size_t)m0 * ldb;
  const char* Wb = (const char*)W + (size_t)n0 * ldb;

  const int srow = l >> 3;
  const int scb  = ((l & 7) ^ srow) << 4;
  const int fr = l & 15;
  const int fg = l >> 4;
  const int fsw = (fr & 7) << 4;

  f32x4 acc[4][4];
  #pragma unroll
  for (int m = 0; m < 4; ++m)
    #pragma unroll
    for (int n = 0; n < 4; ++n) acc[m][n] = (f32x4){0.f,0.f,0.f,0.f};

  const int nk = K >> 6;
  for (int kt = 0; kt < nk; ++kt){
    const char* As = Ab + (size_t)kt * 128;
    const char* Ws = Wb + (size_t)kt * 128;
    #pragma unroll
    for (int i = 0; i < 4; ++i){
      int row = (i*4 + w)*8 + srow;
      gload16(As + (size_t)row*ldb + scb, &lsA[(i*4 + w)*1024]);
    }
    #pragma unroll
    for (int i = 0; i < 4; ++i){
      int row = (i*4 + w)*8 + srow;
      gload16(Ws + (size_t)row*ldb + scb, &lsB[(i*4 + w)*1024]);
    }
    __syncthreads();

    s16x8 af[4][2], bfr[4][2];
    #pragma unroll
    for (int m = 0; m < 4; ++m){
      int row = wr*64 + m*16 + fr;
      af[m][0] = *(const s16x8*)&lsA[row*128 + (( 0 + fg*16) ^ fsw)];
      af[m][1] = *(const s16x8*)&lsA[row*128 + ((64 + fg*16) ^ fsw)];
    }
    #pragma unroll
    for (int n = 0; n < 4; ++n){
      int row = wc*64 + n*16 + fr;
      bfr[n][0] = *(const s16x8*)&lsB[row*128 + (( 0 + fg*16) ^ fsw)];
      bfr[n][1] = *(const s16x8*)&lsB[row*128 + ((64 + fg*16) ^ fsw)];
    }
    #pragma unroll
    for (int m = 0; m < 4; ++m)
      #pragma unroll
      for (int n = 0; n < 4; ++n){
        acc[m][n] = __builtin_amdgcn_mfma_f32_16x16x32_bf16(af[m][0], bfr[n][0], acc[m][n], 0, 0, 0);
        acc[m][n] = __builtin_amdgcn_mfma_f32_16x16x32_bf16(af[m][1], bfr[n][1], acc[m][n], 0, 0, 0);
      }
    __syncthreads();
  }

  const int orow0 = m0 + wr*64, ocol0 = n0 + wc*64;
  #pragma unroll
  for (int n = 0; n < 4; ++n){
    int col = ocol0 + n*16 + fr;
    float bv = HASBIAS ? bias[col] : 0.f;
    #pragma unroll
    for (int m = 0; m < 4; ++m){
      int rbase = orow0 + m*16 + fg*4;
      #pragma unroll
      for (int r = 0; r < 4; ++r){
        float v = acc[m][n][r] + bv;
        if (ACT == 1) v = fmaxf(v, 0.f);
        if (ACT == 2) v = (v > 20.f) ? v : log1pf(__expf(v));
        size_t oi = (size_t)(rbase + r) * ldo + col;
        if (OMODE == 0)      ((bf16*)outp)[oi] = f2b(v);
        else if (OMODE == 1) ((float*)outp)[oi] = v;
        else                 ((float*)outp)[oi] += v;
      }
    }
  }
}

// ---------------- MFMA GEMM (BK=128): half the barriers -------------------
// Use ONLY where blocks/CU is not reduced by 64KB LDS (grid <= 2 blocks/CU).
template<int ACT, int OMODE, bool HASBIAS>
__global__ __launch_bounds__(256) void mgemm128_kernel(
    const bf16* __restrict__ A, const bf16* __restrict__ W,
    const float* __restrict__ bias, void* __restrict__ outp,
    int K, int ldo)
{
  __shared__ char lsA[32768];   // 128 rows x 256B
  __shared__ char lsB[32768];
  const int tid = threadIdx.x;
  const int w = tid >> 6, l = tid & 63;
  const int nwg = gridDim.x * gridDim.y;
  const int lin = blockIdx.y * gridDim.x + blockIdx.x;
  const int cpx = nwg >> 3;
  const int swz = (lin & 7) * cpx + (lin >> 3);
  const int m0 = (swz % gridDim.x) * 128, n0 = (swz / gridDim.x) * 128;
  const int wr = w >> 1, wc = w & 1;
  const size_t ldb = (size_t)K * 2;
  const char* Ab = (const char*)A + (size_t)m0 * ldb;
  const char* Wb = (const char*)W + (size_t)n0 * ldb;

  // staging: 32 chunks/matrix (1024B each = 4 rows x 256B), 8 per wave
  const int srow4 = l >> 4;            // row-within-chunk 0..3
  const int slot  = l & 15;            // 16B slot within 256B row
  const int fr = l & 15;
  const int fg = l >> 4;
  const int fx = fr & 7;               // read-side row XOR

  f32x4 acc[4][4];
  #pragma unroll
  for (int m = 0; m < 4; ++m)
    #pragma unroll
    for (int n = 0; n < 4; ++n) acc[m][n] = (f32x4){0.f,0.f,0.f,0.f};

  const int nk = K >> 7;
  for (int kt = 0; kt < nk; ++kt){
    const char* As = Ab + (size_t)kt * 256;
    const char* Ws = Wb + (size_t)kt * 256;
    #pragma unroll
    for (int i = 0; i < 8; ++i){
      int c = i*4 + w;                 // chunk 0..31
      int row = c*4 + srow4;
      int colb = (slot ^ (row & 7)) << 4;
      gload16(As + (size_t)row*ldb + colb, &lsA[c*1024]);
      gload16(Ws + (size_t)row*ldb + colb, &lsB[c*1024]);
    }
    __syncthreads();

    #pragma unroll
    for (int half = 0; half < 2; ++half){
      s16x8 af[4][2], bfr[4][2];
      #pragma unroll
      for (int m = 0; m < 4; ++m){
        int row = wr*64 + m*16 + fr;
        af[m][0] = *(const s16x8*)&lsA[row*256 + ((((half*2+0)*4 + fg) ^ fx) << 4)];
        af[m][1] = *(const s16x8*)&lsA[row*256 + ((((half*2+1)*4 + fg) ^ fx) << 4)];
      }
      #pragma unroll
      for (int n = 0; n < 4; ++n){
        int row = wc*64 + n*16 + fr;
        bfr[n][0] = *(const s16x8*)&lsB[row*256 + ((((half*2+0)*4 + fg) ^ fx) << 4)];
        bfr[n][1] = *(const s16x8*)&lsB[row*256 + ((((half*2+1)*4 + fg) ^ fx) << 4)];
      }
      #pragma unroll
      for (int m = 0; m < 4; ++m)
        #pragma unroll
        for (int n = 0; n < 4; ++n){
          acc[m][n] = __builtin_amdgcn_mfma_f32_16x16x32_bf16(af[m][0], bfr[n][0], acc[m][n], 0, 0, 0);
          acc[m][n] = __builtin_amdgcn_mfma_f32_16x16x32_bf16(af[m][1], bfr[n][1], acc[m][n], 0, 0, 0);
        }
    }
    __syncthreads();
  }

  const int orow0 = m0 + wr*64, ocol0 = n0 + wc*64;
  #pragma unroll
  for (int n = 0; n < 4; ++n){
    int col = ocol0 + n*16 + fr;
    float bv = HASBIAS ? bias[col] : 0.f;
    #pragma unroll
    for (int m = 0; m < 4; ++m){
      int rbase = orow0 + m*16 + fg*4;
      #pragma unroll
      for (int r = 0; r < 4; ++r){
        float v = acc[m][n][r] + bv;
        if (ACT == 1) v = fmaxf(v, 0.f);
        if (ACT == 2) v = (v > 20.f) ? v : log1pf(__expf(v));
        size_t oi = (size_t)(rbase + r) * ldo + col;
        if (OMODE == 0)      ((bf16*)outp)[oi] = f2b(v);
        else if (OMODE == 1) ((float*)outp)[oi] = v;
        else                 ((float*)outp)[oi] += v;
      }
    }
  }
}

// ---------------- batched x_proj GEMM: both directions in one launch -------
__global__ __launch_bounds__(256) void bgemm_kernel(
    const bf16* __restrict__ A, const bf16* __restrict__ W,
    bf16* __restrict__ dtr_buf, float* __restrict__ dbl)
{
  __shared__ char lsA[16384];
  __shared__ char lsB[16384];
  const int tid = threadIdx.x;
  const int w = tid >> 6, l = tid & 63;
  const int nwg = gridDim.x * 2;
  const int lin = blockIdx.y * gridDim.x + blockIdx.x;
  const int cpx = nwg >> 3;
  const int swz = (lin & 7) * cpx + (lin >> 3);
  const int m0 = (swz % gridDim.x) * 128;
  const int d  = swz / gridDim.x;
  const int K = 1024;
  const int wr = w >> 1, wc = w & 1;
  const size_t ldb = (size_t)K * 2;
  const char* Ab = (const char*)(A + (size_t)d*8388608) + (size_t)m0 * ldb;
  const char* Wb = (const char*)(W + (size_t)d*131072);

  const int srow = l >> 3;
  const int scb  = ((l & 7) ^ srow) << 4;
  const int fr = l & 15;
  const int fg = l >> 4;
  const int fsw = (fr & 7) << 4;

  f32x4 acc[4][4];
  #pragma unroll
  for (int m = 0; m < 4; ++m)
    #pragma unroll
    for (int n = 0; n < 4; ++n) acc[m][n] = (f32x4){0.f,0.f,0.f,0.f};

  const int nk = K >> 6;
  for (int kt = 0; kt < nk; ++kt){
    const char* As = Ab + (size_t)kt * 128;
    const char* Ws = Wb + (size_t)kt * 128;
    #pragma unroll
    for (int i = 0; i < 4; ++i){
      int row = (i*4 + w)*8 + srow;
      gload16(As + (size_t)row*ldb + scb, &lsA[(i*4 + w)*1024]);
    }
    #pragma unroll
    for (int i = 0; i < 4; ++i){
      int row = (i*4 + w)*8 + srow;
      gload16(Ws + (size_t)row*ldb + scb, &lsB[(i*4 + w)*1024]);
    }
    __syncthreads();

    s16x8 af[4][2], bfr[4][2];
    #pragma unroll
    for (int m = 0; m < 4; ++m){
      int row = wr*64 + m*16 + fr;
      af[m][0] = *(const s16x8*)&lsA[row*128 + (( 0 + fg*16) ^ fsw)];
      af[m][1] = *(const s16x8*)&lsA[row*128 + ((64 + fg*16) ^ fsw)];
    }
    #pragma unroll
    for (int n = 0; n < 4; ++n){
      int row = wc*64 + n*16 + fr;
      bfr[n][0] = *(const s16x8*)&lsB[row*128 + (( 0 + fg*16) ^ fsw)];
      bfr[n][1] = *(const s16x8*)&lsB[row*128 + ((64 + fg*16) ^ fsw)];
    }
    #pragma unroll
    for (int m = 0; m < 4; ++m)
      #pragma unroll
      for (int n = 0; n < 4; ++n){
        acc[m][n] = __builtin_amdgcn_mfma_f32_16x16x32_bf16(af[m][0], bfr[n][0], acc[m][n], 0, 0, 0);
        acc[m][n] = __builtin_amdgcn_mfma_f32_16x16x32_bf16(af[m][1], bfr[n][1], acc[m][n], 0, 0, 0);
      }
    __syncthreads();
  }

  const int orow0 = m0 + wr*64, c0 = wc*64;
  #pragma unroll
  for (int n = 0; n < 4; ++n){
    int col = c0 + n*16 + fr;                   // 0..127 within dir
    #pragma unroll
    for (int m = 0; m < 4; ++m){
      int rbase = orow0 + m*16 + fg*4;
      #pragma unroll
      for (int r = 0; r < 4; ++r){
        float v = acc[m][n][r];
        int row = rbase + r;
        if (col < 32)
          dtr_buf[((size_t)d*8192 + row)*64 + col] = f2b(v);
        else if (col < 64)
          dbl[(size_t)row*128 + d*64 + (col - 32)] = v;
        else if (col < 96)
          dtr_buf[((size_t)d*8192 + row)*64 + (col - 32)] = f2b(v);  // pad zeros
      }
    }
  }
}

// ---------------- dt_proj GEMM, both dirs in one dispatch ------------------
__global__ __launch_bounds__(256) void dtgemm_kernel(
    const bf16* __restrict__ A, const bf16* __restrict__ W2,
    const float* __restrict__ bias2, bf16* __restrict__ out2)
{
  __shared__ char lsA[16384];
  __shared__ char lsB[16384];
  const int tid = threadIdx.x;
  const int w = tid >> 6, l = tid & 63;
  const int nwg = gridDim.x * gridDim.y;          // 1024
  const int lin = blockIdx.y * gridDim.x + blockIdx.x;
  const int cpx = nwg >> 3;
  const int swz = (lin & 7) * cpx + (lin >> 3);
  const int m0 = (swz % gridDim.x) * 128, n0 = (swz / gridDim.x) * 128;
  const int d  = (m0 >= 8192) ? 1 : 0;
  const int wr = w >> 1, wc = w & 1;
  const size_t ldb = 128;
  const char* Ab = (const char*)A + (size_t)m0 * ldb;
  const char* Wb = (const char*)(W2 + (size_t)d*65536) + (size_t)n0 * ldb;
  const float* bias = bias2 + d*1024;
  bf16* outp = out2 + (size_t)d*8388608;

  const int srow = l >> 3;
  const int scb  = ((l & 7) ^ srow) << 4;
  const int fr = l & 15, fg = l >> 4;
  const int fsw = (fr & 7) << 4;

  f32x4 acc[4][4];
  #pragma unroll
  for (int m = 0; m < 4; ++m)
    #pragma unroll
    for (int n = 0; n < 4; ++n) acc[m][n] = (f32x4){0.f,0.f,0.f,0.f};

  #pragma unroll
  for (int i = 0; i < 4; ++i){
    int row = (i*4 + w)*8 + srow;
    gload16(Ab + (size_t)row*ldb + scb, &lsA[(i*4 + w)*1024]);
  }
  #pragma unroll
  for (int i = 0; i < 4; ++i){
    int row = (i*4 + w)*8 + srow;
    gload16(Wb + (size_t)row*ldb + scb, &lsB[(i*4 + w)*1024]);
  }
  __syncthreads();

  s16x8 af[4][2], bfr[4][2];
  #pragma unroll
  for (int m = 0; m < 4; ++m){
    int row = wr*64 + m*16 + fr;
    af[m][0] = *(const s16x8*)&lsA[row*128 + (( 0 + fg*16) ^ fsw)];
    af[m][1] = *(const s16x8*)&lsA[row*128 + ((64 + fg*16) ^ fsw)];
  }
  #pragma unroll
  for (int n = 0; n < 4; ++n){
    int row = wc*64 + n*16 + fr;
    bfr[n][0] = *(const s16x8*)&lsB[row*128 + (( 0 + fg*16) ^ fsw)];
    bfr[n][1] = *(const s16x8*)&lsB[row*128 + ((64 + fg*16) ^ fsw)];
  }
  #pragma unroll
  for (int m = 0; m < 4; ++m)
    #pragma unroll
    for (int n = 0; n < 4; ++n){
      acc[m][n] = __builtin_amdgcn_mfma_f32_16x16x32_bf16(af[m][0], bfr[n][0], acc[m][n], 0, 0, 0);
      acc[m][n] = __builtin_amdgcn_mfma_f32_16x16x32_bf16(af[m][1], bfr[n][1], acc[m][n], 0, 0, 0);
    }

  const int orow0 = (m0 - d*8192) + wr*64, ocol0 = n0 + wc*64;
  #pragma unroll
  for (int n = 0; n < 4; ++n){
    int col = ocol0 + n*16 + fr;
    float bv = bias[col];
    #pragma unroll
    for (int m = 0; m < 4; ++m){
      int rbase = orow0 + m*16 + fg*4;
      #pragma unroll
      for (int r = 0; r < 4; ++r){
        float v = acc[m][n][r] + bv;
        v = (v > 20.f) ? v : log1pf(__expf(v));          // softplus
        outp[(size_t)(rbase + r) * 1024 + col] = f2b(v);
      }
    }
  }
}

// ---------------- stem im2col: x -> conv_a patches (bf16) + maxpool (bf16) --
__global__ __launch_bounds__(256) void im2col_kernel(
    const float* __restrict__ x_flat, bf16* __restrict__ Aa, bf16* __restrict__ P)
{
  __shared__ float xs[512][8];
  const int n = blockIdx.x, tid = threadIdx.x;
  const float* xr = x_flat + (size_t)n * 3584;
  for (int i = tid; i < 3584; i += 256) xs[i / 7][i % 7] = xr[i];
  __syncthreads();
  bf16* Ar = Aa + (size_t)n * 4 * 1536;
  for (int i = tid; i < 6144; i += 256){
    int t = i / 1536, col = i - t*1536;
    int c = col / 3, kk = col - c*3;
    int p = 2*t - 1 + kk;
    float v = (p >= 0 && p < 7) ? xs[c][p] : 0.f;
    Ar[i] = f2b(v);
  }
  bf16* Pr = P + (size_t)n * 4 * 512;
  for (int i = tid; i < 2048; i += 256){
    int t = i >> 9, c = i & 511;
    int st = 2*t - 1;
    float m = -1e30f;
    #pragma unroll
    for (int k = 0; k < 3; ++k){ int p = st + k; if (p >= 0 && p < 7) m = fmaxf(m, xs[c][p]); }
    Pr[i] = f2b(m);
  }
}

// ---------------- SE: mean over t -> 2 matvecs -> sigmoid -> scale h in place
__global__ __launch_bounds__(256) void se_kernel(
    const float* __restrict__ sw1, const float* __restrict__ sb1,
    const float* __restrict__ sw2, const float* __restrict__ sb2,
    float* __restrict__ h)
{
  __shared__ float yms[512];
  __shared__ float s1s[32];
  const int n = blockIdx.x, tid = threadIdx.x;
  float* hb = h + (size_t)n * 2048;
  for (int c = tid; c < 512; c += 256)
    yms[c] = 0.25f * (hb[c] + hb[512+c] + hb[1024+c] + hb[1536+c]);
  __syncthreads();
  {
    int o = tid >> 3, sl = tid & 7;
    const float* wr = sw1 + (size_t)o * 512 + sl*64;
    const float* ym = yms + sl*64;
    float a = 0.f;
    #pragma unroll 16
    for (int i = 0; i < 64; ++i) a += wr[i] * ym[i];
    a += __shfl_down(a, 4, 8);
    a += __shfl_down(a, 2, 8);
    a += __shfl_down(a, 1, 8);
    if (sl == 0) s1s[o] = fmaxf(a + sb1[o], 0.f);
  }
  __syncthreads();
  for (int c = tid; c < 512; c += 256){
    float a = sb2[c];
    const float* wr = sw2 + (size_t)c * 32;
    #pragma unroll
    for (int j = 0; j < 32; ++j) a += wr[j] * s1s[j];
    float s = 1.f / (1.f + __expf(-a));
    #pragma unroll
    for (int t = 0; t < 4; ++t) hb[t*512 + c] *= s;
  }
}

// ---------------- layernorm: wave-per-row, 4 rows/block, grid 2048 ---------
__global__ __launch_bounds__(256) void ln_kernel(
    const float* __restrict__ x, const float* __restrict__ g,
    const float* __restrict__ b, bf16* __restrict__ out)
{
  const int lane = threadIdx.x & 63, wid = threadIdx.x >> 6;
  const int row = blockIdx.x*4 + wid;
  const float4* xr = (const float4*)(x + (size_t)row*512);
  float4 v0 = xr[lane], v1 = xr[lane + 64];
  float s = wave_sum(v0.x+v0.y+v0.z+v0.w + v1.x+v1.y+v1.z+v1.w);
  float mu = s * (1.f/512.f);
  float d0x=v0.x-mu, d0y=v0.y-mu, d0z=v0.z-mu, d0w=v0.w-mu;
  float d1x=v1.x-mu, d1y=v1.y-mu, d1z=v1.z-mu, d1w=v1.w-mu;
  float sq = wave_sum(d0x*d0x+d0y*d0y+d0z*d0z+d0w*d0w +
                      d1x*d1x+d1y*d1y+d1z*d1z+d1w*d1w);
  float rstd = rsqrtf(sq * (1.f/512.f) + 1e-5f);
  float4 g0 = ((const float4*)g)[lane], g1 = ((const float4*)g)[lane+64];
  float4 b0 = ((const float4*)b)[lane], b1 = ((const float4*)b)[lane+64];
  ushort4 o0, o1;
  o0.x = __bfloat16_as_ushort(f2b(d0x*rstd*g0.x + b0.x));
  o0.y = __bfloat16_as_ushort(f2b(d0y*rstd*g0.y + b0.y));
  o0.z = __bfloat16_as_ushort(f2b(d0z*rstd*g0.z + b0.z));
  o0.w = __bfloat16_as_ushort(f2b(d0w*rstd*g0.w + b0.w));
  o1.x = __bfloat16_as_ushort(f2b(d1x*rstd*g1.x + b1.x));
  o1.y = __bfloat16_as_ushort(f2b(d1y*rstd*g1.y + b1.y));
  o1.z = __bfloat16_as_ushort(f2b(d1z*rstd*g1.z + b1.z));
  o1.w = __bfloat16_as_ushort(f2b(d1w*rstd*g1.w + b1.w));
  ushort4* orow = (ushort4*)(out + (size_t)row*512);
  orow[lane] = o0;
  orow[lane + 64] = o1;
}

// ---------------- final LN + mean over t -> feat bf16 [N][512] -------------
__global__ __launch_bounds__(256) void finalln_kernel(
    const float* __restrict__ h, const float* __restrict__ g,
    const float* __restrict__ b, bf16* __restrict__ feat)
{
  __shared__ float red[4];
  const int n = blockIdx.x, t = threadIdx.x;
  float a0 = 0.f, a1 = 0.f;
  for (int tt = 0; tt < 4; ++tt){
    const float* xr = h + ((size_t)n*4 + tt)*512;
    float v0 = xr[t], v1 = xr[t+256];
    float s = block_sum256(v0 + v1, red);
    float mu = s * (1.f/512.f);
    float d0 = v0 - mu, d1 = v1 - mu;
    float sq = block_sum256(d0*d0 + d1*d1, red);
    float rstd = rsqrtf(sq * (1.f/512.f) + 1e-5f);
    a0 += d0*rstd*g[t]     + b[t];
    a1 += d1*rstd*g[t+256] + b[t+256];
  }
  feat[(size_t)n*512 + t]       = f2b(a0 * 0.25f);
  feat[(size_t)n*512 + t + 256] = f2b(a1 * 0.25f);
}

// ---------------- causal dwconv (both dirs) + silu, 4 ch/thread ------------
__global__ __launch_bounds__(256) void dwconv2_kernel(
    const bf16* __restrict__ xz, const float* __restrict__ cw,
    const float* __restrict__ cb, bf16* __restrict__ u)
{
  const int n = blockIdx.x;
  const int c4 = threadIdx.x * 4;
  ushort4 in4[4];
  #pragma unroll
  for (int t = 0; t < 4; ++t)
    in4[t] = *reinterpret_cast<const ushort4*>(&xz[((size_t)n*4 + t)*2048 + c4]);
  #pragma unroll
  for (int d = 0; d < 2; ++d){
    const float* cwd = cw + d*4096;
    const float* cbd = cb + d*1024;
    ushort4 out[4];
    #pragma unroll
    for (int j = 0; j < 4; ++j){
      float xa[4];
      #pragma unroll
      for (int t = 0; t < 4; ++t){
        int ts = d ? 3 - t : t;
        unsigned short us = j==0?in4[ts].x : j==1?in4[ts].y : j==2?in4[ts].z : in4[ts].w;
        xa[t] = u2f(us);
      }
      float4 wv = *reinterpret_cast<const float4*>(&cwd[(c4 + j)*4]);
      float bb = cbd[c4 + j];
      float o[4];
      o[0] = xa[0]*wv.w + bb;
      o[1] = xa[0]*wv.z + xa[1]*wv.w + bb;
      o[2] = xa[0]*wv.y + xa[1]*wv.z + xa[2]*wv.w + bb;
      o[3] = xa[0]*wv.x + xa[1]*wv.y + xa[2]*wv.z + xa[3]*wv.w + bb;
      #pragma unroll
      for (int t = 0; t < 4; ++t){
        float v = o[t];
        float sv = v / (1.f + __expf(-v));
        unsigned short us = __bfloat16_as_ushort(f2b(sv));
        if (j==0) out[t].x = us; else if (j==1) out[t].y = us;
        else if (j==2) out[t].z = us; else out[t].w = us;
      }
    }
    #pragma unroll
    for (int t = 0; t < 4; ++t)
      *reinterpret_cast<ushort4*>(&u[(size_t)d*8388608 + ((size_t)n*4 + t)*1024 + c4]) = out[t];
  }
}

// ---------------- fused bidirectional scan + gate --------------------------
__global__ __launch_bounds__(256) void scan2_kernel(
    const float* __restrict__ dbl, const bf16* __restrict__ dt2,
    const bf16* __restrict__ u, const bf16* __restrict__ xz,
    const float* __restrict__ Atab2, const float* __restrict__ Dp,
    bf16* __restrict__ gated)
{
  __shared__ float Bs[2][4][16], Cs[2][4][16];
  const int n = blockIdx.x, g = blockIdx.y, tid = threadIdx.x;
  {
    int t = tid >> 6, j = tid & 63;
    int d = j >> 5, jj = j & 31;
    float v = dbl[((size_t)n*4 + t)*128 + d*64 + jj];
    if (jj < 16) Bs[d][t][jj] = v; else Cs[d][t][jj-16] = v;
  }
  __syncthreads();
  const int c = g*256 + tid;
  const size_t base = (size_t)n*4*1024 + c;
  float yo0[4], yo1[4];
  float hs[16];
  // ---- direction 0 ----
  {
    float A[16];
    const float4* ap = reinterpret_cast<const float4*>(Atab2 + (size_t)c*16);
    #pragma unroll
    for (int q = 0; q < 4; ++q){
      float4 v = ap[q];
      A[q*4+0]=v.x; A[q*4+1]=v.y; A[q*4+2]=v.z; A[q*4+3]=v.w;
    }
    const float Dpc = Dp[c];
    #pragma unroll
    for (int s = 0; s < 16; ++s) hs[s] = 0.f;
    #pragma unroll
    for (int t = 0; t < 4; ++t){
      float dtv = bfu(dt2[base + (size_t)t*1024]);
      float uv  = bfu(u  [base + (size_t)t*1024]);
      float du = dtv * uv;
      float yv = 0.f;
      #pragma unroll
      for (int s = 0; s < 16; ++s){
        float dA = __builtin_amdgcn_exp2f(dtv * A[s]);
        hs[s] = dA * hs[s] + du * Bs[0][t][s];
        yv += hs[s] * Cs[0][t][s];
      }
      yo0[t] = yv + uv * Dpc;
    }
  }
  // ---- direction 1 (time-reversed input; output flipped) ----
  {
    float A[16];
    const float4* ap = reinterpret_cast<const float4*>(Atab2 + 16384 + (size_t)c*16);
    #pragma unroll
    for (int q = 0; q < 4; ++q){
      float4 v = ap[q];
      A[q*4+0]=v.x; A[q*4+1]=v.y; A[q*4+2]=v.z; A[q*4+3]=v.w;
    }
    const float Dpc = Dp[1024 + c];
    #pragma unroll
    for (int s = 0; s < 16; ++s) hs[s] = 0.f;
    #pragma unroll
    for (int t = 0; t < 4; ++t){
      float dtv = bfu(dt2[8388608 + base + (size_t)t*1024]);
      float uv  = bfu(u  [8388608 + base + (size_t)t*1024]);
      float du = dtv * uv;
      float yv = 0.f;
      #pragma unroll
      for (int s = 0; s < 16; ++s){
        float dA = __builtin_amdgcn_exp2f(dtv * A[s]);
        hs[s] = dA * hs[s] + du * Bs[1][t][s];
        yv += hs[s] * Cs[1][t][s];
      }
      yo1[3 - t] = yv + uv * Dpc;
    }
  }
  // ---- gate + store (same thread wrote/read only channel c) ----
  #pragma unroll
  for (int t = 0; t < 4; ++t){
    float z = bfu(xz[(size_t)(n*4 + t)*2048 + 1024 + c]);
    float sv = z / (1.f + __expf(-z));
    gated[base + (size_t)t*1024] = f2b((yo0[t] + yo1[t]) * sv);
  }
}

// ---------------- launch ---------------------------------------------------
extern "C" void kernel_launch(void* const* d_in, const int* in_sizes, int n_in,
                              void* d_out, int out_size, void* d_ws, size_t ws_size,
                              hipStream_t stream)
{
  const float* x_flat    = (const float*)d_in[0];
  const float* conv_a_w  = (const float*)d_in[1];
  const float* conv_p_w  = (const float*)d_in[2];
  const float* se_w1     = (const float*)d_in[3];
  const float* se_b1     = (const float*)d_in[4];
  const float* se_w2     = (const float*)d_in[5];
  const float* se_b2     = (const float*)d_in[6];
  const float* ln_g      = (const float*)d_in[7];
  const float* ln_b      = (const float*)d_in[8];
  const float* in_proj_w = (const float*)d_in[9];
  const float* conv_w    = (const float*)d_in[10];
  const float* conv_b    = (const float*)d_in[11];
  const float* x_proj_w  = (const float*)d_in[12];
  const float* dt_proj_w = (const float*)d_in[13];
  const float* dt_proj_b = (const float*)d_in[14];
  const float* A_log     = (const float*)d_in[15];
  const float* D_param   = (const float*)d_in[16];
  const float* out_proj_w= (const float*)d_in[17];
  const float* out_ln_g  = (const float*)d_in[18];
  const float* out_ln_b  = (const float*)d_in[19];
  const float* mlp_w1    = (const float*)d_in[20];
  const float* mlp_b1    = (const float*)d_in[21];
  const float* mlp_w2    = (const float*)d_in[22];
  const float* mlp_b2    = (const float*)d_in[23];

  char* ws = (char*)d_ws;
  const size_t OFF_H    = 0;                       // f32  8192*512  = 16.78MB
  const size_t OFF_HN   = OFF_H    + 16777216;     // bf16 8192*512  (feat overlay)
  const size_t OFF_XZ   = OFF_HN   + 8388608;      // bf16 8192*2048 (z1 overlay)
  const size_t OFF_U    = OFF_XZ   + 33554432;     // bf16 u[2] 8192*1024 = 33.55MB
  const size_t OFF_SCR  = OFF_U    + 33554432;     // 25.17MB: Aa(stem)/dbl+dtrb(layers)/wb1(MLP)
  const size_t OFF_YB   = OFF_SCR  + 25165824;     // 33.55MB: Pm+wa+wp(stem)/dt2(layers)/wb2(MLP)
  const size_t OFF_WB   = OFF_YB   + 33554432;     // bf16 in_proj+out_proj
  const size_t OFF_WXP  = OFF_WB   + 6291456;      // bf16 2*256*1024 packed x_proj
  const size_t OFF_WDT  = OFF_WXP  + 1048576;      // bf16 4*1024*64 padded dt_proj
  const size_t OFF_ATAB = OFF_WDT  + 524288;       // f32  4*1024*16
  // total = OFF_ATAB + 262144 = ~160MB

  float* h    = (float*)(ws + OFF_H);
  bf16*  hn   = (bf16*) (ws + OFF_HN);
  bf16*  xz   = (bf16*) (ws + OFF_XZ);
  bf16*  u    = (bf16*) (ws + OFF_U);
  float* dbl  = (float*)(ws + OFF_SCR);                 // [8192][128] f32
  bf16*  dtrb = (bf16*) (ws + OFF_SCR + 4194304);       // [2][8192][64]
  bf16*  dt2  = (bf16*) (ws + OFF_YB);                  // [2][8192][1024]
  bf16*  feat = (bf16*) (ws + OFF_HN);   // overlay
  bf16*  z1   = (bf16*) (ws + OFF_XZ);   // overlay
  bf16*  wbi  = (bf16*) (ws + OFF_WB);
  bf16*  wbo  = (bf16*) (ws + OFF_WB + 4194304);
  bf16*  wxp  = (bf16*) (ws + OFF_WXP);
  bf16*  wdtp = (bf16*) (ws + OFF_WDT);
  float* Atab = (float*)(ws + OFF_ATAB);
  bf16*  wb1  = (bf16*) (ws + OFF_SCR);  // overlay (MLP phase)
  bf16*  wb2  = (bf16*) (ws + OFF_YB);   // overlay (MLP phase)
  // stem-phase overlays
  bf16*  Aa   = (bf16*) (ws + OFF_SCR);
  bf16*  Pm   = (bf16*) (ws + OFF_YB);
  bf16*  wa   = (bf16*) (ws + OFF_YB + 8388608);
  bf16*  wp   = (bf16*) (ws + OFF_YB + 8388608 + 786432);
  float* outf = (float*)d_out;

  // all weight prep in one dispatch
  prep_kernel<<<2048, 256, 0, stream>>>(
      conv_a_w, conv_p_w, in_proj_w, out_proj_w, x_proj_w, dt_proj_w, A_log,
      wa, wp, wbi, wbo, wxp, wdtp, Atab);

  // stem
  im2col_kernel<<<2048, 256, 0, stream>>>(x_flat, Aa, Pm);
  mgemm_kernel<1,1,false><<<dim3(64,2), 256, 0, stream>>>(
      Aa, wa, nullptr, h, 1536, 512);
  mgemm_kernel<1,1,false><<<dim3(64,2), 256, 0, stream>>>(
      Pm, wp, nullptr, (float*)h + 256, 512, 512);
  se_kernel<<<2048, 256, 0, stream>>>(se_w1, se_b1, se_w2, se_b2, h);

  for (int l = 0; l < 2; ++l){
    ln_kernel<<<2048, 256, 0, stream>>>(h, ln_g + l*512, ln_b + l*512, hn);
    mgemm_kernel<0,0,false><<<dim3(64,16), 256, 0, stream>>>(
        hn, wbi + (size_t)l*2048*512, nullptr, xz, 512, 2048);
    dwconv2_kernel<<<2048, 256, 0, stream>>>(
        xz, conv_w + (size_t)l*8192, conv_b + (size_t)l*2048, u);
    bgemm_kernel<<<dim3(64,2), 256, 0, stream>>>(
        u, wxp + (size_t)l*262144, dtrb, dbl);
    dtgemm_kernel<<<dim3(128,8), 256, 0, stream>>>(
        dtrb, wdtp + (size_t)l*131072, dt_proj_b + (size_t)l*2048, dt2);
    scan2_kernel<<<dim3(2048,4), 256, 0, stream>>>(
        dbl, dt2, u, xz, Atab + (size_t)l*32768, D_param + (size_t)l*2048,
        u /* gated overlays u dir0 */);
    mgemm128_kernel<0,2,false><<<dim3(64,4), 256, 0, stream>>>(
        u, wbo + (size_t)l*512*1024, nullptr, h, 1024, 512);
  }

  finalln_kernel<<<2048, 256, 0, stream>>>(h, out_ln_g, out_ln_b, feat);

  mlpprep_kernel<<<4096, 256, 0, stream>>>(
      (const float4*)mlp_w1, (const float4*)mlp_w2, (ushort4*)wb1, (ushort4*)wb2);

  mgemm128_kernel<1,0,true><<<dim3(16,32), 256, 0, stream>>>(
      feat, wb1, mlp_b1, z1, 512, 4096);
  mgemm128_kernel<1,1,true><<<dim3(16,32), 256, 0, stream>>>(
      z1, wb2, mlp_b2, outf, 4096, 4096);
}

// Round 13
// 635.180 us; speedup vs baseline: 4.2857x; 1.0290x over previous
//
#include <hip/hip_runtime.h>
#include <hip/hip_bf16.h>

typedef __hip_bfloat16 bf16;
typedef __attribute__((ext_vector_type(8))) short s16x8;
typedef __attribute__((ext_vector_type(4))) float f32x4;

__device__ __forceinline__ float u2f(unsigned short u){
  union { unsigned int i; float f; } v; v.i = ((unsigned int)u) << 16; return v.f;
}
__device__ __forceinline__ float bfu(bf16 x){ return __bfloat162float(x); }
__device__ __forceinline__ bf16  f2b(float x){ return __float2bfloat16(x); }

__device__ __forceinline__ void gload16(const void* g, void* l){
  __builtin_amdgcn_global_load_lds(
      (const __attribute__((address_space(1))) void*)g,
      (__attribute__((address_space(3))) void*)l, 16, 0, 0);
}

__device__ __forceinline__ float wave_sum(float v){
  #pragma unroll
  for (int o = 1; o < 64; o <<= 1) v += __shfl_xor(v, o, 64);
  return v;
}

__device__ __forceinline__ ushort4 cvt4(float4 v){
  ushort4 o;
  o.x = __bfloat16_as_ushort(f2b(v.x));
  o.y = __bfloat16_as_ushort(f2b(v.y));
  o.z = __bfloat16_as_ushort(f2b(v.z));
  o.w = __bfloat16_as_ushort(f2b(v.w));
  return o;
}

// ---------------- prep + im2col in ONE dispatch (grid 4096) ----------------
// blocks 0..2047: im2col of sample n.  blocks 2048..4095: weight conversions.
__global__ __launch_bounds__(256) void prep_im2col_kernel(
    const float* __restrict__ x_flat,
    const float* __restrict__ caw, const float* __restrict__ cpw,
    const float* __restrict__ ipw, const float* __restrict__ opw,
    const float* __restrict__ xpw, const float* __restrict__ dtw,
    const float* __restrict__ alog,
    bf16* __restrict__ Aa, bf16* __restrict__ P,
    bf16* __restrict__ wa, bf16* __restrict__ wp,
    bf16* __restrict__ wbi, bf16* __restrict__ wbo,
    bf16* __restrict__ wxp, bf16* __restrict__ wdtp,
    float* __restrict__ atab)
{
  __shared__ float xs[512][8];
  const int tid = threadIdx.x;
  if (blockIdx.x < 2048){
    const int n = blockIdx.x;
    const float* xr = x_flat + (size_t)n * 3584;
    for (int i = tid; i < 3584; i += 256) xs[i / 7][i % 7] = xr[i];
    __syncthreads();
    bf16* Ar = Aa + (size_t)n * 4 * 1536;
    for (int i = tid; i < 6144; i += 256){
      int t = i / 1536, col = i - t*1536;
      int c = col / 3, kk = col - c*3;
      int p = 2*t - 1 + kk;
      float v = (p >= 0 && p < 7) ? xs[c][p] : 0.f;
      Ar[i] = f2b(v);
    }
    bf16* Pr = P + (size_t)n * 4 * 512;
    for (int i = tid; i < 2048; i += 256){
      int t = i >> 9, c = i & 511;
      int st = 2*t - 1;
      float m = -1e30f;
      #pragma unroll
      for (int k = 0; k < 3; ++k){ int p = st + k; if (p >= 0 && p < 7) m = fmaxf(m, xs[c][p]); }
      Pr[i] = f2b(m);
    }
  } else {
    for (int i = (blockIdx.x - 2048)*256 + tid; i < 1769472; i += 2048*256){
      if (i < 917504){
        int j = i;
        const float4* src; ushort4* dst;
        if (j < 98304)      { src = (const float4*)caw; dst = (ushort4*)wa; }
        else if (j < 131072){ j -= 98304;  src = (const float4*)cpw; dst = (ushort4*)wp; }
        else if (j < 655360){ j -= 131072; src = (const float4*)ipw; dst = (ushort4*)wbi; }
        else                { j -= 655360; src = (const float4*)opw; dst = (ushort4*)wbo; }
        dst[j] = cvt4(src[j]);
      } else if (i < 1441792){
        int idx = i - 917504;                 // xpw pad: [L][2*128][1024]
        int l = idx >> 18, rem = idx & 262143, row = rem >> 10, c = rem & 1023;
        int d = row >> 7, r = row & 127;
        float v = (r < 64) ? xpw[(((size_t)l*2 + d)*64 + r)*1024 + c] : 0.f;
        wxp[idx] = f2b(v);
      } else if (i < 1703936){
        int idx = i - 1441792;                // wdt pad: [4][1024][64]
        int ld = idx >> 16, rem = idx & 65535, r = rem >> 6, cc = rem & 63;
        float v = (cc < 32) ? dtw[((size_t)ld*1024 + r)*32 + cc] : 0.f;
        wdtp[idx] = f2b(v);
      } else {
        int idx = i - 1703936;                // atab (pre-scaled by log2 e)
        atab[idx] = -__expf(alog[idx]) * 1.44269504088896f;
      }
    }
  }
}

// ---------------- MFMA GEMM (BK=64): out = act(A·Wᵀ + bias) ---------------
template<int ACT, int OMODE, bool HASBIAS>
__global__ __launch_bounds__(256) void mgemm_kernel(
    const bf16* __restrict__ A, const bf16* __restrict__ W,
    const float* __restrict__ bias, void* __restrict__ outp,
    int K, int ldo)
{
  __shared__ char lsA[16384];
  __shared__ char lsB[16384];
  const int tid = threadIdx.x;
  const int w = tid >> 6, l = tid & 63;
  const int nwg = gridDim.x * gridDim.y;
  const int lin = blockIdx.y * gridDim.x + blockIdx.x;
  const int cpx = nwg >> 3;
  const int swz = (lin & 7) * cpx + (lin >> 3);
  const int m0 = (swz % gridDim.x) * 128, n0 = (swz / gridDim.x) * 128;
  const int wr = w >> 1, wc = w & 1;
  const size_t ldb = (size_t)K * 2;
  const char* Ab = (const char*)A + (size_t)m0 * ldb;
  const char* Wb = (const char*)W + (size_t)n0 * ldb;

  const int srow = l >> 3;
  const int scb  = ((l & 7) ^ srow) << 4;
  const int fr = l & 15;
  const int fg = l >> 4;
  const int fsw = (fr & 7) << 4;

  f32x4 acc[4][4];
  #pragma unroll
  for (int m = 0; m < 4; ++m)
    #pragma unroll
    for (int n = 0; n < 4; ++n) acc[m][n] = (f32x4){0.f,0.f,0.f,0.f};

  const int nk = K >> 6;
  for (int kt = 0; kt < nk; ++kt){
    const char* As = Ab + (size_t)kt * 128;
    const char* Ws = Wb + (size_t)kt * 128;
    #pragma unroll
    for (int i = 0; i < 4; ++i){
      int row = (i*4 + w)*8 + srow;
      gload16(As + (size_t)row*ldb + scb, &lsA[(i*4 + w)*1024]);
    }
    #pragma unroll
    for (int i = 0; i < 4; ++i){
      int row = (i*4 + w)*8 + srow;
      gload16(Ws + (size_t)row*ldb + scb, &lsB[(i*4 + w)*1024]);
    }
    __syncthreads();

    s16x8 af[4][2], bfr[4][2];
    #pragma unroll
    for (int m = 0; m < 4; ++m){
      int row = wr*64 + m*16 + fr;
      af[m][0] = *(const s16x8*)&lsA[row*128 + (( 0 + fg*16) ^ fsw)];
      af[m][1] = *(const s16x8*)&lsA[row*128 + ((64 + fg*16) ^ fsw)];
    }
    #pragma unroll
    for (int n = 0; n < 4; ++n){
      int row = wc*64 + n*16 + fr;
      bfr[n][0] = *(const s16x8*)&lsB[row*128 + (( 0 + fg*16) ^ fsw)];
      bfr[n][1] = *(const s16x8*)&lsB[row*128 + ((64 + fg*16) ^ fsw)];
    }
    #pragma unroll
    for (int m = 0; m < 4; ++m)
      #pragma unroll
      for (int n = 0; n < 4; ++n){
        acc[m][n] = __builtin_amdgcn_mfma_f32_16x16x32_bf16(af[m][0], bfr[n][0], acc[m][n], 0, 0, 0);
        acc[m][n] = __builtin_amdgcn_mfma_f32_16x16x32_bf16(af[m][1], bfr[n][1], acc[m][n], 0, 0, 0);
      }
    __syncthreads();
  }

  const int orow0 = m0 + wr*64, ocol0 = n0 + wc*64;
  #pragma unroll
  for (int n = 0; n < 4; ++n){
    int col = ocol0 + n*16 + fr;
    float bv = HASBIAS ? bias[col] : 0.f;
    #pragma unroll
    for (int m = 0; m < 4; ++m){
      int rbase = orow0 + m*16 + fg*4;
      #pragma unroll
      for (int r = 0; r < 4; ++r){
        float v = acc[m][n][r] + bv;
        if (ACT == 1) v = fmaxf(v, 0.f);
        if (ACT == 2) v = (v > 20.f) ? v : log1pf(__expf(v));
        size_t oi = (size_t)(rbase + r) * ldo + col;
        if (OMODE == 0)      ((bf16*)outp)[oi] = f2b(v);
        else if (OMODE == 1) ((float*)outp)[oi] = v;
        else                 ((float*)outp)[oi] += v;
      }
    }
  }
}

// ---------------- batched stem GEMM: conv_a + conv_p in ONE dispatch -------
// grid (64,4): after swizzle, tile ty=swz/64 (0,1: conv_a; 2,3: conv_p),
// tm = swz%64. out col base = ty*128, ldo=512, f32 store + relu.
__global__ __launch_bounds__(256) void stemgemm_kernel(
    const bf16* __restrict__ Aa, const bf16* __restrict__ wa,
    const bf16* __restrict__ Pm, const bf16* __restrict__ wp,
    float* __restrict__ h)
{
  __shared__ char lsA[16384];
  __shared__ char lsB[16384];
  const int tid = threadIdx.x;
  const int w = tid >> 6, l = tid & 63;
  const int lin = blockIdx.y * gridDim.x + blockIdx.x;  // 256 blocks
  const int swz = (lin & 7) * 32 + (lin >> 3);
  const int tm = swz & 63, ty = swz >> 6;
  const int m0 = tm * 128;
  const bf16* A;
  const bf16* W;
  int K;
  if (ty < 2){ A = Aa; W = wa + (size_t)(ty)*128*1536; K = 1536; }
  else       { A = Pm; W = wp + (size_t)(ty-2)*128*512; K = 512; }
  const int wr = w >> 1, wc = w & 1;
  const size_t ldb = (size_t)K * 2;
  const char* Ab = (const char*)A + (size_t)m0 * ldb;
  const char* Wb = (const char*)W;

  const int srow = l >> 3;
  const int scb  = ((l & 7) ^ srow) << 4;
  const int fr = l & 15;
  const int fg = l >> 4;
  const int fsw = (fr & 7) << 4;

  f32x4 acc[4][4];
  #pragma unroll
  for (int m = 0; m < 4; ++m)
    #pragma unroll
    for (int n = 0; n < 4; ++n) acc[m][n] = (f32x4){0.f,0.f,0.f,0.f};

  const int nk = K >> 6;
  for (int kt = 0; kt < nk; ++kt){
    const char* As = Ab + (size_t)kt * 128;
    const char* Ws = Wb + (size_t)kt * 128;
    #pragma unroll
    for (int i = 0; i < 4; ++i){
      int row = (i*4 + w)*8 + srow;
      gload16(As + (size_t)row*ldb + scb, &lsA[(i*4 + w)*1024]);
    }
    #pragma unroll
    for (int i = 0; i < 4; ++i){
      int row = (i*4 + w)*8 + srow;
      gload16(Ws + (size_t)row*ldb + scb, &lsB[(i*4 + w)*1024]);
    }
    __syncthreads();

    s16x8 af[4][2], bfr[4][2];
    #pragma unroll
    for (int m = 0; m < 4; ++m){
      int row = wr*64 + m*16 + fr;
      af[m][0] = *(const s16x8*)&lsA[row*128 + (( 0 + fg*16) ^ fsw)];
      af[m][1] = *(const s16x8*)&lsA[row*128 + ((64 + fg*16) ^ fsw)];
    }
    #pragma unroll
    for (int n = 0; n < 4; ++n){
      int row = wc*64 + n*16 + fr;
      bfr[n][0] = *(const s16x8*)&lsB[row*128 + (( 0 + fg*16) ^ fsw)];
      bfr[n][1] = *(const s16x8*)&lsB[row*128 + ((64 + fg*16) ^ fsw)];
    }
    #pragma unroll
    for (int m = 0; m < 4; ++m)
      #pragma unroll
      for (int n = 0; n < 4; ++n){
        acc[m][n] = __builtin_amdgcn_mfma_f32_16x16x32_bf16(af[m][0], bfr[n][0], acc[m][n], 0, 0, 0);
        acc[m][n] = __builtin_amdgcn_mfma_f32_16x16x32_bf16(af[m][1], bfr[n][1], acc[m][n], 0, 0, 0);
      }
    __syncthreads();
  }

  const int orow0 = m0 + wr*64, ocol0 = ty*128 + wc*64;
  #pragma unroll
  for (int n = 0; n < 4; ++n){
    int col = ocol0 + n*16 + fr;
    #pragma unroll
    for (int m = 0; m < 4; ++m){
      int rbase = orow0 + m*16 + fg*4;
      #pragma unroll
      for (int r = 0; r < 4; ++r)
        h[(size_t)(rbase + r)*512 + col] = fmaxf(acc[m][n][r], 0.f);
    }
  }
}

// ---------------- MFMA GEMM (BK=128): half the barriers --------------------
template<int ACT, int OMODE, bool HASBIAS>
__global__ __launch_bounds__(256) void mgemm128_kernel(
    const bf16* __restrict__ A, const bf16* __restrict__ W,
    const float* __restrict__ bias, void* __restrict__ outp,
    int K, int ldo)
{
  __shared__ char lsA[32768];
  __shared__ char lsB[32768];
  const int tid = threadIdx.x;
  const int w = tid >> 6, l = tid & 63;
  const int nwg = gridDim.x * gridDim.y;
  const int lin = blockIdx.y * gridDim.x + blockIdx.x;
  const int cpx = nwg >> 3;
  const int swz = (lin & 7) * cpx + (lin >> 3);
  const int m0 = (swz % gridDim.x) * 128, n0 = (swz / gridDim.x) * 128;
  const int wr = w >> 1, wc = w & 1;
  const size_t ldb = (size_t)K * 2;
  const char* Ab = (const char*)A + (size_t)m0 * ldb;
  const char* Wb = (const char*)W + (size_t)n0 * ldb;

  const int srow4 = l >> 4;
  const int slot  = l & 15;
  const int fr = l & 15;
  const int fg = l >> 4;
  const int fx = fr & 7;

  f32x4 acc[4][4];
  #pragma unroll
  for (int m = 0; m < 4; ++m)
    #pragma unroll
    for (int n = 0; n < 4; ++n) acc[m][n] = (f32x4){0.f,0.f,0.f,0.f};

  const int nk = K >> 7;
  for (int kt = 0; kt < nk; ++kt){
    const char* As = Ab + (size_t)kt * 256;
    const char* Ws = Wb + (size_t)kt * 256;
    #pragma unroll
    for (int i = 0; i < 8; ++i){
      int c = i*4 + w;
      int row = c*4 + srow4;
      int colb = (slot ^ (row & 7)) << 4;
      gload16(As + (size_t)row*ldb + colb, &lsA[c*1024]);
      gload16(Ws + (size_t)row*ldb + colb, &lsB[c*1024]);
    }
    __syncthreads();

    #pragma unroll
    for (int half = 0; half < 2; ++half){
      s16x8 af[4][2], bfr[4][2];
      #pragma unroll
      for (int m = 0; m < 4; ++m){
        int row = wr*64 + m*16 + fr;
        af[m][0] = *(const s16x8*)&lsA[row*256 + ((((half*2+0)*4 + fg) ^ fx) << 4)];
        af[m][1] = *(const s16x8*)&lsA[row*256 + ((((half*2+1)*4 + fg) ^ fx) << 4)];
      }
      #pragma unroll
      for (int n = 0; n < 4; ++n){
        int row = wc*64 + n*16 + fr;
        bfr[n][0] = *(const s16x8*)&lsB[row*256 + ((((half*2+0)*4 + fg) ^ fx) << 4)];
        bfr[n][1] = *(const s16x8*)&lsB[row*256 + ((((half*2+1)*4 + fg) ^ fx) << 4)];
      }
      #pragma unroll
      for (int m = 0; m < 4; ++m)
        #pragma unroll
        for (int n = 0; n < 4; ++n){
          acc[m][n] = __builtin_amdgcn_mfma_f32_16x16x32_bf16(af[m][0], bfr[n][0], acc[m][n], 0, 0, 0);
          acc[m][n] = __builtin_amdgcn_mfma_f32_16x16x32_bf16(af[m][1], bfr[n][1], acc[m][n], 0, 0, 0);
        }
    }
    __syncthreads();
  }

  const int orow0 = m0 + wr*64, ocol0 = n0 + wc*64;
  #pragma unroll
  for (int n = 0; n < 4; ++n){
    int col = ocol0 + n*16 + fr;
    float bv = HASBIAS ? bias[col] : 0.f;
    #pragma unroll
    for (int m = 0; m < 4; ++m){
      int rbase = orow0 + m*16 + fg*4;
      #pragma unroll
      for (int r = 0; r < 4; ++r){
        float v = acc[m][n][r] + bv;
        if (ACT == 1) v = fmaxf(v, 0.f);
        if (ACT == 2) v = (v > 20.f) ? v : log1pf(__expf(v));
        size_t oi = (size_t)(rbase + r) * ldo + col;
        if (OMODE == 0)      ((bf16*)outp)[oi] = f2b(v);
        else if (OMODE == 1) ((float*)outp)[oi] = v;
        else                 ((float*)outp)[oi] += v;
      }
    }
  }
}

// ---------------- batched x_proj GEMM ---------------------------------------
__global__ __launch_bounds__(256) void bgemm_kernel(
    const bf16* __restrict__ A, const bf16* __restrict__ W,
    bf16* __restrict__ dtr_buf, float* __restrict__ dbl)
{
  __shared__ char lsA[16384];
  __shared__ char lsB[16384];
  const int tid = threadIdx.x;
  const int w = tid >> 6, l = tid & 63;
  const int nwg = gridDim.x * 2;
  const int lin = blockIdx.y * gridDim.x + blockIdx.x;
  const int cpx = nwg >> 3;
  const int swz = (lin & 7) * cpx + (lin >> 3);
  const int m0 = (swz % gridDim.x) * 128;
  const int d  = swz / gridDim.x;
  const int K = 1024;
  const int wr = w >> 1, wc = w & 1;
  const size_t ldb = (size_t)K * 2;
  const char* Ab = (const char*)(A + (size_t)d*8388608) + (size_t)m0 * ldb;
  const char* Wb = (const char*)(W + (size_t)d*131072);

  const int srow = l >> 3;
  const int scb  = ((l & 7) ^ srow) << 4;
  const int fr = l & 15;
  const int fg = l >> 4;
  const int fsw = (fr & 7) << 4;

  f32x4 acc[4][4];
  #pragma unroll
  for (int m = 0; m < 4; ++m)
    #pragma unroll
    for (int n = 0; n < 4; ++n) acc[m][n] = (f32x4){0.f,0.f,0.f,0.f};

  const int nk = K >> 6;
  for (int kt = 0; kt < nk; ++kt){
    const char* As = Ab + (size_t)kt * 128;
    const char* Ws = Wb + (size_t)kt * 128;
    #pragma unroll
    for (int i = 0; i < 4; ++i){
      int row = (i*4 + w)*8 + srow;
      gload16(As + (size_t)row*ldb + scb, &lsA[(i*4 + w)*1024]);
    }
    #pragma unroll
    for (int i = 0; i < 4; ++i){
      int row = (i*4 + w)*8 + srow;
      gload16(Ws + (size_t)row*ldb + scb, &lsB[(i*4 + w)*1024]);
    }
    __syncthreads();

    s16x8 af[4][2], bfr[4][2];
    #pragma unroll
    for (int m = 0; m < 4; ++m){
      int row = wr*64 + m*16 + fr;
      af[m][0] = *(const s16x8*)&lsA[row*128 + (( 0 + fg*16) ^ fsw)];
      af[m][1] = *(const s16x8*)&lsA[row*128 + ((64 + fg*16) ^ fsw)];
    }
    #pragma unroll
    for (int n = 0; n < 4; ++n){
      int row = wc*64 + n*16 + fr;
      bfr[n][0] = *(const s16x8*)&lsB[row*128 + (( 0 + fg*16) ^ fsw)];
      bfr[n][1] = *(const s16x8*)&lsB[row*128 + ((64 + fg*16) ^ fsw)];
    }
    #pragma unroll
    for (int m = 0; m < 4; ++m)
      #pragma unroll
      for (int n = 0; n < 4; ++n){
        acc[m][n] = __builtin_amdgcn_mfma_f32_16x16x32_bf16(af[m][0], bfr[n][0], acc[m][n], 0, 0, 0);
        acc[m][n] = __builtin_amdgcn_mfma_f32_16x16x32_bf16(af[m][1], bfr[n][1], acc[m][n], 0, 0, 0);
      }
    __syncthreads();
  }

  const int orow0 = m0 + wr*64, c0 = wc*64;
  #pragma unroll
  for (int n = 0; n < 4; ++n){
    int col = c0 + n*16 + fr;
    #pragma unroll
    for (int m = 0; m < 4; ++m){
      int rbase = orow0 + m*16 + fg*4;
      #pragma unroll
      for (int r = 0; r < 4; ++r){
        float v = acc[m][n][r];
        int row = rbase + r;
        if (col < 32)
          dtr_buf[((size_t)d*8192 + row)*64 + col] = f2b(v);
        else if (col < 64)
          dbl[(size_t)row*128 + d*64 + (col - 32)] = v;
        else if (col < 96)
          dtr_buf[((size_t)d*8192 + row)*64 + (col - 32)] = f2b(v);  // pad zeros
      }
    }
  }
}

// ---------------- dt_proj GEMM, both dirs in one dispatch ------------------
__global__ __launch_bounds__(256) void dtgemm_kernel(
    const bf16* __restrict__ A, const bf16* __restrict__ W2,
    const float* __restrict__ bias2, bf16* __restrict__ out2)
{
  __shared__ char lsA[16384];
  __shared__ char lsB[16384];
  const int tid = threadIdx.x;
  const int w = tid >> 6, l = tid & 63;
  const int nwg = gridDim.x * gridDim.y;          // 1024
  const int lin = blockIdx.y * gridDim.x + blockIdx.x;
  const int cpx = nwg >> 3;
  const int swz = (lin & 7) * cpx + (lin >> 3);
  const int m0 = (swz % gridDim.x) * 128, n0 = (swz / gridDim.x) * 128;
  const int d  = (m0 >= 8192) ? 1 : 0;
  const int wr = w >> 1, wc = w & 1;
  const size_t ldb = 128;
  const char* Ab = (const char*)A + (size_t)m0 * ldb;
  const char* Wb = (const char*)(W2 + (size_t)d*65536) + (size_t)n0 * ldb;
  const float* bias = bias2 + d*1024;
  bf16* outp = out2 + (size_t)d*8388608;

  const int srow = l >> 3;
  const int scb  = ((l & 7) ^ srow) << 4;
  const int fr = l & 15, fg = l >> 4;
  const int fsw = (fr & 7) << 4;

  f32x4 acc[4][4];
  #pragma unroll
  for (int m = 0; m < 4; ++m)
    #pragma unroll
    for (int n = 0; n < 4; ++n) acc[m][n] = (f32x4){0.f,0.f,0.f,0.f};

  #pragma unroll
  for (int i = 0; i < 4; ++i){
    int row = (i*4 + w)*8 + srow;
    gload16(Ab + (size_t)row*ldb + scb, &lsA[(i*4 + w)*1024]);
  }
  #pragma unroll
  for (int i = 0; i < 4; ++i){
    int row = (i*4 + w)*8 + srow;
    gload16(Wb + (size_t)row*ldb + scb, &lsB[(i*4 + w)*1024]);
  }
  __syncthreads();

  s16x8 af[4][2], bfr[4][2];
  #pragma unroll
  for (int m = 0; m < 4; ++m){
    int row = wr*64 + m*16 + fr;
    af[m][0] = *(const s16x8*)&lsA[row*128 + (( 0 + fg*16) ^ fsw)];
    af[m][1] = *(const s16x8*)&lsA[row*128 + ((64 + fg*16) ^ fsw)];
  }
  #pragma unroll
  for (int n = 0; n < 4; ++n){
    int row = wc*64 + n*16 + fr;
    bfr[n][0] = *(const s16x8*)&lsB[row*128 + (( 0 + fg*16) ^ fsw)];
    bfr[n][1] = *(const s16x8*)&lsB[row*128 + ((64 + fg*16) ^ fsw)];
  }
  #pragma unroll
  for (int m = 0; m < 4; ++m)
    #pragma unroll
    for (int n = 0; n < 4; ++n){
      acc[m][n] = __builtin_amdgcn_mfma_f32_16x16x32_bf16(af[m][0], bfr[n][0], acc[m][n], 0, 0, 0);
      acc[m][n] = __builtin_amdgcn_mfma_f32_16x16x32_bf16(af[m][1], bfr[n][1], acc[m][n], 0, 0, 0);
    }

  const int orow0 = (m0 - d*8192) + wr*64, ocol0 = n0 + wc*64;
  #pragma unroll
  for (int n = 0; n < 4; ++n){
    int col = ocol0 + n*16 + fr;
    float bv = bias[col];
    #pragma unroll
    for (int m = 0; m < 4; ++m){
      int rbase = orow0 + m*16 + fg*4;
      #pragma unroll
      for (int r = 0; r < 4; ++r){
        float v = acc[m][n][r] + bv;
        v = (v > 20.f) ? v : log1pf(__expf(v));          // softplus
        outp[(size_t)(rbase + r) * 1024 + col] = f2b(v);
      }
    }
  }
}

// ---------------- SE + layer-0 LN fused (one block per sample) -------------
// Phase 1: SE (mean, 2 matvecs, sigmoid). Phase 2: scale h in place AND
// layernorm each of the 4 rows (wave w owns row t=w) -> hn (bf16).
__global__ __launch_bounds__(256) void se_ln_kernel(
    const float* __restrict__ sw1, const float* __restrict__ sb1,
    const float* __restrict__ sw2, const float* __restrict__ sb2,
    const float* __restrict__ g, const float* __restrict__ b,
    float* __restrict__ h, bf16* __restrict__ hn)
{
  __shared__ float yms[512];
  __shared__ float s1s[32];
  __shared__ float sg[512];
  const int n = blockIdx.x, tid = threadIdx.x;
  float* hb = h + (size_t)n * 2048;
  for (int c = tid; c < 512; c += 256)
    yms[c] = 0.25f * (hb[c] + hb[512+c] + hb[1024+c] + hb[1536+c]);
  __syncthreads();
  {
    int o = tid >> 3, sl = tid & 7;
    const float* wr = sw1 + (size_t)o * 512 + sl*64;
    const float* ym = yms + sl*64;
    float a = 0.f;
    #pragma unroll 16
    for (int i = 0; i < 64; ++i) a += wr[i] * ym[i];
    a += __shfl_down(a, 4, 8);
    a += __shfl_down(a, 2, 8);
    a += __shfl_down(a, 1, 8);
    if (sl == 0) s1s[o] = fmaxf(a + sb1[o], 0.f);
  }
  __syncthreads();
  for (int c = tid; c < 512; c += 256){
    float a = sb2[c];
    const float* wr = sw2 + (size_t)c * 32;
    #pragma unroll
    for (int j = 0; j < 32; ++j) a += wr[j] * s1s[j];
    sg[c] = 1.f / (1.f + __expf(-a));
  }
  __syncthreads();
  // per-wave row: scale + writeback + LN
  const int lane = tid & 63, wv = tid >> 6;
  float* hr = hb + wv*512;
  float4 v0 = ((float4*)hr)[lane], v1 = ((float4*)hr)[lane + 64];
  int c0 = lane*4, c1 = 256 + lane*4;
  v0.x *= sg[c0+0]; v0.y *= sg[c0+1]; v0.z *= sg[c0+2]; v0.w *= sg[c0+3];
  v1.x *= sg[c1+0]; v1.y *= sg[c1+1]; v1.z *= sg[c1+2]; v1.w *= sg[c1+3];
  ((float4*)hr)[lane] = v0;
  ((float4*)hr)[lane + 64] = v1;
  float s = wave_sum(v0.x+v0.y+v0.z+v0.w + v1.x+v1.y+v1.z+v1.w);
  float mu = s * (1.f/512.f);
  float d0x=v0.x-mu, d0y=v0.y-mu, d0z=v0.z-mu, d0w=v0.w-mu;
  float d1x=v1.x-mu, d1y=v1.y-mu, d1z=v1.z-mu, d1w=v1.w-mu;
  float sq = wave_sum(d0x*d0x+d0y*d0y+d0z*d0z+d0w*d0w +
                      d1x*d1x+d1y*d1y+d1z*d1z+d1w*d1w);
  float rstd = rsqrtf(sq * (1.f/512.f) + 1e-5f);
  float4 g0 = ((const float4*)g)[lane], g1 = ((const float4*)g)[lane+64];
  float4 b0 = ((const float4*)b)[lane], b1 = ((const float4*)b)[lane+64];
  ushort4 o0, o1;
  o0.x = __bfloat16_as_ushort(f2b(d0x*rstd*g0.x + b0.x));
  o0.y = __bfloat16_as_ushort(f2b(d0y*rstd*g0.y + b0.y));
  o0.z = __bfloat16_as_ushort(f2b(d0z*rstd*g0.z + b0.z));
  o0.w = __bfloat16_as_ushort(f2b(d0w*rstd*g0.w + b0.w));
  o1.x = __bfloat16_as_ushort(f2b(d1x*rstd*g1.x + b1.x));
  o1.y = __bfloat16_as_ushort(f2b(d1y*rstd*g1.y + b1.y));
  o1.z = __bfloat16_as_ushort(f2b(d1z*rstd*g1.z + b1.z));
  o1.w = __bfloat16_as_ushort(f2b(d1w*rstd*g1.w + b1.w));
  ushort4* orow = (ushort4*)(hn + ((size_t)n*4 + wv)*512);
  orow[lane] = o0;
  orow[lane + 64] = o1;
}

// ---------------- layernorm: wave-per-row, 4 rows/block, grid 2048 ---------
__global__ __launch_bounds__(256) void ln_kernel(
    const float* __restrict__ x, const float* __restrict__ g,
    const float* __restrict__ b, bf16* __restrict__ out)
{
  const int lane = threadIdx.x & 63, wid = threadIdx.x >> 6;
  const int row = blockIdx.x*4 + wid;
  const float4* xr = (const float4*)(x + (size_t)row*512);
  float4 v0 = xr[lane], v1 = xr[lane + 64];
  float s = wave_sum(v0.x+v0.y+v0.z+v0.w + v1.x+v1.y+v1.z+v1.w);
  float mu = s * (1.f/512.f);
  float d0x=v0.x-mu, d0y=v0.y-mu, d0z=v0.z-mu, d0w=v0.w-mu;
  float d1x=v1.x-mu, d1y=v1.y-mu, d1z=v1.z-mu, d1w=v1.w-mu;
  float sq = wave_sum(d0x*d0x+d0y*d0y+d0z*d0z+d0w*d0w +
                      d1x*d1x+d1y*d1y+d1z*d1z+d1w*d1w);
  float rstd = rsqrtf(sq * (1.f/512.f) + 1e-5f);
  float4 g0 = ((const float4*)g)[lane], g1 = ((const float4*)g)[lane+64];
  float4 b0 = ((const float4*)b)[lane], b1 = ((const float4*)b)[lane+64];
  ushort4 o0, o1;
  o0.x = __bfloat16_as_ushort(f2b(d0x*rstd*g0.x + b0.x));
  o0.y = __bfloat16_as_ushort(f2b(d0y*rstd*g0.y + b0.y));
  o0.z = __bfloat16_as_ushort(f2b(d0z*rstd*g0.z + b0.z));
  o0.w = __bfloat16_as_ushort(f2b(d0w*rstd*g0.w + b0.w));
  o1.x = __bfloat16_as_ushort(f2b(d1x*rstd*g1.x + b1.x));
  o1.y = __bfloat16_as_ushort(f2b(d1y*rstd*g1.y + b1.y));
  o1.z = __bfloat16_as_ushort(f2b(d1z*rstd*g1.z + b1.z));
  o1.w = __bfloat16_as_ushort(f2b(d1w*rstd*g1.w + b1.w));
  ushort4* orow = (ushort4*)(out + (size_t)row*512);
  orow[lane] = o0;
  orow[lane + 64] = o1;
}

// ---------------- final LN+mean (blocks 0..2047) + MLP weight conv ---------
__global__ __launch_bounds__(256) void finalln_mlp_kernel(
    const float* __restrict__ h, const float* __restrict__ g,
    const float* __restrict__ b, bf16* __restrict__ feat,
    const float4* __restrict__ w1, const float4* __restrict__ w2,
    ushort4* __restrict__ o1, ushort4* __restrict__ o2)
{
  __shared__ float red[4];
  const int tid = threadIdx.x;
  if (blockIdx.x < 2048){
    const int n = blockIdx.x, t = tid;
    float a0 = 0.f, a1 = 0.f;
    for (int tt = 0; tt < 4; ++tt){
      const float* xr = h + ((size_t)n*4 + tt)*512;
      float v0 = xr[t], v1 = xr[t+256];
      float sv = v0 + v1;
      #pragma unroll
      for (int o = 32; o > 0; o >>= 1) sv += __shfl_down(sv, o, 64);
      int lane = tid & 63, wid = tid >> 6;
      if (lane == 0) red[wid] = sv;
      __syncthreads();
      float s = red[0] + red[1] + red[2] + red[3];
      __syncthreads();
      float mu = s * (1.f/512.f);
      float d0 = v0 - mu, d1 = v1 - mu;
      float q = d0*d0 + d1*d1;
      #pragma unroll
      for (int o = 32; o > 0; o >>= 1) q += __shfl_down(q, o, 64);
      if (lane == 0) red[wid] = q;
      __syncthreads();
      float sq = red[0] + red[1] + red[2] + red[3];
      __syncthreads();
      float rstd = rsqrtf(sq * (1.f/512.f) + 1e-5f);
      a0 += d0*rstd*g[t]     + b[t];
      a1 += d1*rstd*g[t+256] + b[t+256];
    }
    feat[(size_t)n*512 + t]       = f2b(a0 * 0.25f);
    feat[(size_t)n*512 + t + 256] = f2b(a1 * 0.25f);
  } else {
    for (int i = (blockIdx.x - 2048)*256 + tid; i < 4718592; i += 4096*256){
      if (i < 524288) o1[i] = cvt4(w1[i]);
      else            o2[i - 524288] = cvt4(w2[i - 524288]);
    }
  }
}

// ---------------- causal dwconv (both dirs) + silu, 4 ch/thread ------------
__global__ __launch_bounds__(256) void dwconv2_kernel(
    const bf16* __restrict__ xz, const float* __restrict__ cw,
    const float* __restrict__ cb, bf16* __restrict__ u)
{
  const int n = blockIdx.x;
  const int c4 = threadIdx.x * 4;
  ushort4 in4[4];
  #pragma unroll
  for (int t = 0; t < 4; ++t)
    in4[t] = *reinterpret_cast<const ushort4*>(&xz[((size_t)n*4 + t)*2048 + c4]);
  #pragma unroll
  for (int d = 0; d < 2; ++d){
    const float* cwd = cw + d*4096;
    const float* cbd = cb + d*1024;
    ushort4 out[4];
    #pragma unroll
    for (int j = 0; j < 4; ++j){
      float xa[4];
      #pragma unroll
      for (int t = 0; t < 4; ++t){
        int ts = d ? 3 - t : t;
        unsigned short us = j==0?in4[ts].x : j==1?in4[ts].y : j==2?in4[ts].z : in4[ts].w;
        xa[t] = u2f(us);
      }
      float4 wv = *reinterpret_cast<const float4*>(&cwd[(c4 + j)*4]);
      float bb = cbd[c4 + j];
      float o[4];
      o[0] = xa[0]*wv.w + bb;
      o[1] = xa[0]*wv.z + xa[1]*wv.w + bb;
      o[2] = xa[0]*wv.y + xa[1]*wv.z + xa[2]*wv.w + bb;
      o[3] = xa[0]*wv.x + xa[1]*wv.y + xa[2]*wv.z + xa[3]*wv.w + bb;
      #pragma unroll
      for (int t = 0; t < 4; ++t){
        float v = o[t];
        float sv = v / (1.f + __expf(-v));
        unsigned short us = __bfloat16_as_ushort(f2b(sv));
        if (j==0) out[t].x = us; else if (j==1) out[t].y = us;
        else if (j==2) out[t].z = us; else out[t].w = us;
      }
    }
    #pragma unroll
    for (int t = 0; t < 4; ++t)
      *reinterpret_cast<ushort4*>(&u[(size_t)d*8388608 + ((size_t)n*4 + t)*1024 + c4]) = out[t];
  }
}

// ---------------- fused bidirectional scan + gate --------------------------
__global__ __launch_bounds__(256) void scan2_kernel(
    const float* __restrict__ dbl, const bf16* __restrict__ dt2,
    const bf16* __restrict__ u, const bf16* __restrict__ xz,
    const float* __restrict__ Atab2, const float* __restrict__ Dp,
    bf16* __restrict__ gated)
{
  __shared__ float Bs[2][4][16], Cs[2][4][16];
  const int n = blockIdx.x, g = blockIdx.y, tid = threadIdx.x;
  {
    int t = tid >> 6, j = tid & 63;
    int d = j >> 5, jj = j & 31;
    float v = dbl[((size_t)n*4 + t)*128 + d*64 + jj];
    if (jj < 16) Bs[d][t][jj] = v; else Cs[d][t][jj-16] = v;
  }
  __syncthreads();
  const int c = g*256 + tid;
  const size_t base = (size_t)n*4*1024 + c;
  float yo0[4], yo1[4];
  float hs[16];
  // ---- direction 0 ----
  {
    float A[16];
    const float4* ap = reinterpret_cast<const float4*>(Atab2 + (size_t)c*16);
    #pragma unroll
    for (int q = 0; q < 4; ++q){
      float4 v = ap[q];
      A[q*4+0]=v.x; A[q*4+1]=v.y; A[q*4+2]=v.z; A[q*4+3]=v.w;
    }
    const float Dpc = Dp[c];
    #pragma unroll
    for (int s = 0; s < 16; ++s) hs[s] = 0.f;
    #pragma unroll
    for (int t = 0; t < 4; ++t){
      float dtv = bfu(dt2[base + (size_t)t*1024]);
      float uv  = bfu(u  [base + (size_t)t*1024]);
      float du = dtv * uv;
      float yv = 0.f;
      #pragma unroll
      for (int s = 0; s < 16; ++s){
        float dA = __builtin_amdgcn_exp2f(dtv * A[s]);
        hs[s] = dA * hs[s] + du * Bs[0][t][s];
        yv += hs[s] * Cs[0][t][s];
      }
      yo0[t] = yv + uv * Dpc;
    }
  }
  // ---- direction 1 (time-reversed input; output flipped) ----
  {
    float A[16];
    const float4* ap = reinterpret_cast<const float4*>(Atab2 + 16384 + (size_t)c*16);
    #pragma unroll
    for (int q = 0; q < 4; ++q){
      float4 v = ap[q];
      A[q*4+0]=v.x; A[q*4+1]=v.y; A[q*4+2]=v.z; A[q*4+3]=v.w;
    }
    const float Dpc = Dp[1024 + c];
    #pragma unroll
    for (int s = 0; s < 16; ++s) hs[s] = 0.f;
    #pragma unroll
    for (int t = 0; t < 4; ++t){
      float dtv = bfu(dt2[8388608 + base + (size_t)t*1024]);
      float uv  = bfu(u  [8388608 + base + (size_t)t*1024]);
      float du = dtv * uv;
      float yv = 0.f;
      #pragma unroll
      for (int s = 0; s < 16; ++s){
        float dA = __builtin_amdgcn_exp2f(dtv * A[s]);
        hs[s] = dA * hs[s] + du * Bs[1][t][s];
        yv += hs[s] * Cs[1][t][s];
      }
      yo1[3 - t] = yv + uv * Dpc;
    }
  }
  // ---- gate + store ----
  #pragma unroll
  for (int t = 0; t < 4; ++t){
    float z = bfu(xz[(size_t)(n*4 + t)*2048 + 1024 + c]);
    float sv = z / (1.f + __expf(-z));
    gated[base + (size_t)t*1024] = f2b((yo0[t] + yo1[t]) * sv);
  }
}

// ---------------- launch ---------------------------------------------------
extern "C" void kernel_launch(void* const* d_in, const int* in_sizes, int n_in,
                              void* d_out, int out_size, void* d_ws, size_t ws_size,
                              hipStream_t stream)
{
  const float* x_flat    = (const float*)d_in[0];
  const float* conv_a_w  = (const float*)d_in[1];
  const float* conv_p_w  = (const float*)d_in[2];
  const float* se_w1     = (const float*)d_in[3];
  const float* se_b1     = (const float*)d_in[4];
  const float* se_w2     = (const float*)d_in[5];
  const float* se_b2     = (const float*)d_in[6];
  const float* ln_g      = (const float*)d_in[7];
  const float* ln_b      = (const float*)d_in[8];
  const float* in_proj_w = (const float*)d_in[9];
  const float* conv_w    = (const float*)d_in[10];
  const float* conv_b    = (const float*)d_in[11];
  const float* x_proj_w  = (const float*)d_in[12];
  const float* dt_proj_w = (const float*)d_in[13];
  const float* dt_proj_b = (const float*)d_in[14];
  const float* A_log     = (const float*)d_in[15];
  const float* D_param   = (const float*)d_in[16];
  const float* out_proj_w= (const float*)d_in[17];
  const float* out_ln_g  = (const float*)d_in[18];
  const float* out_ln_b  = (const float*)d_in[19];
  const float* mlp_w1    = (const float*)d_in[20];
  const float* mlp_b1    = (const float*)d_in[21];
  const float* mlp_w2    = (const float*)d_in[22];
  const float* mlp_b2    = (const float*)d_in[23];

  char* ws = (char*)d_ws;
  const size_t OFF_H    = 0;                       // f32  8192*512  = 16.78MB
  const size_t OFF_HN   = OFF_H    + 16777216;     // bf16 8192*512  (feat overlay)
  const size_t OFF_XZ   = OFF_HN   + 8388608;      // bf16 8192*2048 (z1 overlay)
  const size_t OFF_U    = OFF_XZ   + 33554432;     // bf16 u[2] 8192*1024
  const size_t OFF_SCR  = OFF_U    + 33554432;     // Aa(stem)/dbl+dtrb(layers)/wb1(MLP)
  const size_t OFF_YB   = OFF_SCR  + 25165824;     // Pm+wa+wp(stem)/dt2(layers)/wb2(MLP)
  const size_t OFF_WB   = OFF_YB   + 33554432;     // bf16 in_proj+out_proj
  const size_t OFF_WXP  = OFF_WB   + 6291456;      // bf16 packed x_proj
  const size_t OFF_WDT  = OFF_WXP  + 1048576;      // bf16 padded dt_proj
  const size_t OFF_ATAB = OFF_WDT  + 524288;       // f32  4*1024*16

  float* h    = (float*)(ws + OFF_H);
  bf16*  hn   = (bf16*) (ws + OFF_HN);
  bf16*  xz   = (bf16*) (ws + OFF_XZ);
  bf16*  u    = (bf16*) (ws + OFF_U);
  float* dbl  = (float*)(ws + OFF_SCR);
  bf16*  dtrb = (bf16*) (ws + OFF_SCR + 4194304);
  bf16*  dt2  = (bf16*) (ws + OFF_YB);
  bf16*  feat = (bf16*) (ws + OFF_HN);   // overlay
  bf16*  z1   = (bf16*) (ws + OFF_XZ);   // overlay
  bf16*  wbi  = (bf16*) (ws + OFF_WB);
  bf16*  wbo  = (bf16*) (ws + OFF_WB + 4194304);
  bf16*  wxp  = (bf16*) (ws + OFF_WXP);
  bf16*  wdtp = (bf16*) (ws + OFF_WDT);
  float* Atab = (float*)(ws + OFF_ATAB);
  bf16*  wb1  = (bf16*) (ws + OFF_SCR);  // overlay (MLP phase)
  bf16*  wb2  = (bf16*) (ws + OFF_YB);   // overlay (MLP phase)
  bf16*  Aa   = (bf16*) (ws + OFF_SCR);
  bf16*  Pm   = (bf16*) (ws + OFF_YB);
  bf16*  wa   = (bf16*) (ws + OFF_YB + 8388608);
  bf16*  wp   = (bf16*) (ws + OFF_YB + 8388608 + 786432);
  float* outf = (float*)d_out;

  // prep + im2col in one dispatch
  prep_im2col_kernel<<<4096, 256, 0, stream>>>(
      x_flat, conv_a_w, conv_p_w, in_proj_w, out_proj_w, x_proj_w, dt_proj_w,
      A_log, Aa, Pm, wa, wp, wbi, wbo, wxp, wdtp, Atab);

  // both stem convs in one batched GEMM (256 blocks)
  stemgemm_kernel<<<dim3(64,4), 256, 0, stream>>>(Aa, wa, Pm, wp, h);

  // SE + layer-0 LN fused
  se_ln_kernel<<<2048, 256, 0, stream>>>(
      se_w1, se_b1, se_w2, se_b2, ln_g, ln_b, h, hn);

  for (int l = 0; l < 2; ++l){
    if (l == 1)
      ln_kernel<<<2048, 256, 0, stream>>>(h, ln_g + 512, ln_b + 512, hn);
    mgemm_kernel<0,0,false><<<dim3(64,16), 256, 0, stream>>>(
        hn, wbi + (size_t)l*2048*512, nullptr, xz, 512, 2048);
    dwconv2_kernel<<<2048, 256, 0, stream>>>(
        xz, conv_w + (size_t)l*8192, conv_b + (size_t)l*2048, u);
    bgemm_kernel<<<dim3(64,2), 256, 0, stream>>>(
        u, wxp + (size_t)l*262144, dtrb, dbl);
    dtgemm_kernel<<<dim3(128,8), 256, 0, stream>>>(
        dtrb, wdtp + (size_t)l*131072, dt_proj_b + (size_t)l*2048, dt2);
    scan2_kernel<<<dim3(2048,4), 256, 0, stream>>>(
        dbl, dt2, u, xz, Atab + (size_t)l*32768, D_param + (size_t)l*2048,
        u /* gated overlays u dir0 */);
    mgemm128_kernel<0,2,false><<<dim3(64,4), 256, 0, stream>>>(
        u, wbo + (size_t)l*512*1024, nullptr, h, 1024, 512);
  }

  // final LN + MLP weight conversion in one dispatch
  finalln_mlp_kernel<<<6144, 256, 0, stream>>>(
      h, out_ln_g, out_ln_b, feat,
      (const float4*)mlp_w1, (const float4*)mlp_w2, (ushort4*)wb1, (ushort4*)wb2);

  mgemm128_kernel<1,0,true><<<dim3(16,32), 256, 0, stream>>>(
      feat, wb1, mlp_b1, z1, 512, 4096);
  mgemm128_kernel<1,1,true><<<dim3(16,32), 256, 0, stream>>>(
      z1, wb2, mlp_b2, outf, 4096, 4096);
}